// Round 1
// baseline (1117.229 us; speedup 1.0000x reference)
//
#include <hip/hip_runtime.h>
#include <cstdint>
#include <cstddef>

typedef __bf16 bf16;
typedef __bf16 bf16x2 __attribute__((ext_vector_type(2)));
typedef __bf16 bf16x4 __attribute__((ext_vector_type(4)));
typedef __bf16 bf16x8 __attribute__((ext_vector_type(8)));
typedef float  f32x4  __attribute__((ext_vector_type(4)));
typedef __attribute__((address_space(1))) unsigned int u32_g;
typedef __attribute__((address_space(3))) unsigned int u32_l;

#define DI __device__ __forceinline__

constexpr int Bc = 2, Sc = 2048, Dc = 1024, Hc = 16, HDc = 64, Fc = 4096, Mc = 1024;
constexpr int NTc = Bc * Sc;  // 4096 tokens

DI void llds16(const bf16* g, bf16* l) {
  __builtin_amdgcn_global_load_lds((const u32_g*)g, (u32_l*)l, 16, 0, 0);
}
DI f32x4 cvt4(bf16x4 a) {
  f32x4 r; r[0] = (float)a[0]; r[1] = (float)a[1]; r[2] = (float)a[2]; r[3] = (float)a[3];
  return r;
}

// ---------------------------------------------------------------- dtype detector (inputs)
__global__ void k_detect(const unsigned short* __restrict__ x, int* __restrict__ flag)
{
  const int tid = threadIdx.x;  // 64
  int cnt = 0;
#pragma unroll
  for (int i = 0; i < 8; i++) {
    unsigned short h = x[tid * 8 + i];
    int e = (h >> 7) & 0xFF;
    if (e < 96 || e > 160) cnt++;
  }
#pragma unroll
  for (int off = 32; off > 0; off >>= 1) cnt += __shfl_down(cnt, off, 64);
  if (tid == 0) *flag = (cnt > 32) ? 1 : 0;
}

// ---------------------------------------------------------------- dtype-aware convert to bf16
__global__ __launch_bounds__(256)
void k_cvt(const void* __restrict__ src, bf16* __restrict__ dst, int n4, const int* __restrict__ flag)
{
  int i = blockIdx.x * 256 + threadIdx.x;
  if (i >= n4) return;
  bf16x4 o;
  if (*flag) {
    f32x4 v = ((const f32x4*)src)[i];
    o[0] = (bf16)v[0]; o[1] = (bf16)v[1]; o[2] = (bf16)v[2]; o[3] = (bf16)v[3];
  } else {
    o = ((const bf16x4*)src)[i];
  }
  ((bf16x4*)dst)[i] = o;
}

// ---------------------------------------------------------------- dtype-aware transpose [R][C] -> bf16 [C][R]
__global__ void k_transpose_dt(const void* __restrict__ src, bf16* __restrict__ dst,
                               int R, int C, const int* __restrict__ flag)
{
  __shared__ bf16 tile[32][33];
  const int c0 = blockIdx.x * 32, r0 = blockIdx.y * 32;
  const int tx = threadIdx.x, ty = threadIdx.y;
  const bool f32 = (*flag != 0);
  for (int i = ty; i < 32; i += 8) {
    size_t idx = (size_t)(r0 + i) * C + (c0 + tx);
    tile[i][tx] = f32 ? (bf16)((const float*)src)[idx] : ((const bf16*)src)[idx];
  }
  __syncthreads();
  for (int i = ty; i < 32; i += 8)
    dst[(size_t)(c0 + i) * R + (r0 + tx)] = tile[tx][i];
}

// ---------------------------------------------------------------- per-head V transpose: v[(b*S+s)][h*64+d] -> vt[(bh*64+d)][s]
__global__ void k_transpose_v(const bf16* __restrict__ v, bf16* __restrict__ vt)
{
  __shared__ bf16 tile[32][33];
  const int d0 = blockIdx.x * 32, s0 = blockIdx.y * 32;
  const int bh = blockIdx.z;
  const int b = bh >> 4, hh = bh & 15;
  const int tx = threadIdx.x, ty = threadIdx.y;
  for (int i = ty; i < 32; i += 8)
    tile[i][tx] = v[((size_t)(b * Sc + s0 + i)) * Dc + hh * HDc + d0 + tx];
  __syncthreads();
  for (int i = ty; i < 32; i += 8)
    vt[((size_t)(bh * HDc + d0 + i)) * Sc + s0 + tx] = tile[tx][i];
}

// ---------------------------------------------------------------- GEMM (NT): C[M][N] = A[M][K] * Bt[N][K]^T
// Epilogue batches aux/res loads per mt-phase into registers BEFORE any store
// of that phase: breaks the compiler's conservative store->load alias ordering
// that serialized the in-place SILU epilogue (926us, MfmaUtil 2.5% in R8).
enum EpiMode { EPI_BF16 = 0, EPI_BIAS_BF16, EPI_BIAS_RELU_BF16, EPI_BIAS_RESB_F32,
               EPI_SILU_BF16, EPI_DZ_BF16, EPI_RESX_BF16, EPI_RESF_F32 };

template <int EPI>
__global__ __launch_bounds__(256)
void k_gemm(const bf16* __restrict__ A, const bf16* __restrict__ Bt,
            int Mr, int Nr, int Kr,
            float* outF, bf16* outB,
            const bf16* __restrict__ bias, const bf16* auxB,
            const float* resF,
            const void* __restrict__ resX, const int* __restrict__ flag)
{
  __shared__ bf16 As[128 * 32];
  __shared__ bf16 Bs[128 * 32];
  const int tid = threadIdx.x;
  const int w = tid >> 6, l = tid & 63;
  const int wr = w >> 1, wc = w & 1;
  const int row0 = blockIdx.y * 128, col0 = blockIdx.x * 128;

  const f32x4 vzero = {0.f, 0.f, 0.f, 0.f};
  f32x4 acc[4][4];
#pragma unroll
  for (int i = 0; i < 4; i++)
#pragma unroll
    for (int j = 0; j < 4; j++) acc[i][j] = vzero;

  const bf16* Ag = A + (size_t)(row0 + w * 16 + (l >> 2)) * Kr + ((l & 3) << 3);
  const bf16* Bg = Bt + (size_t)(col0 + w * 16 + (l >> 2)) * Kr + ((l & 3) << 3);
  bf16* AsW = &As[w * 512];
  bf16* BsW = &Bs[w * 512];
  const size_t rowHop = (size_t)64 * Kr;

  for (int k0 = 0; k0 < Kr; k0 += 32) {
    __syncthreads();
    llds16(Ag + k0, AsW);
    llds16(Ag + rowHop + k0, AsW + 2048);
    llds16(Bg + k0, BsW);
    llds16(Bg + rowHop + k0, BsW + 2048);
    __syncthreads();
    bf16x8 af[4], bfr[4];
#pragma unroll
    for (int mt = 0; mt < 4; mt++)
      af[mt] = *(const bf16x8*)&As[(wr * 64 + mt * 16 + (l & 15)) * 32 + (l >> 4) * 8];
#pragma unroll
    for (int nt = 0; nt < 4; nt++)
      bfr[nt] = *(const bf16x8*)&Bs[(wc * 64 + nt * 16 + (l & 15)) * 32 + (l >> 4) * 8];
#pragma unroll
    for (int mt = 0; mt < 4; mt++)
#pragma unroll
      for (int nt = 0; nt < 4; nt++)
        acc[mt][nt] = __builtin_amdgcn_mfma_f32_16x16x32_bf16(af[mt], bfr[nt], acc[mt][nt], 0, 0, 0);
  }

  const bool f32res = (EPI == EPI_RESX_BF16) ? (*flag != 0) : false;
  // bias preload (before ANY store exists -> fully parallel)
  float biasv[4];
  if (EPI == EPI_BIAS_BF16 || EPI == EPI_BIAS_RELU_BF16 || EPI == EPI_BIAS_RESB_F32) {
#pragma unroll
    for (int nt = 0; nt < 4; nt++)
      biasv[nt] = (float)bias[col0 + wc * 64 + nt * 16 + (l & 15)];
  }
  // C/D layout (verified m89/m91): col = lane&15, row = (lane>>4)*4 + reg
#pragma unroll
  for (int mt = 0; mt < 4; mt++) {
    const int rowb = row0 + wr * 64 + mt * 16 + ((l >> 4) << 2);
    // phase 1: batch-gather aux/res for this mt (16 independent loads)
    float av[4][4];
    if (EPI == EPI_SILU_BF16 || EPI == EPI_DZ_BF16 || EPI == EPI_BIAS_RESB_F32) {
#pragma unroll
      for (int nt = 0; nt < 4; nt++) {
        const int col = col0 + wc * 64 + nt * 16 + (l & 15);
#pragma unroll
        for (int r = 0; r < 4; r++)
          av[nt][r] = (float)auxB[(size_t)(rowb + r) * Nr + col];
      }
    }
    if (EPI == EPI_RESF_F32) {
#pragma unroll
      for (int nt = 0; nt < 4; nt++) {
        const int col = col0 + wc * 64 + nt * 16 + (l & 15);
#pragma unroll
        for (int r = 0; r < 4; r++)
          av[nt][r] = resF[(size_t)(rowb + r) * Nr + col];
      }
    }
    if (EPI == EPI_RESX_BF16) {
#pragma unroll
      for (int nt = 0; nt < 4; nt++) {
        const int col = col0 + wc * 64 + nt * 16 + (l & 15);
#pragma unroll
        for (int r = 0; r < 4; r++) {
          const size_t idx = (size_t)(rowb + r) * Nr + col;
          av[nt][r] = f32res ? ((const float*)resX)[idx] : (float)((const bf16*)resX)[idx];
        }
      }
    }
    // phase 2: compute + store
#pragma unroll
    for (int nt = 0; nt < 4; nt++) {
      const int col = col0 + wc * 64 + nt * 16 + (l & 15);
#pragma unroll
      for (int r = 0; r < 4; r++) {
        const size_t idx = (size_t)(rowb + r) * Nr + col;
        float v = acc[mt][nt][r];
        if (EPI == EPI_BF16) { outB[idx] = (bf16)v; }
        else if (EPI == EPI_BIAS_BF16) { outB[idx] = (bf16)(v + biasv[nt]); }
        else if (EPI == EPI_BIAS_RELU_BF16) { outB[idx] = (bf16)fmaxf(v + biasv[nt], 0.f); }
        else if (EPI == EPI_BIAS_RESB_F32) { outF[idx] = v + biasv[nt] + av[nt][r]; }
        else if (EPI == EPI_SILU_BF16) {
          float s1v = av[nt][r];
          float sl = s1v / (1.f + __expf(-s1v));
          outB[idx] = (bf16)(sl * v);
        }
        else if (EPI == EPI_DZ_BF16) { outB[idx] = (bf16)(av[nt][r] > 0.f ? v : 0.f); }
        else if (EPI == EPI_RESX_BF16) { outB[idx] = (bf16)(v + av[nt][r]); }
        else if (EPI == EPI_RESF_F32) { outF[idx] = v + av[nt][r]; }
      }
    }
  }
}

// ---------------------------------------------------------------- GEMM (TN) split-K: C[i][j] += sum_t X[t][i]*Y[t][j]
// grid (8,8,SPLIT); out must be zero-initialized; fp32 atomicAdd epilogue.
__global__ __launch_bounds__(256)
void k_gemm_tn(const bf16* __restrict__ X, const bf16* __restrict__ Y, int Kt,
               float* __restrict__ out)
{
  __shared__ bf16 As[128 * 36];
  __shared__ bf16 Bs[128 * 36];
  const int tid = threadIdx.x;
  const int w = tid >> 6, l = tid & 63;
  const int wr = w >> 1, wc = w & 1;
  const int row0 = blockIdx.y * 128, col0 = blockIdx.x * 128;
  const int iofs = (tid & 15) * 8;   // 0..120
  const int tp   = (tid >> 4) * 2;   // 0..30

  const f32x4 vzero = {0.f, 0.f, 0.f, 0.f};
  f32x4 acc[4][4];
#pragma unroll
  for (int i = 0; i < 4; i++)
#pragma unroll
    for (int j = 0; j < 4; j++) acc[i][j] = vzero;

  const int chunk = Kt / gridDim.z;
  const int tbeg = blockIdx.z * chunk;

  for (int t0 = tbeg; t0 < tbeg + chunk; t0 += 32) {
    __syncthreads();
    bf16x8 a0 = *(const bf16x8*)&X[(size_t)(t0 + tp) * 1024 + row0 + iofs];
    bf16x8 a1 = *(const bf16x8*)&X[(size_t)(t0 + tp + 1) * 1024 + row0 + iofs];
    bf16x8 b0 = *(const bf16x8*)&Y[(size_t)(t0 + tp) * 1024 + col0 + iofs];
    bf16x8 b1 = *(const bf16x8*)&Y[(size_t)(t0 + tp + 1) * 1024 + col0 + iofs];
#pragma unroll
    for (int e = 0; e < 8; e++) {
      bf16x2 pa; pa[0] = a0[e]; pa[1] = a1[e];
      bf16x2 pb; pb[0] = b0[e]; pb[1] = b1[e];
      *(bf16x2*)&As[(iofs + e) * 36 + tp] = pa;
      *(bf16x2*)&Bs[(iofs + e) * 36 + tp] = pb;
    }
    __syncthreads();
    bf16x8 af[4], bfr[4];
#pragma unroll
    for (int mt = 0; mt < 4; mt++) {
      const int base = (wr * 64 + mt * 16 + (l & 15)) * 36 + (l >> 4) * 8;
      bf16x4 lo = *(const bf16x4*)&As[base];
      bf16x4 hi = *(const bf16x4*)&As[base + 4];
#pragma unroll
      for (int e = 0; e < 4; e++) { af[mt][e] = lo[e]; af[mt][4 + e] = hi[e]; }
    }
#pragma unroll
    for (int nt = 0; nt < 4; nt++) {
      const int base = (wc * 64 + nt * 16 + (l & 15)) * 36 + (l >> 4) * 8;
      bf16x4 lo = *(const bf16x4*)&Bs[base];
      bf16x4 hi = *(const bf16x4*)&Bs[base + 4];
#pragma unroll
      for (int e = 0; e < 4; e++) { bfr[nt][e] = lo[e]; bfr[nt][4 + e] = hi[e]; }
    }
#pragma unroll
    for (int mt = 0; mt < 4; mt++)
#pragma unroll
      for (int nt = 0; nt < 4; nt++)
        acc[mt][nt] = __builtin_amdgcn_mfma_f32_16x16x32_bf16(af[mt], bfr[nt], acc[mt][nt], 0, 0, 0);
  }

#pragma unroll
  for (int mt = 0; mt < 4; mt++) {
    const int rowb = row0 + wr * 64 + mt * 16 + ((l >> 4) << 2);
#pragma unroll
    for (int nt = 0; nt < 4; nt++) {
      const int col = col0 + wc * 64 + nt * 16 + (l & 15);
#pragma unroll
      for (int r = 0; r < 4; r++)
        atomicAdd(&out[(size_t)(rowb + r) * 1024 + col], acc[mt][nt][r]);
    }
  }
}

// ---------------------------------------------------------------- RMSNorm variants
__global__ __launch_bounds__(256)
void k_rmsnorm_dt(const void* __restrict__ x, const bf16* __restrict__ w, bf16* __restrict__ out,
                  const int* __restrict__ flag)
{
  const int row = blockIdx.x;
  const int tid = threadIdx.x;
  f32x4 xv;
  if (*flag) xv = *(const f32x4*)((const float*)x + (size_t)row * Dc + tid * 4);
  else       xv = cvt4(*(const bf16x4*)((const bf16*)x + (size_t)row * Dc + tid * 4));
  float ss = xv[0] * xv[0] + xv[1] * xv[1] + xv[2] * xv[2] + xv[3] * xv[3];
#pragma unroll
  for (int off = 32; off > 0; off >>= 1) ss += __shfl_down(ss, off, 64);
  __shared__ float part[4];
  if ((tid & 63) == 0) part[tid >> 6] = ss;
  __syncthreads();
  float tot = part[0] + part[1] + part[2] + part[3];
  float inv = 1.f / (sqrtf(tot) * 0.03125f + 1e-8f);
  bf16x4 wb = *(const bf16x4*)(w + tid * 4);
  bf16x4 ov;
  ov[0] = (bf16)((float)wb[0] * xv[0] * inv);
  ov[1] = (bf16)((float)wb[1] * xv[1] * inv);
  ov[2] = (bf16)((float)wb[2] * xv[2] * inv);
  ov[3] = (bf16)((float)wb[3] * xv[3] * inv);
  *(bf16x4*)(out + (size_t)row * Dc + tid * 4) = ov;
}

__global__ __launch_bounds__(256)
void k_rmsnorm_b(const bf16* __restrict__ x, const bf16* __restrict__ w, bf16* __restrict__ out)
{
  const int row = blockIdx.x;
  const int tid = threadIdx.x;
  f32x4 xv = cvt4(*(const bf16x4*)(x + (size_t)row * Dc + tid * 4));
  float ss = xv[0] * xv[0] + xv[1] * xv[1] + xv[2] * xv[2] + xv[3] * xv[3];
#pragma unroll
  for (int off = 32; off > 0; off >>= 1) ss += __shfl_down(ss, off, 64);
  __shared__ float part[4];
  if ((tid & 63) == 0) part[tid >> 6] = ss;
  __syncthreads();
  float tot = part[0] + part[1] + part[2] + part[3];
  float inv = 1.f / (sqrtf(tot) * 0.03125f + 1e-8f);
  bf16x4 wb = *(const bf16x4*)(w + tid * 4);
  bf16x4 ov;
  ov[0] = (bf16)((float)wb[0] * xv[0] * inv);
  ov[1] = (bf16)((float)wb[1] * xv[1] * inv);
  ov[2] = (bf16)((float)wb[2] * xv[2] * inv);
  ov[3] = (bf16)((float)wb[3] * xv[3] * inv);
  *(bf16x4*)(out + (size_t)row * Dc + tid * 4) = ov;
}

__global__ __launch_bounds__(256)
void k_rmsnorm_f(const float* __restrict__ x, const bf16* __restrict__ w, bf16* __restrict__ out)
{
  const int row = blockIdx.x;
  const int tid = threadIdx.x;
  f32x4 xv = *(const f32x4*)(x + (size_t)row * Dc + tid * 4);
  float ss = xv[0] * xv[0] + xv[1] * xv[1] + xv[2] * xv[2] + xv[3] * xv[3];
#pragma unroll
  for (int off = 32; off > 0; off >>= 1) ss += __shfl_down(ss, off, 64);
  __shared__ float part[4];
  if ((tid & 63) == 0) part[tid >> 6] = ss;
  __syncthreads();
  float tot = part[0] + part[1] + part[2] + part[3];
  float inv = 1.f / (sqrtf(tot) * 0.03125f + 1e-8f);
  bf16x4 wb = *(const bf16x4*)(w + tid * 4);
  bf16x4 ov;
  ov[0] = (bf16)((float)wb[0] * xv[0] * inv);
  ov[1] = (bf16)((float)wb[1] * xv[1] * inv);
  ov[2] = (bf16)((float)wb[2] * xv[2] * inv);
  ov[3] = (bf16)((float)wb[3] * xv[3] * inv);
  *(bf16x4*)(out + (size_t)row * Dc + tid * 4) = ov;
}

// ---------------------------------------------------------------- RoPE in-place on bf16 q,k
__global__ __launch_bounds__(256)
void k_rope(bf16* __restrict__ q, bf16* __restrict__ kx)
{
  const int idx = blockIdx.x * 256 + threadIdx.x;  // NT*H = 65536
  const int t = idx >> 4, hh = idx & 15;
  const int s = t & (Sc - 1);
  float sn[32], cs[32];
#pragma unroll
  for (int i = 0; i < 32; i++) {
    float f = expf(-(float)i * 0.28782313662425574f);  // ln(10000)/32
    float ang = (float)s * f;
    sn[i] = sinf(ang);
    cs[i] = cosf(ang);
  }
  for (int pass = 0; pass < 2; pass++) {
    bf16* p = (pass ? kx : q) + (size_t)t * Dc + hh * HDc;
    float xb[64], ob[64];
#pragma unroll
    for (int j = 0; j < 16; j++) *(f32x4*)&xb[j * 4] = cvt4(*(const bf16x4*)(p + j * 4));
#pragma unroll
    for (int i = 0; i < 32; i++) {
      float x1 = xb[2 * i], x2 = xb[2 * i + 1];
      ob[i] = x1 * cs[i] - x2 * sn[i];
      ob[32 + i] = x1 * sn[i] + x2 * cs[i];
    }
#pragma unroll
    for (int j = 0; j < 16; j++) {
      bf16x4 o4;
      o4[0] = (bf16)ob[j * 4]; o4[1] = (bf16)ob[j * 4 + 1];
      o4[2] = (bf16)ob[j * 4 + 2]; o4[3] = (bf16)ob[j * 4 + 3];
      *(bf16x4*)(p + j * 4) = o4;
    }
  }
}

// ---------------------------------------------------------------- MFMA flash attention (no K/V LDS staging)
// K/V per head = 512 KB -> L2-resident. blk&31==bh keeps a head's 32 q-blocks
// on one XCD (blk%8==bh%8); qt reversed = LPT packing. Zero __syncthreads:
// only per-wave Ps LDS remains (9 KB/block -> 8 blocks/CU residency cap).
__global__ __launch_bounds__(256)
void k_attn(const bf16* __restrict__ q, const bf16* __restrict__ kx,
            const bf16* __restrict__ vt, bf16* __restrict__ o)
{
  constexpr int PAD = 72;
  __shared__ bf16 Ps[4][16 * PAD];     // per-wave P buffer

  const int blk = blockIdx.x;
  const int qt = 31 - (blk >> 5);      // heavy q-tiles dispatch first
  const int bh = blk & 31;             // same head -> same XCD residue
  const int b = bh >> 4, hh = bh & 15;
  const int tid = threadIdx.x;
  const int w = tid >> 6, l = tid & 63;
  const int quad = l >> 4, c = l & 15;

  const int qrow = qt * 64 + w * 16 + c;
  const size_t qbase = ((size_t)(b * Sc + qrow)) * Dc + hh * HDc;
  bf16x8 qf0 = *(const bf16x8*)(q + qbase + quad * 8);
  bf16x8 qf1 = *(const bf16x8*)(q + qbase + 32 + quad * 8);
#pragma unroll
  for (int j = 0; j < 8; j++) {
    qf0[j] = (bf16)((float)qf0[j] * 0.125f);
    qf1[j] = (bf16)((float)qf1[j] * 0.125f);
  }

  const f32x4 vzero = {0.f, 0.f, 0.f, 0.f};
  f32x4 oacc[4];
#pragma unroll
  for (int nt = 0; nt < 4; nt++) oacc[nt] = vzero;
  float mrun[4] = {-3.0e38f, -3.0e38f, -3.0e38f, -3.0e38f};
  float lrun[4] = {0.f, 0.f, 0.f, 0.f};

  const int qrow0 = qt * 64 + w * 16 + quad * 4;

  const bf16* kb = kx + (size_t)b * Sc * Dc + hh * HDc;   // + krow*Dc
  const bf16* vb = vt + (size_t)bh * HDc * Sc;            // + d*Sc + kk

  for (int t0 = 0; t0 <= qt; t0++) {
    const int kk0 = t0 * 64;

    // QK^T: B-fragments straight from global K (row-major, 8 contiguous bf16/lane)
    f32x4 sf[4];
#pragma unroll
    for (int nt = 0; nt < 4; nt++) {
      const bf16* kr = kb + (size_t)(kk0 + nt * 16 + c) * Dc + quad * 8;
      bf16x8 k0 = *(const bf16x8*)kr;
      bf16x8 k1 = *(const bf16x8*)(kr + 32);
      f32x4 a = vzero;
      a = __builtin_amdgcn_mfma_f32_16x16x32_bf16(qf0, k0, a, 0, 0, 0);
      a = __builtin_amdgcn_mfma_f32_16x16x32_bf16(qf1, k1, a, 0, 0, 0);
      sf[nt] = a;
    }
    if (t0 == qt) {
#pragma unroll
      for (int nt = 0; nt < 4; nt++)
#pragma unroll
        for (int r = 0; r < 4; r++)
          if (kk0 + nt * 16 + c > qrow0 + r) sf[nt][r] = -3.0e38f;
    }

    float mnew[4], alpha[4];
#pragma unroll
    for (int r = 0; r < 4; r++) {
      float mt = fmaxf(fmaxf(sf[0][r], sf[1][r]), fmaxf(sf[2][r], sf[3][r]));
      mt = fmaxf(mt, __shfl_xor(mt, 1, 64));
      mt = fmaxf(mt, __shfl_xor(mt, 2, 64));
      mt = fmaxf(mt, __shfl_xor(mt, 4, 64));
      mt = fmaxf(mt, __shfl_xor(mt, 8, 64));
      mnew[r] = fmaxf(mrun[r], mt);
      alpha[r] = __expf(mrun[r] - mnew[r]);
      mrun[r] = mnew[r];
    }
    float ps[4] = {0.f, 0.f, 0.f, 0.f};
#pragma unroll
    for (int nt = 0; nt < 4; nt++)
#pragma unroll
      for (int r = 0; r < 4; r++) {
        float p = __expf(sf[nt][r] - mnew[r]);
        sf[nt][r] = p;
        ps[r] += p;
      }
#pragma unroll
    for (int r = 0; r < 4; r++) {
      ps[r] += __shfl_xor(ps[r], 1, 64);
      ps[r] += __shfl_xor(ps[r], 2, 64);
      ps[r] += __shfl_xor(ps[r], 4, 64);
      ps[r] += __shfl_xor(ps[r], 8, 64);
      lrun[r] = lrun[r] * alpha[r] + ps[r];
    }
#pragma unroll
    for (int nt = 0; nt < 4; nt++)
#pragma unroll
      for (int r = 0; r < 4; r++) oacc[nt][r] *= alpha[r];

    // P layout shuffle through per-wave LDS (wave-internal: no barrier needed)
#pragma unroll
    for (int nt = 0; nt < 4; nt++)
#pragma unroll
      for (int r = 0; r < 4; r++)
        Ps[w][(quad * 4 + r) * PAD + nt * 16 + c] = (bf16)sf[nt][r];
    bf16x8 pa0 = *(const bf16x8*)&Ps[w][c * PAD + quad * 8];
    bf16x8 pa1 = *(const bf16x8*)&Ps[w][c * PAD + 32 + quad * 8];

    // PV: B-fragments from pre-transposed global Vt (8 contiguous bf16/lane)
#pragma unroll
    for (int nt = 0; nt < 4; nt++) {
      const bf16* vr = vb + (size_t)(nt * 16 + c) * Sc + kk0 + quad * 8;
      bf16x8 v0 = *(const bf16x8*)vr;
      bf16x8 v1 = *(const bf16x8*)(vr + 32);
      oacc[nt] = __builtin_amdgcn_mfma_f32_16x16x32_bf16(pa0, v0, oacc[nt], 0, 0, 0);
      oacc[nt] = __builtin_amdgcn_mfma_f32_16x16x32_bf16(pa1, v1, oacc[nt], 0, 0, 0);
    }
  }

  float inv[4];
#pragma unroll
  for (int r = 0; r < 4; r++) inv[r] = 1.f / lrun[r];
#pragma unroll
  for (int r = 0; r < 4; r++) {
    const size_t obase = ((size_t)(b * Sc + qrow0 + r)) * Dc + hh * HDc;
#pragma unroll
    for (int nt = 0; nt < 4; nt++)
      o[obase + nt * 16 + c] = (bf16)(oacc[nt][r] * inv[r]);
  }
}

// ---------------------------------------------------------------- elementwise relu (x8)
__global__ __launch_bounds__(256)
void k_relu(const bf16* __restrict__ src, bf16* __restrict__ dst)
{
  int i = blockIdx.x * 256 + threadIdx.x;  // n/8 threads
  bf16x8 v = ((const bf16x8*)src)[i];
  bf16x8 o;
#pragma unroll
  for (int e = 0; e < 8; e++) o[e] = ((float)v[e] > 0.f) ? v[e] : (bf16)0.f;
  ((bf16x8*)dst)[i] = o;
}

// ---------------------------------------------------------------- dp = 2(pred-vf)/M in-place + loss
__global__ __launch_bounds__(256)
void k_dpred(bf16* __restrict__ predDp, const bf16* __restrict__ vf, float* __restrict__ loss)
{
  __shared__ float red[4];
  const int tid = threadIdx.x;
  const size_t n8 = (size_t)NTc * Mc / 8;
  float lacc = 0.f;
  for (size_t i = (size_t)blockIdx.x * 256 + tid; i < n8; i += (size_t)gridDim.x * 256) {
    bf16x8 p8 = ((const bf16x8*)predDp)[i];
    bf16x8 v8 = ((const bf16x8*)vf)[i];
    bf16x8 d8;
#pragma unroll
    for (int e = 0; e < 8; e++) {
      float df = (float)p8[e] - (float)v8[e];
      lacc += df * df;
      d8[e] = (bf16)(df * (2.0f / 1024.0f));
    }
    ((bf16x8*)predDp)[i] = d8;
  }
#pragma unroll
  for (int off = 32; off > 0; off >>= 1) lacc += __shfl_down(lacc, off, 64);
  if ((tid & 63) == 0) red[tid >> 6] = lacc;
  __syncthreads();
  if (tid == 0) atomicAdd(loss, red[0] + red[1] + red[2] + red[3]);
}

// ---------------------------------------------------------------- colsum: out[c] += sum over a row chunk
__global__ __launch_bounds__(256)
void k_colsum(const bf16* __restrict__ X, float* __restrict__ out, int C, int rowsPer)
{
  int c = blockIdx.x * 256 + threadIdx.x;
  int r0 = blockIdx.y * rowsPer;
  float s = 0.f;
#pragma unroll 8
  for (int r = r0; r < r0 + rowsPer; r++) s += (float)X[(size_t)r * C + c];
  atomicAdd(&out[c], s);
}

// ---------------------------------------------------------------- dtype-aware param/momentum update -> fp32 d_out
__global__ __launch_bounds__(256)
void k_update_dt(const void* __restrict__ p0w, const void* __restrict__ p0b,
                 const void* __restrict__ p1w, const void* __restrict__ p1b,
                 const void* __restrict__ m0w, const void* __restrict__ m0b,
                 const void* __restrict__ m1w, const void* __restrict__ m1b,
                 const float* __restrict__ g0wF, const float* __restrict__ g0b,
                 const float* __restrict__ g1wF, const float* __restrict__ g1b,
                 const float* __restrict__ loss, const int* __restrict__ flag,
                 float* __restrict__ outP, float* __restrict__ outM)
{
  const int i = blockIdx.x * 256 + threadIdx.x;  // < 2099200 exactly
  const bool upd = (loss[0] >= 0.1f * 1024.f * 4096.f);  // avg_loss >= THRESH
  const bool f32 = (*flag != 0);
  constexpr int W = 1024 * 1024;
  const void *pp, *pm; int j; float g;
  if (i < W) { pp = p0w; pm = m0w; j = i; g = g0wF[i]; }
  else if (i < W + 1024) { j = i - W; pp = p0b; pm = m0b; g = g0b[j]; }
  else if (i < 2 * W + 1024) { j = i - W - 1024; pp = p1w; pm = m1w; g = g1wF[j]; }
  else { j = i - 2 * W - 1024; pp = p1b; pm = m1b; g = g1b[j]; }
  float p = f32 ? ((const float*)pp)[j] : (float)((const bf16*)pp)[j];
  float m = f32 ? ((const float*)pm)[j] : (float)((const bf16*)pm)[j];
  float nm = 0.9f * m - 0.01f * g;
  float np = 0.99f * p + nm;
  outP[i] = upd ? np : p;
  outM[i] = upd ? nm : m;
}

// ================================================================ host
extern "C" void kernel_launch(void* const* d_in, const int* in_sizes, int n_in,
                              void* d_out, int out_size, void* d_ws, size_t ws_size,
                              hipStream_t stream)
{
  (void)in_sizes; (void)n_in; (void)out_size; (void)ws_size;
  const void* x   = d_in[0];
  const void* wq  = d_in[2];
  const void* wk  = d_in[3];
  const void* wv  = d_in[4];
  const void* wo  = d_in[5];
  const void* n1  = d_in[6];
  const void* n2  = d_in[7];
  const void* n3  = d_in[8];
  const void* fw1 = d_in[9];
  const void* fw2 = d_in[10];
  const void* fw3 = d_in[11];
  const void* pkw = d_in[12];
  const void* pkb = d_in[13];
  const void* pvw = d_in[14];
  const void* pvb = d_in[15];
  const void* pqw = d_in[16];
  const void* pqb = d_in[17];
  const void* l0w = d_in[18];
  const void* l0b = d_in[19];
  const void* l1w = d_in[20];
  const void* l1b = d_in[21];
  const void* m0w = d_in[22];
  const void* m0b = d_in[23];
  const void* m1w = d_in[24];
  const void* m1b = d_in[25];

  char* ws = (char*)d_ws;
  size_t off = 0;
  auto alloc = [&](size_t bytes) -> char* {
    char* p = ws + off;
    off += (bytes + 255) & ~(size_t)255;
    return p;
  };

  const size_t DD = (size_t)Dc * Dc;   // 1M elems
  const size_t ND = (size_t)NTc * Dc;  // 4M elems
  const size_t MB8 = 2 * ND;           // 8 MiB
  const size_t M1 = DD;                // 1M elems

  // --- weight region W: 8M bf16 elems (16 MiB), phase-cycled
  bf16* W = (bf16*)alloc(2 * 8 * M1);
  bf16 *wqT = W, *wkT = W + M1, *wvT = W + 2 * M1, *woT = W + 3 * M1;
  bf16 *pqT = W + 4 * M1, *pkT = W + 5 * M1, *pvT = W + 6 * M1, *l0T = W + 7 * M1;
  bf16 *l1T = W + M1;          // staged after wo-GEMM (wkT dead)
  bf16 *l1c = W;               // staged after pred-GEMM (over wqT)
  bf16 *w1T = W + 4 * M1;      // staged after z0-GEMM (pqT..l0T dead)
  bf16 *w2T = W;               // staged after grads (l1c/l1T dead)
  bf16 *w3T = W + 4 * M1;      // staged after ffn1 (w1T dead)

  // --- 5 activation slots, B0..B3 contiguous (s1 spans them at FFN)
  bf16* B0 = (bf16*)alloc(MB8);  // q -> hn2 -> h1r -> h1 -> (s1)
  bf16* B1 = (bf16*)alloc(MB8);  // k -> qlmm -> pred/dp -> (s1)
  bf16* B2 = (bf16*)alloc(MB8);  // v -> kf -> (s1)
  bf16* B3 = (bf16*)alloc(MB8);  // o -> vf -> dz -> (s1)
  bf16* B4 = (bf16*)alloc(MB8);  // Vt (attn) -> hb -> z0 -> hn3
  bf16* s1 = B0;                 // [NT][F] = 32 MiB
  bf16* VtG = B4;                // [BH][HD][S] per-head transposed V, dead before hb

  // --- smalls
  float* g0b = (float*)alloc(4 * 1024);
  float* g1b = (float*)alloc(4 * 1024);
  float* lossb = (float*)alloc(256);
  int*   flag  = (int*)alloc(256);
  bf16* n1c = (bf16*)alloc(2 * 1024);
  bf16* n2c = (bf16*)alloc(2 * 1024);
  bf16* n3c = (bf16*)alloc(2 * 1024);
  bf16* bqc = (bf16*)alloc(2 * 1024);
  bf16* bkc = (bf16*)alloc(2 * 1024);
  bf16* bvc = (bf16*)alloc(2 * 1024);
  bf16* b0c = (bf16*)alloc(2 * 1024);
  bf16* b1c = (bf16*)alloc(2 * 1024);

  // --- output regions (fp32)
  float* outX = (float*)d_out;                 // hn(bf16 head), then h2 fp32, then final out fp32
  float* outP = outX + ND;                     // new params (l0w,l0b,l1w,l1b)
  float* outM = outP + (2 * DD + 2048);        // new momenta; hosts g0wF/g1wF pre-update
  float* g0wF = outM;                          // [1M] grad l0_w
  float* g1wF = outM + M1 + 1024;              // [1M] grad l1_w
  bf16*  hn   = (bf16*)outX;                   // bf16 hn in first 8 MiB of outX, dead before h2

  const dim3 tb(32, 8);

  hipMemsetAsync(lossb, 0, sizeof(float), stream);
  hipMemsetAsync(g0b, 0, 4 * 1024, stream);
  hipMemsetAsync(g1b, 0, 4 * 1024, stream);
  hipMemsetAsync(outM, 0, (2 * M1 + 2048) * sizeof(float), stream);  // zero g0wF/g1wF for split-K atomics
  k_detect<<<1, 64, 0, stream>>>((const unsigned short*)x, flag);

  // small cvts
  k_cvt<<<1, 256, 0, stream>>>(n1, n1c, 256, flag);
  k_cvt<<<1, 256, 0, stream>>>(n2, n2c, 256, flag);
  k_cvt<<<1, 256, 0, stream>>>(n3, n3c, 256, flag);
  k_cvt<<<1, 256, 0, stream>>>(pqb, bqc, 256, flag);
  k_cvt<<<1, 256, 0, stream>>>(pkb, bkc, 256, flag);
  k_cvt<<<1, 256, 0, stream>>>(pvb, bvc, 256, flag);
  k_cvt<<<1, 256, 0, stream>>>(l0b, b0c, 256, flag);
  k_cvt<<<1, 256, 0, stream>>>(l1b, b1c, 256, flag);

  // phase-1 weight transposes
  k_transpose_dt<<<dim3(32, 32), tb, 0, stream>>>(wq, wqT, Dc, Dc, flag);
  k_transpose_dt<<<dim3(32, 32), tb, 0, stream>>>(wk, wkT, Dc, Dc, flag);
  k_transpose_dt<<<dim3(32, 32), tb, 0, stream>>>(wv, wvT, Dc, Dc, flag);
  k_transpose_dt<<<dim3(32, 32), tb, 0, stream>>>(wo, woT, Dc, Dc, flag);
  k_transpose_dt<<<dim3(32, 32), tb, 0, stream>>>(pqw, pqT, Dc, Mc, flag);
  k_transpose_dt<<<dim3(32, 32), tb, 0, stream>>>(pkw, pkT, Dc, Mc, flag);
  k_transpose_dt<<<dim3(32, 32), tb, 0, stream>>>(pvw, pvT, Dc, Mc, flag);
  k_transpose_dt<<<dim3(32, 32), tb, 0, stream>>>(l0w, l0T, Mc, Mc, flag);

  // ---- attention
  k_rmsnorm_dt<<<NTc, 256, 0, stream>>>(x, n1c, hn, flag);
  k_gemm<EPI_BF16><<<dim3(8, 32), 256, 0, stream>>>(hn, wqT, NTc, Dc, Dc, nullptr, B0, nullptr, nullptr, nullptr, nullptr, nullptr);
  k_gemm<EPI_BF16><<<dim3(8, 32), 256, 0, stream>>>(hn, wkT, NTc, Dc, Dc, nullptr, B1, nullptr, nullptr, nullptr, nullptr, nullptr);
  k_gemm<EPI_BF16><<<dim3(8, 32), 256, 0, stream>>>(hn, wvT, NTc, Dc, Dc, nullptr, B2, nullptr, nullptr, nullptr, nullptr, nullptr);
  k_transpose_v<<<dim3(2, 64, 32), tb, 0, stream>>>(B2, VtG);   // per-head V^T -> B4
  k_rope<<<256, 256, 0, stream>>>(B0, B1);
  k_attn<<<1024, 256, 0, stream>>>(B0, B1, VtG, B3);
  k_gemm<EPI_RESX_BF16><<<dim3(8, 32), 256, 0, stream>>>(B3, woT, NTc, Dc, Dc, nullptr, B4, nullptr, nullptr, nullptr, x, flag);  // hb -> B4
  k_transpose_dt<<<dim3(32, 32), tb, 0, stream>>>(l1w, l1T, Mc, Mc, flag);

  // ---- LMM forward
  k_rmsnorm_b<<<NTc, 256, 0, stream>>>(B4, n2c, B0);   // hn2 -> B0
  k_gemm<EPI_BIAS_BF16><<<dim3(8, 32), 256, 0, stream>>>(B0, pqT, NTc, Mc, Dc, nullptr, B1, bqc, nullptr, nullptr, nullptr, nullptr);  // qlmm
  k_gemm<EPI_BIAS_BF16><<<dim3(8, 32), 256, 0, stream>>>(B0, pkT, NTc, Mc, Dc, nullptr, B2, bkc, nullptr, nullptr, nullptr, nullptr);  // kf
  k_gemm<EPI_BIAS_BF16><<<dim3(8, 32), 256, 0, stream>>>(B0, pvT, NTc, Mc, Dc, nullptr, B3, bvc, nullptr, nullptr, nullptr, nullptr);  // vf
  k_gemm<EPI_BIAS_RELU_BF16><<<dim3(8, 32), 256, 0, stream>>>(B1, l0T, NTc, Mc, Mc, nullptr, B0, b0c, nullptr, nullptr, nullptr, nullptr);  // h1r
  // h2 = h1r@l1T + l1b + hb -> fp32 in outX (overwrites bf16 hn region; hn is dead)
  k_gemm<EPI_BIAS_RESB_F32><<<dim3(8, 32), 256, 0, stream>>>(B0, l1T, NTc, Mc, Mc, outX, nullptr, b1c, B4, nullptr, nullptr, nullptr);

  // ---- LMM loss fwd/bwd
  k_gemm<EPI_BIAS_BF16><<<dim3(8, 32), 256, 0, stream>>>(B2, l0T, NTc, Mc, Mc, nullptr, B4, b0c, nullptr, nullptr, nullptr, nullptr);  // z0 -> B4
  k_transpose_dt<<<dim3(128, 32), tb, 0, stream>>>(fw1, w1T, Dc, Fc, flag);     // stage w1T (pqT..l0T dead)
  k_relu<<<2048, 256, 0, stream>>>(B4, B0);            // h1 -> B0
  k_gemm<EPI_BIAS_BF16><<<dim3(8, 32), 256, 0, stream>>>(B0, l1T, NTc, Mc, Mc, nullptr, B1, b1c, nullptr, nullptr, nullptr, nullptr);  // pred -> B1
  k_cvt<<<1024, 256, 0, stream>>>(l1w, l1c, (int)(DD / 4), flag);
  k_dpred<<<256, 256, 0, stream>>>(B1, B3, lossb);     // dp in-place over pred (1 atomic/block)
  k_gemm<EPI_DZ_BF16><<<dim3(8, 32), 256, 0, stream>>>(B1, l1c, NTc, Mc, Mc, nullptr, B3, nullptr, B4, nullptr, nullptr, nullptr);     // dz -> B3
  k_gemm_tn<<<dim3(8, 8, 8), 256, 0, stream>>>(B0, B1, NTc, g1wF);   // g1w = h1^T dp (split-K atomic)
  k_gemm_tn<<<dim3(8, 8, 8), 256, 0, stream>>>(B2, B3, NTc, g0wF);   // g0w = kf^T dz (split-K atomic)
  k_colsum<<<dim3(4, 32), 256, 0, stream>>>(B1, g1b, Mc, NTc / 32);
  k_colsum<<<dim3(4, 32), 256, 0, stream>>>(B3, g0b, Mc, NTc / 32);
  k_update_dt<<<8200, 256, 0, stream>>>(l0w, l0b, l1w, l1b, m0w, m0b, m1w, m1b,
                                        g0wF, g0b, g1wF, g1b, lossb, flag, outP, outM);

  // ---- FFN (all B-slots free; h2 fp32 in outX)
  k_transpose_dt<<<dim3(128, 32), tb, 0, stream>>>(fw2, w2T, Dc, Fc, flag);     // stage w2T (l1c/l1T dead)
  k_rmsnorm_f<<<NTc, 256, 0, stream>>>(outX, n3c, B4); // hn3 -> B4
  k_gemm<EPI_BF16><<<dim3(32, 32), 256, 0, stream>>>(B4, w1T, NTc, Fc, Dc, nullptr, s1, nullptr, nullptr, nullptr, nullptr, nullptr);
  k_transpose_dt<<<dim3(32, 128), tb, 0, stream>>>(fw3, w3T, Fc, Dc, flag);     // stage w3T (w1T dead)
  k_gemm<EPI_SILU_BF16><<<dim3(32, 32), 256, 0, stream>>>(B4, w2T, NTc, Fc, Dc, nullptr, s1, nullptr, s1, nullptr, nullptr, nullptr);
  // out = s1@w3T + h2  (fp32 in-place over outX)
  k_gemm<EPI_RESF_F32><<<dim3(8, 32), 256, 0, stream>>>(s1, w3T, NTc, Dc, Fc, outX, nullptr, nullptr, nullptr, outX, nullptr, nullptr);
}

// Round 2
// 1091.177 us; speedup vs baseline: 1.0239x; 1.0239x over previous
//
#include <hip/hip_runtime.h>
#include <cstdint>
#include <cstddef>

typedef __bf16 bf16;
typedef __bf16 bf16x2 __attribute__((ext_vector_type(2)));
typedef __bf16 bf16x4 __attribute__((ext_vector_type(4)));
typedef __bf16 bf16x8 __attribute__((ext_vector_type(8)));
typedef float  f32x4  __attribute__((ext_vector_type(4)));
typedef __attribute__((address_space(1))) unsigned int u32_g;
typedef __attribute__((address_space(3))) unsigned int u32_l;

#define DI __device__ __forceinline__

constexpr int Bc = 2, Sc = 2048, Dc = 1024, Hc = 16, HDc = 64, Fc = 4096, Mc = 1024;
constexpr int NTc = Bc * Sc;  // 4096 tokens

DI void llds16(const bf16* g, bf16* l) {
  __builtin_amdgcn_global_load_lds((const u32_g*)g, (u32_l*)l, 16, 0, 0);
}
DI f32x4 cvt4(bf16x4 a) {
  f32x4 r; r[0] = (float)a[0]; r[1] = (float)a[1]; r[2] = (float)a[2]; r[3] = (float)a[3];
  return r;
}

// ---------------------------------------------------------------- dtype detector (inputs)
__global__ void k_detect(const unsigned short* __restrict__ x, int* __restrict__ flag)
{
  const int tid = threadIdx.x;  // 64
  int cnt = 0;
#pragma unroll
  for (int i = 0; i < 8; i++) {
    unsigned short h = x[tid * 8 + i];
    int e = (h >> 7) & 0xFF;
    if (e < 96 || e > 160) cnt++;
  }
#pragma unroll
  for (int off = 32; off > 0; off >>= 1) cnt += __shfl_down(cnt, off, 64);
  if (tid == 0) *flag = (cnt > 32) ? 1 : 0;
}

// ---------------------------------------------------------------- dtype-aware convert to bf16
__global__ __launch_bounds__(256)
void k_cvt(const void* __restrict__ src, bf16* __restrict__ dst, int n4, const int* __restrict__ flag)
{
  int i = blockIdx.x * 256 + threadIdx.x;
  if (i >= n4) return;
  bf16x4 o;
  if (*flag) {
    f32x4 v = ((const f32x4*)src)[i];
    o[0] = (bf16)v[0]; o[1] = (bf16)v[1]; o[2] = (bf16)v[2]; o[3] = (bf16)v[3];
  } else {
    o = ((const bf16x4*)src)[i];
  }
  ((bf16x4*)dst)[i] = o;
}

// ---------------------------------------------------------------- dtype-aware transpose [R][C] -> bf16 [C][R]
__global__ void k_transpose_dt(const void* __restrict__ src, bf16* __restrict__ dst,
                               int R, int C, const int* __restrict__ flag)
{
  __shared__ bf16 tile[32][33];
  const int c0 = blockIdx.x * 32, r0 = blockIdx.y * 32;
  const int tx = threadIdx.x, ty = threadIdx.y;
  const bool f32 = (*flag != 0);
  for (int i = ty; i < 32; i += 8) {
    size_t idx = (size_t)(r0 + i) * C + (c0 + tx);
    tile[i][tx] = f32 ? (bf16)((const float*)src)[idx] : ((const bf16*)src)[idx];
  }
  __syncthreads();
  for (int i = ty; i < 32; i += 8)
    dst[(size_t)(c0 + i) * R + (r0 + tx)] = tile[tx][i];
}

// ---------------------------------------------------------------- per-head V transpose: v[(b*S+s)][h*64+d] -> vt[(bh*64+d)][s]
__global__ void k_transpose_v(const bf16* __restrict__ v, bf16* __restrict__ vt)
{
  __shared__ bf16 tile[32][33];
  const int d0 = blockIdx.x * 32, s0 = blockIdx.y * 32;
  const int bh = blockIdx.z;
  const int b = bh >> 4, hh = bh & 15;
  const int tx = threadIdx.x, ty = threadIdx.y;
  for (int i = ty; i < 32; i += 8)
    tile[i][tx] = v[((size_t)(b * Sc + s0 + i)) * Dc + hh * HDc + d0 + tx];
  __syncthreads();
  for (int i = ty; i < 32; i += 8)
    vt[((size_t)(bh * HDc + d0 + i)) * Sc + s0 + tx] = tile[tx][i];
}

// ---------------------------------------------------------------- GEMM (NT): C[M][N] = A[M][K] * Bt[N][K]^T
enum EpiMode { EPI_BF16 = 0, EPI_BIAS_BF16, EPI_BIAS_RELU_BF16, EPI_BIAS_RESB_F32,
               EPI_SILU_BF16, EPI_DZ_BF16, EPI_RESX_BF16, EPI_RESF_F32 };

template <int EPI>
__global__ __launch_bounds__(256)
void k_gemm(const bf16* __restrict__ A, const bf16* __restrict__ Bt,
            int Mr, int Nr, int Kr,
            float* outF, bf16* outB,
            const bf16* __restrict__ bias, const bf16* auxB,
            const float* resF,
            const void* __restrict__ resX, const int* __restrict__ flag)
{
  __shared__ bf16 As[128 * 32];
  __shared__ bf16 Bs[128 * 32];
  const int tid = threadIdx.x;
  const int w = tid >> 6, l = tid & 63;
  const int wr = w >> 1, wc = w & 1;
  const int row0 = blockIdx.y * 128, col0 = blockIdx.x * 128;

  const f32x4 vzero = {0.f, 0.f, 0.f, 0.f};
  f32x4 acc[4][4];
#pragma unroll
  for (int i = 0; i < 4; i++)
#pragma unroll
    for (int j = 0; j < 4; j++) acc[i][j] = vzero;

  const bf16* Ag = A + (size_t)(row0 + w * 16 + (l >> 2)) * Kr + ((l & 3) << 3);
  const bf16* Bg = Bt + (size_t)(col0 + w * 16 + (l >> 2)) * Kr + ((l & 3) << 3);
  bf16* AsW = &As[w * 512];
  bf16* BsW = &Bs[w * 512];
  const size_t rowHop = (size_t)64 * Kr;

  for (int k0 = 0; k0 < Kr; k0 += 32) {
    __syncthreads();
    llds16(Ag + k0, AsW);
    llds16(Ag + rowHop + k0, AsW + 2048);
    llds16(Bg + k0, BsW);
    llds16(Bg + rowHop + k0, BsW + 2048);
    __syncthreads();
    bf16x8 af[4], bfr[4];
#pragma unroll
    for (int mt = 0; mt < 4; mt++)
      af[mt] = *(const bf16x8*)&As[(wr * 64 + mt * 16 + (l & 15)) * 32 + (l >> 4) * 8];
#pragma unroll
    for (int nt = 0; nt < 4; nt++)
      bfr[nt] = *(const bf16x8*)&Bs[(wc * 64 + nt * 16 + (l & 15)) * 32 + (l >> 4) * 8];
#pragma unroll
    for (int mt = 0; mt < 4; mt++)
#pragma unroll
      for (int nt = 0; nt < 4; nt++)
        acc[mt][nt] = __builtin_amdgcn_mfma_f32_16x16x32_bf16(af[mt], bfr[nt], acc[mt][nt], 0, 0, 0);
  }

  const bool f32res = (EPI == EPI_RESX_BF16) ? (*flag != 0) : false;
  float biasv[4];
  if (EPI == EPI_BIAS_BF16 || EPI == EPI_BIAS_RELU_BF16 || EPI == EPI_BIAS_RESB_F32) {
#pragma unroll
    for (int nt = 0; nt < 4; nt++)
      biasv[nt] = (float)bias[col0 + wc * 64 + nt * 16 + (l & 15)];
  }
  // C/D layout (verified m89/m91): col = lane&15, row = (lane>>4)*4 + reg
#pragma unroll
  for (int mt = 0; mt < 4; mt++) {
    const int rowb = row0 + wr * 64 + mt * 16 + ((l >> 4) << 2);
    float av[4][4];
    if (EPI == EPI_SILU_BF16 || EPI == EPI_DZ_BF16 || EPI == EPI_BIAS_RESB_F32) {
#pragma unroll
      for (int nt = 0; nt < 4; nt++) {
        const int col = col0 + wc * 64 + nt * 16 + (l & 15);
#pragma unroll
        for (int r = 0; r < 4; r++)
          av[nt][r] = (float)auxB[(size_t)(rowb + r) * Nr + col];
      }
    }
    if (EPI == EPI_RESF_F32) {
#pragma unroll
      for (int nt = 0; nt < 4; nt++) {
        const int col = col0 + wc * 64 + nt * 16 + (l & 15);
#pragma unroll
        for (int r = 0; r < 4; r++)
          av[nt][r] = resF[(size_t)(rowb + r) * Nr + col];
      }
    }
    if (EPI == EPI_RESX_BF16) {
#pragma unroll
      for (int nt = 0; nt < 4; nt++) {
        const int col = col0 + wc * 64 + nt * 16 + (l & 15);
#pragma unroll
        for (int r = 0; r < 4; r++) {
          const size_t idx = (size_t)(rowb + r) * Nr + col;
          av[nt][r] = f32res ? ((const float*)resX)[idx] : (float)((const bf16*)resX)[idx];
        }
      }
    }
#pragma unroll
    for (int nt = 0; nt < 4; nt++) {
      const int col = col0 + wc * 64 + nt * 16 + (l & 15);
#pragma unroll
      for (int r = 0; r < 4; r++) {
        const size_t idx = (size_t)(rowb + r) * Nr + col;
        float v = acc[mt][nt][r];
        if (EPI == EPI_BF16) { outB[idx] = (bf16)v; }
        else if (EPI == EPI_BIAS_BF16) { outB[idx] = (bf16)(v + biasv[nt]); }
        else if (EPI == EPI_BIAS_RELU_BF16) { outB[idx] = (bf16)fmaxf(v + biasv[nt], 0.f); }
        else if (EPI == EPI_BIAS_RESB_F32) { outF[idx] = v + biasv[nt] + av[nt][r]; }
        else if (EPI == EPI_SILU_BF16) {
          float s1v = av[nt][r];
          float sl = s1v / (1.f + __expf(-s1v));
          outB[idx] = (bf16)(sl * v);
        }
        else if (EPI == EPI_DZ_BF16) { outB[idx] = (bf16)(av[nt][r] > 0.f ? v : 0.f); }
        else if (EPI == EPI_RESX_BF16) { outB[idx] = (bf16)(v + av[nt][r]); }
        else if (EPI == EPI_RESF_F32) { outF[idx] = v + av[nt][r]; }
      }
    }
  }
}

// ---------------------------------------------------------------- GEMM (TN) split-K: C[i][j] += sum_t X[t][i]*Y[t][j]
__global__ __launch_bounds__(256)
void k_gemm_tn(const bf16* __restrict__ X, const bf16* __restrict__ Y, int Kt,
               float* __restrict__ out)
{
  __shared__ bf16 As[128 * 36];
  __shared__ bf16 Bs[128 * 36];
  const int tid = threadIdx.x;
  const int w = tid >> 6, l = tid & 63;
  const int wr = w >> 1, wc = w & 1;
  const int row0 = blockIdx.y * 128, col0 = blockIdx.x * 128;
  const int iofs = (tid & 15) * 8;   // 0..120
  const int tp   = (tid >> 4) * 2;   // 0..30

  const f32x4 vzero = {0.f, 0.f, 0.f, 0.f};
  f32x4 acc[4][4];
#pragma unroll
  for (int i = 0; i < 4; i++)
#pragma unroll
    for (int j = 0; j < 4; j++) acc[i][j] = vzero;

  const int chunk = Kt / gridDim.z;
  const int tbeg = blockIdx.z * chunk;

  for (int t0 = tbeg; t0 < tbeg + chunk; t0 += 32) {
    __syncthreads();
    bf16x8 a0 = *(const bf16x8*)&X[(size_t)(t0 + tp) * 1024 + row0 + iofs];
    bf16x8 a1 = *(const bf16x8*)&X[(size_t)(t0 + tp + 1) * 1024 + row0 + iofs];
    bf16x8 b0 = *(const bf16x8*)&Y[(size_t)(t0 + tp) * 1024 + col0 + iofs];
    bf16x8 b1 = *(const bf16x8*)&Y[(size_t)(t0 + tp + 1) * 1024 + col0 + iofs];
#pragma unroll
    for (int e = 0; e < 8; e++) {
      bf16x2 pa; pa[0] = a0[e]; pa[1] = a1[e];
      bf16x2 pb; pb[0] = b0[e]; pb[1] = b1[e];
      *(bf16x2*)&As[(iofs + e) * 36 + tp] = pa;
      *(bf16x2*)&Bs[(iofs + e) * 36 + tp] = pb;
    }
    __syncthreads();
    bf16x8 af[4], bfr[4];
#pragma unroll
    for (int mt = 0; mt < 4; mt++) {
      const int base = (wr * 64 + mt * 16 + (l & 15)) * 36 + (l >> 4) * 8;
      bf16x4 lo = *(const bf16x4*)&As[base];
      bf16x4 hi = *(const bf16x4*)&As[base + 4];
#pragma unroll
      for (int e = 0; e < 4; e++) { af[mt][e] = lo[e]; af[mt][4 + e] = hi[e]; }
    }
#pragma unroll
    for (int nt = 0; nt < 4; nt++) {
      const int base = (wc * 64 + nt * 16 + (l & 15)) * 36 + (l >> 4) * 8;
      bf16x4 lo = *(const bf16x4*)&Bs[base];
      bf16x4 hi = *(const bf16x4*)&Bs[base + 4];
#pragma unroll
      for (int e = 0; e < 4; e++) { bfr[nt][e] = lo[e]; bfr[nt][4 + e] = hi[e]; }
    }
#pragma unroll
    for (int mt = 0; mt < 4; mt++)
#pragma unroll
      for (int nt = 0; nt < 4; nt++)
        acc[mt][nt] = __builtin_amdgcn_mfma_f32_16x16x32_bf16(af[mt], bfr[nt], acc[mt][nt], 0, 0, 0);
  }

#pragma unroll
  for (int mt = 0; mt < 4; mt++) {
    const int rowb = row0 + wr * 64 + mt * 16 + ((l >> 4) << 2);
#pragma unroll
    for (int nt = 0; nt < 4; nt++) {
      const int col = col0 + wc * 64 + nt * 16 + (l & 15);
#pragma unroll
      for (int r = 0; r < 4; r++)
        atomicAdd(&out[(size_t)(rowb + r) * 1024 + col], acc[mt][nt][r]);
    }
  }
}

// ---------------------------------------------------------------- RMSNorm variants
__global__ __launch_bounds__(256)
void k_rmsnorm_dt(const void* __restrict__ x, const bf16* __restrict__ w, bf16* __restrict__ out,
                  const int* __restrict__ flag)
{
  const int row = blockIdx.x;
  const int tid = threadIdx.x;
  f32x4 xv;
  if (*flag) xv = *(const f32x4*)((const float*)x + (size_t)row * Dc + tid * 4);
  else       xv = cvt4(*(const bf16x4*)((const bf16*)x + (size_t)row * Dc + tid * 4));
  float ss = xv[0] * xv[0] + xv[1] * xv[1] + xv[2] * xv[2] + xv[3] * xv[3];
#pragma unroll
  for (int off = 32; off > 0; off >>= 1) ss += __shfl_down(ss, off, 64);
  __shared__ float part[4];
  if ((tid & 63) == 0) part[tid >> 6] = ss;
  __syncthreads();
  float tot = part[0] + part[1] + part[2] + part[3];
  float inv = 1.f / (sqrtf(tot) * 0.03125f + 1e-8f);
  bf16x4 wb = *(const bf16x4*)(w + tid * 4);
  bf16x4 ov;
  ov[0] = (bf16)((float)wb[0] * xv[0] * inv);
  ov[1] = (bf16)((float)wb[1] * xv[1] * inv);
  ov[2] = (bf16)((float)wb[2] * xv[2] * inv);
  ov[3] = (bf16)((float)wb[3] * xv[3] * inv);
  *(bf16x4*)(out + (size_t)row * Dc + tid * 4) = ov;
}

__global__ __launch_bounds__(256)
void k_rmsnorm_b(const bf16* __restrict__ x, const bf16* __restrict__ w, bf16* __restrict__ out)
{
  const int row = blockIdx.x;
  const int tid = threadIdx.x;
  f32x4 xv = cvt4(*(const bf16x4*)(x + (size_t)row * Dc + tid * 4));
  float ss = xv[0] * xv[0] + xv[1] * xv[1] + xv[2] * xv[2] + xv[3] * xv[3];
#pragma unroll
  for (int off = 32; off > 0; off >>= 1) ss += __shfl_down(ss, off, 64);
  __shared__ float part[4];
  if ((tid & 63) == 0) part[tid >> 6] = ss;
  __syncthreads();
  float tot = part[0] + part[1] + part[2] + part[3];
  float inv = 1.f / (sqrtf(tot) * 0.03125f + 1e-8f);
  bf16x4 wb = *(const bf16x4*)(w + tid * 4);
  bf16x4 ov;
  ov[0] = (bf16)((float)wb[0] * xv[0] * inv);
  ov[1] = (bf16)((float)wb[1] * xv[1] * inv);
  ov[2] = (bf16)((float)wb[2] * xv[2] * inv);
  ov[3] = (bf16)((float)wb[3] * xv[3] * inv);
  *(bf16x4*)(out + (size_t)row * Dc + tid * 4) = ov;
}

__global__ __launch_bounds__(256)
void k_rmsnorm_f(const float* __restrict__ x, const bf16* __restrict__ w, bf16* __restrict__ out)
{
  const int row = blockIdx.x;
  const int tid = threadIdx.x;
  f32x4 xv = *(const f32x4*)(x + (size_t)row * Dc + tid * 4);
  float ss = xv[0] * xv[0] + xv[1] * xv[1] + xv[2] * xv[2] + xv[3] * xv[3];
#pragma unroll
  for (int off = 32; off > 0; off >>= 1) ss += __shfl_down(ss, off, 64);
  __shared__ float part[4];
  if ((tid & 63) == 0) part[tid >> 6] = ss;
  __syncthreads();
  float tot = part[0] + part[1] + part[2] + part[3];
  float inv = 1.f / (sqrtf(tot) * 0.03125f + 1e-8f);
  bf16x4 wb = *(const bf16x4*)(w + tid * 4);
  bf16x4 ov;
  ov[0] = (bf16)((float)wb[0] * xv[0] * inv);
  ov[1] = (bf16)((float)wb[1] * xv[1] * inv);
  ov[2] = (bf16)((float)wb[2] * xv[2] * inv);
  ov[3] = (bf16)((float)wb[3] * xv[3] * inv);
  *(bf16x4*)(out + (size_t)row * Dc + tid * 4) = ov;
}

// ---------------------------------------------------------------- RoPE in-place on bf16 q,k
__global__ __launch_bounds__(256)
void k_rope(bf16* __restrict__ q, bf16* __restrict__ kx)
{
  const int idx = blockIdx.x * 256 + threadIdx.x;  // NT*H = 65536
  const int t = idx >> 4, hh = idx & 15;
  const int s = t & (Sc - 1);
  float sn[32], cs[32];
#pragma unroll
  for (int i = 0; i < 32; i++) {
    float f = expf(-(float)i * 0.28782313662425574f);  // ln(10000)/32
    float ang = (float)s * f;
    sn[i] = sinf(ang);
    cs[i] = cosf(ang);
  }
  for (int pass = 0; pass < 2; pass++) {
    bf16* p = (pass ? kx : q) + (size_t)t * Dc + hh * HDc;
    float xb[64], ob[64];
#pragma unroll
    for (int j = 0; j < 16; j++) *(f32x4*)&xb[j * 4] = cvt4(*(const bf16x4*)(p + j * 4));
#pragma unroll
    for (int i = 0; i < 32; i++) {
      float x1 = xb[2 * i], x2 = xb[2 * i + 1];
      ob[i] = x1 * cs[i] - x2 * sn[i];
      ob[32 + i] = x1 * sn[i] + x2 * cs[i];
    }
#pragma unroll
    for (int j = 0; j < 16; j++) {
      bf16x4 o4;
      o4[0] = (bf16)ob[j * 4]; o4[1] = (bf16)ob[j * 4 + 1];
      o4[2] = (bf16)ob[j * 4 + 2]; o4[3] = (bf16)ob[j * 4 + 3];
      *(bf16x4*)(p + j * 4) = o4;
    }
  }
}

// ---------------------------------------------------------------- MFMA flash attention, KV-split across waves
// R1 counters (160us): MfmaUtil 4.4, VALUBusy 19, occ 26, hbm 1.6% -> pure
// latency x serial-depth bound (qt=31 block = 32 serial online-softmax iters,
// grid 1024 = no refill). Fix: block = 16 q-rows (grid 4096, LPT+XCD swizzle);
// 4 waves split the kv-tile loop mod 4 with private (m,l,oacc); one-barrier
// LDS merge at the end. Serial depth 32 -> 8; 2 rounds of 8 blocks/CU.
__global__ __launch_bounds__(256)
void k_attn(const bf16* __restrict__ q, const bf16* __restrict__ kx,
            const bf16* __restrict__ vt, bf16* __restrict__ o)
{
  constexpr int PAD = 72;
  // smem shared between per-wave Ps (loop phase, 9216B) and merge buffer
  // (3 waves x 64 lanes x 25 floats = 19200B); phases separated by barrier.
  __shared__ __align__(16) char smem[19456];

  const int blk = blockIdx.x;
  const int qi = 127 - (blk >> 5);     // heavy q-tiles dispatch first (LPT)
  const int bh = blk & 31;             // same head -> same XCD residue
  const int b = bh >> 4, hh = bh & 15;
  const int tid = threadIdx.x;
  const int w = tid >> 6, l = tid & 63;
  const int quad = l >> 4, c = l & 15;

  bf16* Psw = (bf16*)smem + w * 16 * PAD;
  float* Buf = (float*)smem;

  const int qrow = qi * 16 + c;
  const size_t qbase = ((size_t)(b * Sc + qrow)) * Dc + hh * HDc;
  bf16x8 qf0 = *(const bf16x8*)(q + qbase + quad * 8);
  bf16x8 qf1 = *(const bf16x8*)(q + qbase + 32 + quad * 8);
#pragma unroll
  for (int j = 0; j < 8; j++) {
    qf0[j] = (bf16)((float)qf0[j] * 0.125f);
    qf1[j] = (bf16)((float)qf1[j] * 0.125f);
  }

  const f32x4 vzero = {0.f, 0.f, 0.f, 0.f};
  f32x4 oacc[4];
#pragma unroll
  for (int nt = 0; nt < 4; nt++) oacc[nt] = vzero;
  float mrun[4] = {-3.0e38f, -3.0e38f, -3.0e38f, -3.0e38f};
  float lrun[4] = {0.f, 0.f, 0.f, 0.f};

  const int qrow0 = qi * 16 + quad * 4;
  const int ntiles = (qi >> 2) + 1;    // 64-wide kv tiles covering 0..qi*16+15

  const bf16* kb = kx + (size_t)b * Sc * Dc + hh * HDc;   // + krow*Dc
  const bf16* vb = vt + (size_t)bh * HDc * Sc;            // + d*Sc + kk

  for (int t0 = w; t0 < ntiles; t0 += 4) {
    const int kk0 = t0 * 64;

    // QK^T: B-fragments straight from global K (row-major, 8 contiguous bf16/lane)
    f32x4 sf[4];
#pragma unroll
    for (int nt = 0; nt < 4; nt++) {
      const bf16* kr = kb + (size_t)(kk0 + nt * 16 + c) * Dc + quad * 8;
      bf16x8 k0 = *(const bf16x8*)kr;
      bf16x8 k1 = *(const bf16x8*)(kr + 32);
      f32x4 a = vzero;
      a = __builtin_amdgcn_mfma_f32_16x16x32_bf16(qf0, k0, a, 0, 0, 0);
      a = __builtin_amdgcn_mfma_f32_16x16x32_bf16(qf1, k1, a, 0, 0, 0);
      sf[nt] = a;
    }
    if (t0 == ntiles - 1) {            // diagonal tile: causal mask
#pragma unroll
      for (int nt = 0; nt < 4; nt++)
#pragma unroll
        for (int r = 0; r < 4; r++)
          if (kk0 + nt * 16 + c > qrow0 + r) sf[nt][r] = -3.0e38f;
    }

    float mnew[4], alpha[4];
#pragma unroll
    for (int r = 0; r < 4; r++) {
      float mt = fmaxf(fmaxf(sf[0][r], sf[1][r]), fmaxf(sf[2][r], sf[3][r]));
      mt = fmaxf(mt, __shfl_xor(mt, 1, 64));
      mt = fmaxf(mt, __shfl_xor(mt, 2, 64));
      mt = fmaxf(mt, __shfl_xor(mt, 4, 64));
      mt = fmaxf(mt, __shfl_xor(mt, 8, 64));
      mnew[r] = fmaxf(mrun[r], mt);
      alpha[r] = __expf(mrun[r] - mnew[r]);
      mrun[r] = mnew[r];
    }
    float ps[4] = {0.f, 0.f, 0.f, 0.f};
#pragma unroll
    for (int nt = 0; nt < 4; nt++)
#pragma unroll
      for (int r = 0; r < 4; r++) {
        float p = __expf(sf[nt][r] - mnew[r]);
        sf[nt][r] = p;
        ps[r] += p;
      }
#pragma unroll
    for (int r = 0; r < 4; r++) {
      ps[r] += __shfl_xor(ps[r], 1, 64);
      ps[r] += __shfl_xor(ps[r], 2, 64);
      ps[r] += __shfl_xor(ps[r], 4, 64);
      ps[r] += __shfl_xor(ps[r], 8, 64);
      lrun[r] = lrun[r] * alpha[r] + ps[r];
    }
#pragma unroll
    for (int nt = 0; nt < 4; nt++)
#pragma unroll
      for (int r = 0; r < 4; r++) oacc[nt][r] *= alpha[r];

    // P layout shuffle through per-wave LDS (wave-internal: no barrier needed)
#pragma unroll
    for (int nt = 0; nt < 4; nt++)
#pragma unroll
      for (int r = 0; r < 4; r++)
        Psw[(quad * 4 + r) * PAD + nt * 16 + c] = (bf16)sf[nt][r];
    bf16x8 pa0 = *(const bf16x8*)&Psw[c * PAD + quad * 8];
    bf16x8 pa1 = *(const bf16x8*)&Psw[c * PAD + 32 + quad * 8];

    // PV: B-fragments from pre-transposed global Vt (8 contiguous bf16/lane)
#pragma unroll
    for (int nt = 0; nt < 4; nt++) {
      const bf16* vr = vb + (size_t)(nt * 16 + c) * Sc + kk0 + quad * 8;
      bf16x8 v0 = *(const bf16x8*)vr;
      bf16x8 v1 = *(const bf16x8*)(vr + 32);
      oacc[nt] = __builtin_amdgcn_mfma_f32_16x16x32_bf16(pa0, v0, oacc[nt], 0, 0, 0);
      oacc[nt] = __builtin_amdgcn_mfma_f32_16x16x32_bf16(pa1, v1, oacc[nt], 0, 0, 0);
    }
  }

  // ---- cross-wave online-softmax merge (waves 1..3 -> wave 0)
  __syncthreads();                      // Ps phase done everywhere
  if (w > 0) {
    float* dst = Buf + ((w - 1) * 64 + l) * 25;   // stride 25 dwords: conflict-free
#pragma unroll
    for (int nt = 0; nt < 4; nt++)
#pragma unroll
      for (int r = 0; r < 4; r++) dst[nt * 4 + r] = oacc[nt][r];
#pragma unroll
    for (int r = 0; r < 4; r++) { dst[16 + r] = mrun[r]; dst[20 + r] = lrun[r]; }
  }
  __syncthreads();
  if (w == 0) {
#pragma unroll
    for (int w2 = 0; w2 < 3; w2++) {
      const float* src = Buf + (w2 * 64 + l) * 25;
      float m2[4], l2[4];
#pragma unroll
      for (int r = 0; r < 4; r++) { m2[r] = src[16 + r]; l2[r] = src[20 + r]; }
#pragma unroll
      for (int r = 0; r < 4; r++) {
        float mn = fmaxf(mrun[r], m2[r]);
        float a = __expf(mrun[r] - mn);
        float bb = __expf(m2[r] - mn);
        lrun[r] = lrun[r] * a + l2[r] * bb;
        mrun[r] = mn;
#pragma unroll
        for (int nt = 0; nt < 4; nt++)
          oacc[nt][r] = oacc[nt][r] * a + src[nt * 4 + r] * bb;
      }
    }
    float inv[4];
#pragma unroll
    for (int r = 0; r < 4; r++) inv[r] = 1.f / lrun[r];
#pragma unroll
    for (int r = 0; r < 4; r++) {
      const size_t obase = ((size_t)(b * Sc + qrow0 + r)) * Dc + hh * HDc;
#pragma unroll
      for (int nt = 0; nt < 4; nt++)
        o[obase + nt * 16 + c] = (bf16)(oacc[nt][r] * inv[r]);
    }
  }
}

// ---------------------------------------------------------------- elementwise relu (x8)
__global__ __launch_bounds__(256)
void k_relu(const bf16* __restrict__ src, bf16* __restrict__ dst)
{
  int i = blockIdx.x * 256 + threadIdx.x;  // n/8 threads
  bf16x8 v = ((const bf16x8*)src)[i];
  bf16x8 o;
#pragma unroll
  for (int e = 0; e < 8; e++) o[e] = ((float)v[e] > 0.f) ? v[e] : (bf16)0.f;
  ((bf16x8*)dst)[i] = o;
}

// ---------------------------------------------------------------- dp = 2(pred-vf)/M in-place + loss
__global__ __launch_bounds__(256)
void k_dpred(bf16* __restrict__ predDp, const bf16* __restrict__ vf, float* __restrict__ loss)
{
  __shared__ float red[4];
  const int tid = threadIdx.x;
  const size_t n8 = (size_t)NTc * Mc / 8;
  float lacc = 0.f;
  for (size_t i = (size_t)blockIdx.x * 256 + tid; i < n8; i += (size_t)gridDim.x * 256) {
    bf16x8 p8 = ((const bf16x8*)predDp)[i];
    bf16x8 v8 = ((const bf16x8*)vf)[i];
    bf16x8 d8;
#pragma unroll
    for (int e = 0; e < 8; e++) {
      float df = (float)p8[e] - (float)v8[e];
      lacc += df * df;
      d8[e] = (bf16)(df * (2.0f / 1024.0f));
    }
    ((bf16x8*)predDp)[i] = d8;
  }
#pragma unroll
  for (int off = 32; off > 0; off >>= 1) lacc += __shfl_down(lacc, off, 64);
  if ((tid & 63) == 0) red[tid >> 6] = lacc;
  __syncthreads();
  if (tid == 0) atomicAdd(loss, red[0] + red[1] + red[2] + red[3]);
}

// ---------------------------------------------------------------- colsum: out[c] += sum over a row chunk
__global__ __launch_bounds__(256)
void k_colsum(const bf16* __restrict__ X, float* __restrict__ out, int C, int rowsPer)
{
  int c = blockIdx.x * 256 + threadIdx.x;
  int r0 = blockIdx.y * rowsPer;
  float s = 0.f;
#pragma unroll 8
  for (int r = r0; r < r0 + rowsPer; r++) s += (float)X[(size_t)r * C + c];
  atomicAdd(&out[c], s);
}

// ---------------------------------------------------------------- dtype-aware param/momentum update -> fp32 d_out
__global__ __launch_bounds__(256)
void k_update_dt(const void* __restrict__ p0w, const void* __restrict__ p0b,
                 const void* __restrict__ p1w, const void* __restrict__ p1b,
                 const void* __restrict__ m0w, const void* __restrict__ m0b,
                 const void* __restrict__ m1w, const void* __restrict__ m1b,
                 const float* __restrict__ g0wF, const float* __restrict__ g0b,
                 const float* __restrict__ g1wF, const float* __restrict__ g1b,
                 const float* __restrict__ loss, const int* __restrict__ flag,
                 float* __restrict__ outP, float* __restrict__ outM)
{
  const int i = blockIdx.x * 256 + threadIdx.x;  // < 2099200 exactly
  const bool upd = (loss[0] >= 0.1f * 1024.f * 4096.f);  // avg_loss >= THRESH
  const bool f32 = (*flag != 0);
  constexpr int W = 1024 * 1024;
  const void *pp, *pm; int j; float g;
  if (i < W) { pp = p0w; pm = m0w; j = i; g = g0wF[i]; }
  else if (i < W + 1024) { j = i - W; pp = p0b; pm = m0b; g = g0b[j]; }
  else if (i < 2 * W + 1024) { j = i - W - 1024; pp = p1w; pm = m1w; g = g1wF[j]; }
  else { j = i - 2 * W - 1024; pp = p1b; pm = m1b; g = g1b[j]; }
  float p = f32 ? ((const float*)pp)[j] : (float)((const bf16*)pp)[j];
  float m = f32 ? ((const float*)pm)[j] : (float)((const bf16*)pm)[j];
  float nm = 0.9f * m - 0.01f * g;
  float np = 0.99f * p + nm;
  outP[i] = upd ? np : p;
  outM[i] = upd ? nm : m;
}

// ================================================================ host
extern "C" void kernel_launch(void* const* d_in, const int* in_sizes, int n_in,
                              void* d_out, int out_size, void* d_ws, size_t ws_size,
                              hipStream_t stream)
{
  (void)in_sizes; (void)n_in; (void)out_size; (void)ws_size;
  const void* x   = d_in[0];
  const void* wq  = d_in[2];
  const void* wk  = d_in[3];
  const void* wv  = d_in[4];
  const void* wo  = d_in[5];
  const void* n1  = d_in[6];
  const void* n2  = d_in[7];
  const void* n3  = d_in[8];
  const void* fw1 = d_in[9];
  const void* fw2 = d_in[10];
  const void* fw3 = d_in[11];
  const void* pkw = d_in[12];
  const void* pkb = d_in[13];
  const void* pvw = d_in[14];
  const void* pvb = d_in[15];
  const void* pqw = d_in[16];
  const void* pqb = d_in[17];
  const void* l0w = d_in[18];
  const void* l0b = d_in[19];
  const void* l1w = d_in[20];
  const void* l1b = d_in[21];
  const void* m0w = d_in[22];
  const void* m0b = d_in[23];
  const void* m1w = d_in[24];
  const void* m1b = d_in[25];

  char* ws = (char*)d_ws;
  size_t off = 0;
  auto alloc = [&](size_t bytes) -> char* {
    char* p = ws + off;
    off += (bytes + 255) & ~(size_t)255;
    return p;
  };

  const size_t DD = (size_t)Dc * Dc;   // 1M elems
  const size_t ND = (size_t)NTc * Dc;  // 4M elems
  const size_t MB8 = 2 * ND;           // 8 MiB
  const size_t M1 = DD;                // 1M elems

  // --- weight region W: 8M bf16 elems (16 MiB), phase-cycled
  bf16* W = (bf16*)alloc(2 * 8 * M1);
  bf16 *wqT = W, *wkT = W + M1, *wvT = W + 2 * M1, *woT = W + 3 * M1;
  bf16 *pqT = W + 4 * M1, *pkT = W + 5 * M1, *pvT = W + 6 * M1, *l0T = W + 7 * M1;
  bf16 *l1T = W + M1;          // staged after wo-GEMM (wkT dead)
  bf16 *l1c = W;               // staged after pred-GEMM (over wqT)
  bf16 *w1T = W + 4 * M1;      // staged after z0-GEMM (pqT..l0T dead)
  bf16 *w2T = W;               // staged after grads (l1c/l1T dead)
  bf16 *w3T = W + 4 * M1;      // staged after ffn1 (w1T dead)

  // --- 5 activation slots, B0..B3 contiguous (s1 spans them at FFN)
  bf16* B0 = (bf16*)alloc(MB8);  // q -> hn2 -> h1r -> h1 -> (s1)
  bf16* B1 = (bf16*)alloc(MB8);  // k -> qlmm -> pred/dp -> (s1)
  bf16* B2 = (bf16*)alloc(MB8);  // v -> kf -> (s1)
  bf16* B3 = (bf16*)alloc(MB8);  // o -> vf -> dz -> (s1)
  bf16* B4 = (bf16*)alloc(MB8);  // Vt (attn) -> hb -> z0 -> hn3
  bf16* s1 = B0;                 // [NT][F] = 32 MiB
  bf16* VtG = B4;                // [BH][HD][S] per-head transposed V, dead before hb

  // --- smalls
  float* g0b = (float*)alloc(4 * 1024);
  float* g1b = (float*)alloc(4 * 1024);
  float* lossb = (float*)alloc(256);
  int*   flag  = (int*)alloc(256);
  bf16* n1c = (bf16*)alloc(2 * 1024);
  bf16* n2c = (bf16*)alloc(2 * 1024);
  bf16* n3c = (bf16*)alloc(2 * 1024);
  bf16* bqc = (bf16*)alloc(2 * 1024);
  bf16* bkc = (bf16*)alloc(2 * 1024);
  bf16* bvc = (bf16*)alloc(2 * 1024);
  bf16* b0c = (bf16*)alloc(2 * 1024);
  bf16* b1c = (bf16*)alloc(2 * 1024);

  // --- output regions (fp32)
  float* outX = (float*)d_out;                 // hn(bf16 head), then h2 fp32, then final out fp32
  float* outP = outX + ND;                     // new params (l0w,l0b,l1w,l1b)
  float* outM = outP + (2 * DD + 2048);        // new momenta; hosts g0wF/g1wF pre-update
  float* g0wF = outM;                          // [1M] grad l0_w
  float* g1wF = outM + M1 + 1024;              // [1M] grad l1_w
  bf16*  hn   = (bf16*)outX;                   // bf16 hn in first 8 MiB of outX, dead before h2

  const dim3 tb(32, 8);

  hipMemsetAsync(lossb, 0, sizeof(float), stream);
  hipMemsetAsync(g0b, 0, 4 * 1024, stream);
  hipMemsetAsync(g1b, 0, 4 * 1024, stream);
  hipMemsetAsync(outM, 0, (2 * M1 + 2048) * sizeof(float), stream);  // zero g0wF/g1wF for split-K atomics
  k_detect<<<1, 64, 0, stream>>>((const unsigned short*)x, flag);

  // small cvts
  k_cvt<<<1, 256, 0, stream>>>(n1, n1c, 256, flag);
  k_cvt<<<1, 256, 0, stream>>>(n2, n2c, 256, flag);
  k_cvt<<<1, 256, 0, stream>>>(n3, n3c, 256, flag);
  k_cvt<<<1, 256, 0, stream>>>(pqb, bqc, 256, flag);
  k_cvt<<<1, 256, 0, stream>>>(pkb, bkc, 256, flag);
  k_cvt<<<1, 256, 0, stream>>>(pvb, bvc, 256, flag);
  k_cvt<<<1, 256, 0, stream>>>(l0b, b0c, 256, flag);
  k_cvt<<<1, 256, 0, stream>>>(l1b, b1c, 256, flag);

  // phase-1 weight transposes
  k_transpose_dt<<<dim3(32, 32), tb, 0, stream>>>(wq, wqT, Dc, Dc, flag);
  k_transpose_dt<<<dim3(32, 32), tb, 0, stream>>>(wk, wkT, Dc, Dc, flag);
  k_transpose_dt<<<dim3(32, 32), tb, 0, stream>>>(wv, wvT, Dc, Dc, flag);
  k_transpose_dt<<<dim3(32, 32), tb, 0, stream>>>(wo, woT, Dc, Dc, flag);
  k_transpose_dt<<<dim3(32, 32), tb, 0, stream>>>(pqw, pqT, Dc, Mc, flag);
  k_transpose_dt<<<dim3(32, 32), tb, 0, stream>>>(pkw, pkT, Dc, Mc, flag);
  k_transpose_dt<<<dim3(32, 32), tb, 0, stream>>>(pvw, pvT, Dc, Mc, flag);
  k_transpose_dt<<<dim3(32, 32), tb, 0, stream>>>(l0w, l0T, Mc, Mc, flag);

  // ---- attention
  k_rmsnorm_dt<<<NTc, 256, 0, stream>>>(x, n1c, hn, flag);
  k_gemm<EPI_BF16><<<dim3(8, 32), 256, 0, stream>>>(hn, wqT, NTc, Dc, Dc, nullptr, B0, nullptr, nullptr, nullptr, nullptr, nullptr);
  k_gemm<EPI_BF16><<<dim3(8, 32), 256, 0, stream>>>(hn, wkT, NTc, Dc, Dc, nullptr, B1, nullptr, nullptr, nullptr, nullptr, nullptr);
  k_gemm<EPI_BF16><<<dim3(8, 32), 256, 0, stream>>>(hn, wvT, NTc, Dc, Dc, nullptr, B2, nullptr, nullptr, nullptr, nullptr, nullptr);
  k_transpose_v<<<dim3(2, 64, 32), tb, 0, stream>>>(B2, VtG);   // per-head V^T -> B4
  k_rope<<<256, 256, 0, stream>>>(B0, B1);
  k_attn<<<4096, 256, 0, stream>>>(B0, B1, VtG, B3);
  k_gemm<EPI_RESX_BF16><<<dim3(8, 32), 256, 0, stream>>>(B3, woT, NTc, Dc, Dc, nullptr, B4, nullptr, nullptr, nullptr, x, flag);  // hb -> B4
  k_transpose_dt<<<dim3(32, 32), tb, 0, stream>>>(l1w, l1T, Mc, Mc, flag);

  // ---- LMM forward
  k_rmsnorm_b<<<NTc, 256, 0, stream>>>(B4, n2c, B0);   // hn2 -> B0
  k_gemm<EPI_BIAS_BF16><<<dim3(8, 32), 256, 0, stream>>>(B0, pqT, NTc, Mc, Dc, nullptr, B1, bqc, nullptr, nullptr, nullptr, nullptr);  // qlmm
  k_gemm<EPI_BIAS_BF16><<<dim3(8, 32), 256, 0, stream>>>(B0, pkT, NTc, Mc, Dc, nullptr, B2, bkc, nullptr, nullptr, nullptr, nullptr);  // kf
  k_gemm<EPI_BIAS_BF16><<<dim3(8, 32), 256, 0, stream>>>(B0, pvT, NTc, Mc, Dc, nullptr, B3, bvc, nullptr, nullptr, nullptr, nullptr);  // vf
  k_gemm<EPI_BIAS_RELU_BF16><<<dim3(8, 32), 256, 0, stream>>>(B1, l0T, NTc, Mc, Mc, nullptr, B0, b0c, nullptr, nullptr, nullptr, nullptr);  // h1r
  // h2 = h1r@l1T + l1b + hb -> fp32 in outX (overwrites bf16 hn region; hn is dead)
  k_gemm<EPI_BIAS_RESB_F32><<<dim3(8, 32), 256, 0, stream>>>(B0, l1T, NTc, Mc, Mc, outX, nullptr, b1c, B4, nullptr, nullptr, nullptr);

  // ---- LMM loss fwd/bwd
  k_gemm<EPI_BIAS_BF16><<<dim3(8, 32), 256, 0, stream>>>(B2, l0T, NTc, Mc, Mc, nullptr, B4, b0c, nullptr, nullptr, nullptr, nullptr);  // z0 -> B4
  k_transpose_dt<<<dim3(128, 32), tb, 0, stream>>>(fw1, w1T, Dc, Fc, flag);     // stage w1T (pqT..l0T dead)
  k_relu<<<2048, 256, 0, stream>>>(B4, B0);            // h1 -> B0
  k_gemm<EPI_BIAS_BF16><<<dim3(8, 32), 256, 0, stream>>>(B0, l1T, NTc, Mc, Mc, nullptr, B1, b1c, nullptr, nullptr, nullptr, nullptr);  // pred -> B1
  k_cvt<<<1024, 256, 0, stream>>>(l1w, l1c, (int)(DD / 4), flag);
  k_dpred<<<256, 256, 0, stream>>>(B1, B3, lossb);     // dp in-place over pred (1 atomic/block)
  k_gemm<EPI_DZ_BF16><<<dim3(8, 32), 256, 0, stream>>>(B1, l1c, NTc, Mc, Mc, nullptr, B3, nullptr, B4, nullptr, nullptr, nullptr);     // dz -> B3
  k_gemm_tn<<<dim3(8, 8, 8), 256, 0, stream>>>(B0, B1, NTc, g1wF);   // g1w = h1^T dp (split-K atomic)
  k_gemm_tn<<<dim3(8, 8, 8), 256, 0, stream>>>(B2, B3, NTc, g0wF);   // g0w = kf^T dz (split-K atomic)
  k_colsum<<<dim3(4, 32), 256, 0, stream>>>(B1, g1b, Mc, NTc / 32);
  k_colsum<<<dim3(4, 32), 256, 0, stream>>>(B3, g0b, Mc, NTc / 32);
  k_update_dt<<<8200, 256, 0, stream>>>(l0w, l0b, l1w, l1b, m0w, m0b, m1w, m1b,
                                        g0wF, g0b, g1wF, g1b, lossb, flag, outP, outM);

  // ---- FFN (all B-slots free; h2 fp32 in outX)
  k_transpose_dt<<<dim3(128, 32), tb, 0, stream>>>(fw2, w2T, Dc, Fc, flag);     // stage w2T (l1c/l1T dead)
  k_rmsnorm_f<<<NTc, 256, 0, stream>>>(outX, n3c, B4); // hn3 -> B4
  k_gemm<EPI_BF16><<<dim3(32, 32), 256, 0, stream>>>(B4, w1T, NTc, Fc, Dc, nullptr, s1, nullptr, nullptr, nullptr, nullptr, nullptr);
  k_transpose_dt<<<dim3(32, 128), tb, 0, stream>>>(fw3, w3T, Fc, Dc, flag);     // stage w3T (w1T dead)
  k_gemm<EPI_SILU_BF16><<<dim3(32, 32), 256, 0, stream>>>(B4, w2T, NTc, Fc, Dc, nullptr, s1, nullptr, s1, nullptr, nullptr, nullptr);
  // out = s1@w3T + h2  (fp32 in-place over outX)
  k_gemm<EPI_RESF_F32><<<dim3(8, 32), 256, 0, stream>>>(s1, w3T, NTc, Dc, Fc, outX, nullptr, nullptr, nullptr, outX, nullptr, nullptr);
}

// Round 3
// 980.721 us; speedup vs baseline: 1.1392x; 1.1126x over previous
//
#include <hip/hip_runtime.h>
#include <cstdint>
#include <cstddef>

typedef __bf16 bf16;
typedef __bf16 bf16x2 __attribute__((ext_vector_type(2)));
typedef __bf16 bf16x4 __attribute__((ext_vector_type(4)));
typedef __bf16 bf16x8 __attribute__((ext_vector_type(8)));
typedef float  f32x4  __attribute__((ext_vector_type(4)));
typedef __attribute__((address_space(1))) unsigned int u32_g;
typedef __attribute__((address_space(3))) unsigned int u32_l;

#define DI __device__ __forceinline__

constexpr int Bc = 2, Sc = 2048, Dc = 1024, Hc = 16, HDc = 64, Fc = 4096, Mc = 1024;
constexpr int NTc = Bc * Sc;  // 4096 tokens

DI void llds16(const bf16* g, bf16* l) {
  __builtin_amdgcn_global_load_lds((const u32_g*)g, (u32_l*)l, 16, 0, 0);
}
DI f32x4 cvt4(bf16x4 a) {
  f32x4 r; r[0] = (float)a[0]; r[1] = (float)a[1]; r[2] = (float)a[2]; r[3] = (float)a[3];
  return r;
}

// ---------------------------------------------------------------- dtype detector (inputs)
__global__ void k_detect(const unsigned short* __restrict__ x, int* __restrict__ flag)
{
  const int tid = threadIdx.x;  // 64
  int cnt = 0;
#pragma unroll
  for (int i = 0; i < 8; i++) {
    unsigned short h = x[tid * 8 + i];
    int e = (h >> 7) & 0xFF;
    if (e < 96 || e > 160) cnt++;
  }
#pragma unroll
  for (int off = 32; off > 0; off >>= 1) cnt += __shfl_down(cnt, off, 64);
  if (tid == 0) *flag = (cnt > 32) ? 1 : 0;
}

// ---------------------------------------------------------------- dtype-aware convert to bf16
__global__ __launch_bounds__(256)
void k_cvt(const void* __restrict__ src, bf16* __restrict__ dst, int n4, const int* __restrict__ flag)
{
  int i = blockIdx.x * 256 + threadIdx.x;
  if (i >= n4) return;
  bf16x4 o;
  if (*flag) {
    f32x4 v = ((const f32x4*)src)[i];
    o[0] = (bf16)v[0]; o[1] = (bf16)v[1]; o[2] = (bf16)v[2]; o[3] = (bf16)v[3];
  } else {
    o = ((const bf16x4*)src)[i];
  }
  ((bf16x4*)dst)[i] = o;
}

// ---------------------------------------------------------------- dtype-aware transpose [R][C] -> bf16 [C][R]
__global__ void k_transpose_dt(const void* __restrict__ src, bf16* __restrict__ dst,
                               int R, int C, const int* __restrict__ flag)
{
  __shared__ bf16 tile[32][33];
  const int c0 = blockIdx.x * 32, r0 = blockIdx.y * 32;
  const int tx = threadIdx.x, ty = threadIdx.y;
  const bool f32 = (*flag != 0);
  for (int i = ty; i < 32; i += 8) {
    size_t idx = (size_t)(r0 + i) * C + (c0 + tx);
    tile[i][tx] = f32 ? (bf16)((const float*)src)[idx] : ((const bf16*)src)[idx];
  }
  __syncthreads();
  for (int i = ty; i < 32; i += 8)
    dst[(size_t)(c0 + i) * R + (r0 + tx)] = tile[tx][i];
}

// ---------------------------------------------------------------- per-head V transpose: v[(b*S+s)][h*64+d] -> vt[(bh*64+d)][s]
__global__ void k_transpose_v(const bf16* __restrict__ v, bf16* __restrict__ vt)
{
  __shared__ bf16 tile[32][33];
  const int d0 = blockIdx.x * 32, s0 = blockIdx.y * 32;
  const int bh = blockIdx.z;
  const int b = bh >> 4, hh = bh & 15;
  const int tx = threadIdx.x, ty = threadIdx.y;
  for (int i = ty; i < 32; i += 8)
    tile[i][tx] = v[((size_t)(b * Sc + s0 + i)) * Dc + hh * HDc + d0 + tx];
  __syncthreads();
  for (int i = ty; i < 32; i += 8)
    vt[((size_t)(bh * HDc + d0 + i)) * Sc + s0 + tx] = tile[tx][i];
}

// ---------------------------------------------------------------- GEMM (NT): C[M][N] = A[M][K] * Bt[N][K]^T
// R2 lesson: every N=1024 GEMM at grid(8,32)=256 blocks = 1 block/CU -> the
// 4 waves are barrier-locked with zero cross-phase overlap (m114 needs ~3
// blocks/CU). Fix = batched dispatches:
//   EPI_SEGC_*: N=3072 fused (qkv / pqkv), col>>10 routes to 3 contiguous
//     8MiB output slots (B-slots are consecutive allocs).
//   EPI_SEG2_RELU: M=8192 fused l0-GEMM, rowb>>12 routes seg1 to out2
//     (passed via outF, reinterpreted bf16*).
//   EPI_ATOMIC_F32: split-K (blockIdx.z) fp32 atomicAdd epilogue; out must
//     be pre-filled with the residual (outX holds h2).
enum EpiMode { EPI_BF16 = 0, EPI_BIAS_BF16, EPI_BIAS_RELU_BF16, EPI_BIAS_RESB_F32,
               EPI_SILU_BF16, EPI_DZ_BF16, EPI_RESX_BF16, EPI_RESF_F32,
               EPI_SEGC_BF16, EPI_SEGC_BIAS_BF16, EPI_SEG2_RELU_BF16, EPI_ATOMIC_F32 };

template <int EPI>
__global__ __launch_bounds__(256)
void k_gemm(const bf16* __restrict__ A, const bf16* __restrict__ Bt,
            int Mr, int Nr, int Kr,
            float* outF, bf16* outB,
            const bf16* __restrict__ bias, const bf16* auxB,
            const float* resF,
            const void* __restrict__ resX, const int* __restrict__ flag)
{
  __shared__ bf16 As[128 * 32];
  __shared__ bf16 Bs[128 * 32];
  const int tid = threadIdx.x;
  const int w = tid >> 6, l = tid & 63;
  const int wr = w >> 1, wc = w & 1;
  const int row0 = blockIdx.y * 128, col0 = blockIdx.x * 128;

  const f32x4 vzero = {0.f, 0.f, 0.f, 0.f};
  f32x4 acc[4][4];
#pragma unroll
  for (int i = 0; i < 4; i++)
#pragma unroll
    for (int j = 0; j < 4; j++) acc[i][j] = vzero;

  const bf16* Ag = A + (size_t)(row0 + w * 16 + (l >> 2)) * Kr + ((l & 3) << 3);
  const bf16* Bg = Bt + (size_t)(col0 + w * 16 + (l >> 2)) * Kr + ((l & 3) << 3);
  bf16* AsW = &As[w * 512];
  bf16* BsW = &Bs[w * 512];
  const size_t rowHop = (size_t)64 * Kr;

  const int chunk = Kr / gridDim.z;           // split-K support (z=1 -> full K)
  const int kbeg = blockIdx.z * chunk;

  for (int k0 = kbeg; k0 < kbeg + chunk; k0 += 32) {
    __syncthreads();
    llds16(Ag + k0, AsW);
    llds16(Ag + rowHop + k0, AsW + 2048);
    llds16(Bg + k0, BsW);
    llds16(Bg + rowHop + k0, BsW + 2048);
    __syncthreads();
    bf16x8 af[4], bfr[4];
#pragma unroll
    for (int mt = 0; mt < 4; mt++)
      af[mt] = *(const bf16x8*)&As[(wr * 64 + mt * 16 + (l & 15)) * 32 + (l >> 4) * 8];
#pragma unroll
    for (int nt = 0; nt < 4; nt++)
      bfr[nt] = *(const bf16x8*)&Bs[(wc * 64 + nt * 16 + (l & 15)) * 32 + (l >> 4) * 8];
#pragma unroll
    for (int mt = 0; mt < 4; mt++)
#pragma unroll
      for (int nt = 0; nt < 4; nt++)
        acc[mt][nt] = __builtin_amdgcn_mfma_f32_16x16x32_bf16(af[mt], bfr[nt], acc[mt][nt], 0, 0, 0);
  }

  const bool f32res = (EPI == EPI_RESX_BF16) ? (*flag != 0) : false;
  // bias preload (before ANY store exists -> fully parallel)
  float biasv[4];
  if (EPI == EPI_BIAS_BF16 || EPI == EPI_BIAS_RELU_BF16 || EPI == EPI_BIAS_RESB_F32 ||
      EPI == EPI_SEGC_BIAS_BF16 || EPI == EPI_SEG2_RELU_BF16) {
#pragma unroll
    for (int nt = 0; nt < 4; nt++)
      biasv[nt] = (float)bias[col0 + wc * 64 + nt * 16 + (l & 15)];
  }
  // C/D layout (verified m89/m91): col = lane&15, row = (lane>>4)*4 + reg
#pragma unroll
  for (int mt = 0; mt < 4; mt++) {
    const int rowb = row0 + wr * 64 + mt * 16 + ((l >> 4) << 2);
    // phase 1: batch-gather aux/res for this mt (16 independent loads)
    float av[4][4];
    if (EPI == EPI_SILU_BF16 || EPI == EPI_DZ_BF16 || EPI == EPI_BIAS_RESB_F32) {
#pragma unroll
      for (int nt = 0; nt < 4; nt++) {
        const int col = col0 + wc * 64 + nt * 16 + (l & 15);
#pragma unroll
        for (int r = 0; r < 4; r++)
          av[nt][r] = (float)auxB[(size_t)(rowb + r) * Nr + col];
      }
    }
    if (EPI == EPI_RESF_F32) {
#pragma unroll
      for (int nt = 0; nt < 4; nt++) {
        const int col = col0 + wc * 64 + nt * 16 + (l & 15);
#pragma unroll
        for (int r = 0; r < 4; r++)
          av[nt][r] = resF[(size_t)(rowb + r) * Nr + col];
      }
    }
    if (EPI == EPI_RESX_BF16) {
#pragma unroll
      for (int nt = 0; nt < 4; nt++) {
        const int col = col0 + wc * 64 + nt * 16 + (l & 15);
#pragma unroll
        for (int r = 0; r < 4; r++) {
          const size_t idx = (size_t)(rowb + r) * Nr + col;
          av[nt][r] = f32res ? ((const float*)resX)[idx] : (float)((const bf16*)resX)[idx];
        }
      }
    }
    // phase 2: compute + store
#pragma unroll
    for (int nt = 0; nt < 4; nt++) {
      const int col = col0 + wc * 64 + nt * 16 + (l & 15);
#pragma unroll
      for (int r = 0; r < 4; r++) {
        const size_t idx = (size_t)(rowb + r) * Nr + col;
        float v = acc[mt][nt][r];
        if (EPI == EPI_BF16) { outB[idx] = (bf16)v; }
        else if (EPI == EPI_BIAS_BF16) { outB[idx] = (bf16)(v + biasv[nt]); }
        else if (EPI == EPI_BIAS_RELU_BF16) { outB[idx] = (bf16)fmaxf(v + biasv[nt], 0.f); }
        else if (EPI == EPI_BIAS_RESB_F32) { outF[idx] = v + biasv[nt] + av[nt][r]; }
        else if (EPI == EPI_SILU_BF16) {
          float s1v = av[nt][r];
          float sl = s1v / (1.f + __expf(-s1v));
          outB[idx] = (bf16)(sl * v);
        }
        else if (EPI == EPI_DZ_BF16) { outB[idx] = (bf16)(av[nt][r] > 0.f ? v : 0.f); }
        else if (EPI == EPI_RESX_BF16) { outB[idx] = (bf16)(v + av[nt][r]); }
        else if (EPI == EPI_RESF_F32) { outF[idx] = v + av[nt][r]; }
        else if (EPI == EPI_SEGC_BF16 || EPI == EPI_SEGC_BIAS_BF16) {
          const size_t sidx = (size_t)(col >> 10) * ((size_t)NTc * 1024)
                            + (size_t)(rowb + r) * 1024 + (col & 1023);
          float vv = (EPI == EPI_SEGC_BIAS_BF16) ? (v + biasv[nt]) : v;
          outB[sidx] = (bf16)vv;
        }
        else if (EPI == EPI_SEG2_RELU_BF16) {
          bf16* ob = (rowb >> 12) ? (bf16*)outF : outB;
          ob[(size_t)((rowb + r) & 4095) * 1024 + col] = (bf16)fmaxf(v + biasv[nt], 0.f);
        }
        else if (EPI == EPI_ATOMIC_F32) {
          atomicAdd(&outF[(size_t)(rowb + r) * Nr + col], v);
        }
      }
    }
  }
}

// ---------------------------------------------------------------- GEMM (TN) split-K: C[i][j] += sum_t X[t][i]*Y[t][j]
__global__ __launch_bounds__(256)
void k_gemm_tn(const bf16* __restrict__ X, const bf16* __restrict__ Y, int Kt,
               float* __restrict__ out)
{
  __shared__ bf16 As[128 * 36];
  __shared__ bf16 Bs[128 * 36];
  const int tid = threadIdx.x;
  const int w = tid >> 6, l = tid & 63;
  const int wr = w >> 1, wc = w & 1;
  const int row0 = blockIdx.y * 128, col0 = blockIdx.x * 128;
  const int iofs = (tid & 15) * 8;   // 0..120
  const int tp   = (tid >> 4) * 2;   // 0..30

  const f32x4 vzero = {0.f, 0.f, 0.f, 0.f};
  f32x4 acc[4][4];
#pragma unroll
  for (int i = 0; i < 4; i++)
#pragma unroll
    for (int j = 0; j < 4; j++) acc[i][j] = vzero;

  const int chunk = Kt / gridDim.z;
  const int tbeg = blockIdx.z * chunk;

  for (int t0 = tbeg; t0 < tbeg + chunk; t0 += 32) {
    __syncthreads();
    bf16x8 a0 = *(const bf16x8*)&X[(size_t)(t0 + tp) * 1024 + row0 + iofs];
    bf16x8 a1 = *(const bf16x8*)&X[(size_t)(t0 + tp + 1) * 1024 + row0 + iofs];
    bf16x8 b0 = *(const bf16x8*)&Y[(size_t)(t0 + tp) * 1024 + col0 + iofs];
    bf16x8 b1 = *(const bf16x8*)&Y[(size_t)(t0 + tp + 1) * 1024 + col0 + iofs];
#pragma unroll
    for (int e = 0; e < 8; e++) {
      bf16x2 pa; pa[0] = a0[e]; pa[1] = a1[e];
      bf16x2 pb; pb[0] = b0[e]; pb[1] = b1[e];
      *(bf16x2*)&As[(iofs + e) * 36 + tp] = pa;
      *(bf16x2*)&Bs[(iofs + e) * 36 + tp] = pb;
    }
    __syncthreads();
    bf16x8 af[4], bfr[4];
#pragma unroll
    for (int mt = 0; mt < 4; mt++) {
      const int base = (wr * 64 + mt * 16 + (l & 15)) * 36 + (l >> 4) * 8;
      bf16x4 lo = *(const bf16x4*)&As[base];
      bf16x4 hi = *(const bf16x4*)&As[base + 4];
#pragma unroll
      for (int e = 0; e < 4; e++) { af[mt][e] = lo[e]; af[mt][4 + e] = hi[e]; }
    }
#pragma unroll
    for (int nt = 0; nt < 4; nt++) {
      const int base = (wc * 64 + nt * 16 + (l & 15)) * 36 + (l >> 4) * 8;
      bf16x4 lo = *(const bf16x4*)&Bs[base];
      bf16x4 hi = *(const bf16x4*)&Bs[base + 4];
#pragma unroll
      for (int e = 0; e < 4; e++) { bfr[nt][e] = lo[e]; bfr[nt][4 + e] = hi[e]; }
    }
#pragma unroll
    for (int mt = 0; mt < 4; mt++)
#pragma unroll
      for (int nt = 0; nt < 4; nt++)
        acc[mt][nt] = __builtin_amdgcn_mfma_f32_16x16x32_bf16(af[mt], bfr[nt], acc[mt][nt], 0, 0, 0);
  }

#pragma unroll
  for (int mt = 0; mt < 4; mt++) {
    const int rowb = row0 + wr * 64 + mt * 16 + ((l >> 4) << 2);
#pragma unroll
    for (int nt = 0; nt < 4; nt++) {
      const int col = col0 + wc * 64 + nt * 16 + (l & 15);
#pragma unroll
      for (int r = 0; r < 4; r++)
        atomicAdd(&out[(size_t)(rowb + r) * 1024 + col], acc[mt][nt][r]);
    }
  }
}

// ---------------------------------------------------------------- RMSNorm variants
__global__ __launch_bounds__(256)
void k_rmsnorm_dt(const void* __restrict__ x, const bf16* __restrict__ w, bf16* __restrict__ out,
                  const int* __restrict__ flag)
{
  const int row = blockIdx.x;
  const int tid = threadIdx.x;
  f32x4 xv;
  if (*flag) xv = *(const f32x4*)((const float*)x + (size_t)row * Dc + tid * 4);
  else       xv = cvt4(*(const bf16x4*)((const bf16*)x + (size_t)row * Dc + tid * 4));
  float ss = xv[0] * xv[0] + xv[1] * xv[1] + xv[2] * xv[2] + xv[3] * xv[3];
#pragma unroll
  for (int off = 32; off > 0; off >>= 1) ss += __shfl_down(ss, off, 64);
  __shared__ float part[4];
  if ((tid & 63) == 0) part[tid >> 6] = ss;
  __syncthreads();
  float tot = part[0] + part[1] + part[2] + part[3];
  float inv = 1.f / (sqrtf(tot) * 0.03125f + 1e-8f);
  bf16x4 wb = *(const bf16x4*)(w + tid * 4);
  bf16x4 ov;
  ov[0] = (bf16)((float)wb[0] * xv[0] * inv);
  ov[1] = (bf16)((float)wb[1] * xv[1] * inv);
  ov[2] = (bf16)((float)wb[2] * xv[2] * inv);
  ov[3] = (bf16)((float)wb[3] * xv[3] * inv);
  *(bf16x4*)(out + (size_t)row * Dc + tid * 4) = ov;
}

__global__ __launch_bounds__(256)
void k_rmsnorm_b(const bf16* __restrict__ x, const bf16* __restrict__ w, bf16* __restrict__ out)
{
  const int row = blockIdx.x;
  const int tid = threadIdx.x;
  f32x4 xv = cvt4(*(const bf16x4*)(x + (size_t)row * Dc + tid * 4));
  float ss = xv[0] * xv[0] + xv[1] * xv[1] + xv[2] * xv[2] + xv[3] * xv[3];
#pragma unroll
  for (int off = 32; off > 0; off >>= 1) ss += __shfl_down(ss, off, 64);
  __shared__ float part[4];
  if ((tid & 63) == 0) part[tid >> 6] = ss;
  __syncthreads();
  float tot = part[0] + part[1] + part[2] + part[3];
  float inv = 1.f / (sqrtf(tot) * 0.03125f + 1e-8f);
  bf16x4 wb = *(const bf16x4*)(w + tid * 4);
  bf16x4 ov;
  ov[0] = (bf16)((float)wb[0] * xv[0] * inv);
  ov[1] = (bf16)((float)wb[1] * xv[1] * inv);
  ov[2] = (bf16)((float)wb[2] * xv[2] * inv);
  ov[3] = (bf16)((float)wb[3] * xv[3] * inv);
  *(bf16x4*)(out + (size_t)row * Dc + tid * 4) = ov;
}

__global__ __launch_bounds__(256)
void k_rmsnorm_f(const float* __restrict__ x, const bf16* __restrict__ w, bf16* __restrict__ out)
{
  const int row = blockIdx.x;
  const int tid = threadIdx.x;
  f32x4 xv = *(const f32x4*)(x + (size_t)row * Dc + tid * 4);
  float ss = xv[0] * xv[0] + xv[1] * xv[1] + xv[2] * xv[2] + xv[3] * xv[3];
#pragma unroll
  for (int off = 32; off > 0; off >>= 1) ss += __shfl_down(ss, off, 64);
  __shared__ float part[4];
  if ((tid & 63) == 0) part[tid >> 6] = ss;
  __syncthreads();
  float tot = part[0] + part[1] + part[2] + part[3];
  float inv = 1.f / (sqrtf(tot) * 0.03125f + 1e-8f);
  bf16x4 wb = *(const bf16x4*)(w + tid * 4);
  bf16x4 ov;
  ov[0] = (bf16)((float)wb[0] * xv[0] * inv);
  ov[1] = (bf16)((float)wb[1] * xv[1] * inv);
  ov[2] = (bf16)((float)wb[2] * xv[2] * inv);
  ov[3] = (bf16)((float)wb[3] * xv[3] * inv);
  *(bf16x4*)(out + (size_t)row * Dc + tid * 4) = ov;
}

// ---------------------------------------------------------------- RoPE in-place on bf16 q,k
__global__ __launch_bounds__(256)
void k_rope(bf16* __restrict__ q, bf16* __restrict__ kx)
{
  const int idx = blockIdx.x * 256 + threadIdx.x;  // NT*H = 65536
  const int t = idx >> 4, hh = idx & 15;
  const int s = t & (Sc - 1);
  float sn[32], cs[32];
#pragma unroll
  for (int i = 0; i < 32; i++) {
    float f = expf(-(float)i * 0.28782313662425574f);  // ln(10000)/32
    float ang = (float)s * f;
    sn[i] = sinf(ang);
    cs[i] = cosf(ang);
  }
  for (int pass = 0; pass < 2; pass++) {
    bf16* p = (pass ? kx : q) + (size_t)t * Dc + hh * HDc;
    float xb[64], ob[64];
#pragma unroll
    for (int j = 0; j < 16; j++) *(f32x4*)&xb[j * 4] = cvt4(*(const bf16x4*)(p + j * 4));
#pragma unroll
    for (int i = 0; i < 32; i++) {
      float x1 = xb[2 * i], x2 = xb[2 * i + 1];
      ob[i] = x1 * cs[i] - x2 * sn[i];
      ob[32 + i] = x1 * sn[i] + x2 * cs[i];
    }
#pragma unroll
    for (int j = 0; j < 16; j++) {
      bf16x4 o4;
      o4[0] = (bf16)ob[j * 4]; o4[1] = (bf16)ob[j * 4 + 1];
      o4[2] = (bf16)ob[j * 4 + 2]; o4[3] = (bf16)ob[j * 4 + 3];
      *(bf16x4*)(p + j * 4) = o4;
    }
  }
}

// ---------------------------------------------------------------- MFMA flash attention, KV-split across waves
// Plateau note (R0-R2): 140-160us ~ 127 TF regardless of staging/occupancy/
// depth -> structural limit of the shfl-chain softmax (guide m164-m191,
// ERRATA #12). Next structural step: swapped-QK lane-local softmax rewrite.
__global__ __launch_bounds__(256)
void k_attn(const bf16* __restrict__ q, const bf16* __restrict__ kx,
            const bf16* __restrict__ vt, bf16* __restrict__ o)
{
  constexpr int PAD = 72;
  __shared__ __align__(16) char smem[19456];

  const int blk = blockIdx.x;
  const int qi = 127 - (blk >> 5);     // heavy q-tiles dispatch first (LPT)
  const int bh = blk & 31;             // same head -> same XCD residue
  const int b = bh >> 4, hh = bh & 15;
  const int tid = threadIdx.x;
  const int w = tid >> 6, l = tid & 63;
  const int quad = l >> 4, c = l & 15;

  bf16* Psw = (bf16*)smem + w * 16 * PAD;
  float* Buf = (float*)smem;

  const int qrow = qi * 16 + c;
  const size_t qbase = ((size_t)(b * Sc + qrow)) * Dc + hh * HDc;
  bf16x8 qf0 = *(const bf16x8*)(q + qbase + quad * 8);
  bf16x8 qf1 = *(const bf16x8*)(q + qbase + 32 + quad * 8);
#pragma unroll
  for (int j = 0; j < 8; j++) {
    qf0[j] = (bf16)((float)qf0[j] * 0.125f);
    qf1[j] = (bf16)((float)qf1[j] * 0.125f);
  }

  const f32x4 vzero = {0.f, 0.f, 0.f, 0.f};
  f32x4 oacc[4];
#pragma unroll
  for (int nt = 0; nt < 4; nt++) oacc[nt] = vzero;
  float mrun[4] = {-3.0e38f, -3.0e38f, -3.0e38f, -3.0e38f};
  float lrun[4] = {0.f, 0.f, 0.f, 0.f};

  const int qrow0 = qi * 16 + quad * 4;
  const int ntiles = (qi >> 2) + 1;    // 64-wide kv tiles covering 0..qi*16+15

  const bf16* kb = kx + (size_t)b * Sc * Dc + hh * HDc;   // + krow*Dc
  const bf16* vb = vt + (size_t)bh * HDc * Sc;            // + d*Sc + kk

  for (int t0 = w; t0 < ntiles; t0 += 4) {
    const int kk0 = t0 * 64;

    f32x4 sf[4];
#pragma unroll
    for (int nt = 0; nt < 4; nt++) {
      const bf16* kr = kb + (size_t)(kk0 + nt * 16 + c) * Dc + quad * 8;
      bf16x8 k0 = *(const bf16x8*)kr;
      bf16x8 k1 = *(const bf16x8*)(kr + 32);
      f32x4 a = vzero;
      a = __builtin_amdgcn_mfma_f32_16x16x32_bf16(qf0, k0, a, 0, 0, 0);
      a = __builtin_amdgcn_mfma_f32_16x16x32_bf16(qf1, k1, a, 0, 0, 0);
      sf[nt] = a;
    }
    if (t0 == ntiles - 1) {            // diagonal tile: causal mask
#pragma unroll
      for (int nt = 0; nt < 4; nt++)
#pragma unroll
        for (int r = 0; r < 4; r++)
          if (kk0 + nt * 16 + c > qrow0 + r) sf[nt][r] = -3.0e38f;
    }

    float mnew[4], alpha[4];
#pragma unroll
    for (int r = 0; r < 4; r++) {
      float mt = fmaxf(fmaxf(sf[0][r], sf[1][r]), fmaxf(sf[2][r], sf[3][r]));
      mt = fmaxf(mt, __shfl_xor(mt, 1, 64));
      mt = fmaxf(mt, __shfl_xor(mt, 2, 64));
      mt = fmaxf(mt, __shfl_xor(mt, 4, 64));
      mt = fmaxf(mt, __shfl_xor(mt, 8, 64));
      mnew[r] = fmaxf(mrun[r], mt);
      alpha[r] = __expf(mrun[r] - mnew[r]);
      mrun[r] = mnew[r];
    }
    float ps[4] = {0.f, 0.f, 0.f, 0.f};
#pragma unroll
    for (int nt = 0; nt < 4; nt++)
#pragma unroll
      for (int r = 0; r < 4; r++) {
        float p = __expf(sf[nt][r] - mnew[r]);
        sf[nt][r] = p;
        ps[r] += p;
      }
#pragma unroll
    for (int r = 0; r < 4; r++) {
      ps[r] += __shfl_xor(ps[r], 1, 64);
      ps[r] += __shfl_xor(ps[r], 2, 64);
      ps[r] += __shfl_xor(ps[r], 4, 64);
      ps[r] += __shfl_xor(ps[r], 8, 64);
      lrun[r] = lrun[r] * alpha[r] + ps[r];
    }
#pragma unroll
    for (int nt = 0; nt < 4; nt++)
#pragma unroll
      for (int r = 0; r < 4; r++) oacc[nt][r] *= alpha[r];

#pragma unroll
    for (int nt = 0; nt < 4; nt++)
#pragma unroll
      for (int r = 0; r < 4; r++)
        Psw[(quad * 4 + r) * PAD + nt * 16 + c] = (bf16)sf[nt][r];
    bf16x8 pa0 = *(const bf16x8*)&Psw[c * PAD + quad * 8];
    bf16x8 pa1 = *(const bf16x8*)&Psw[c * PAD + 32 + quad * 8];

#pragma unroll
    for (int nt = 0; nt < 4; nt++) {
      const bf16* vr = vb + (size_t)(nt * 16 + c) * Sc + kk0 + quad * 8;
      bf16x8 v0 = *(const bf16x8*)vr;
      bf16x8 v1 = *(const bf16x8*)(vr + 32);
      oacc[nt] = __builtin_amdgcn_mfma_f32_16x16x32_bf16(pa0, v0, oacc[nt], 0, 0, 0);
      oacc[nt] = __builtin_amdgcn_mfma_f32_16x16x32_bf16(pa1, v1, oacc[nt], 0, 0, 0);
    }
  }

  // ---- cross-wave online-softmax merge (waves 1..3 -> wave 0)
  __syncthreads();
  if (w > 0) {
    float* dst = Buf + ((w - 1) * 64 + l) * 25;
#pragma unroll
    for (int nt = 0; nt < 4; nt++)
#pragma unroll
      for (int r = 0; r < 4; r++) dst[nt * 4 + r] = oacc[nt][r];
#pragma unroll
    for (int r = 0; r < 4; r++) { dst[16 + r] = mrun[r]; dst[20 + r] = lrun[r]; }
  }
  __syncthreads();
  if (w == 0) {
#pragma unroll
    for (int w2 = 0; w2 < 3; w2++) {
      const float* src = Buf + (w2 * 64 + l) * 25;
      float m2[4], l2[4];
#pragma unroll
      for (int r = 0; r < 4; r++) { m2[r] = src[16 + r]; l2[r] = src[20 + r]; }
#pragma unroll
      for (int r = 0; r < 4; r++) {
        float mn = fmaxf(mrun[r], m2[r]);
        float a = __expf(mrun[r] - mn);
        float bb = __expf(m2[r] - mn);
        lrun[r] = lrun[r] * a + l2[r] * bb;
        mrun[r] = mn;
#pragma unroll
        for (int nt = 0; nt < 4; nt++)
          oacc[nt][r] = oacc[nt][r] * a + src[nt * 4 + r] * bb;
      }
    }
    float inv[4];
#pragma unroll
    for (int r = 0; r < 4; r++) inv[r] = 1.f / lrun[r];
#pragma unroll
    for (int r = 0; r < 4; r++) {
      const size_t obase = ((size_t)(b * Sc + qrow0 + r)) * Dc + hh * HDc;
#pragma unroll
      for (int nt = 0; nt < 4; nt++)
        o[obase + nt * 16 + c] = (bf16)(oacc[nt][r] * inv[r]);
    }
  }
}

// ---------------------------------------------------------------- dp = 2(pred-vf)/M in-place + loss
__global__ __launch_bounds__(256)
void k_dpred(bf16* __restrict__ predDp, const bf16* __restrict__ vf, float* __restrict__ loss)
{
  __shared__ float red[4];
  const int tid = threadIdx.x;
  const size_t n8 = (size_t)NTc * Mc / 8;
  float lacc = 0.f;
  for (size_t i = (size_t)blockIdx.x * 256 + tid; i < n8; i += (size_t)gridDim.x * 256) {
    bf16x8 p8 = ((const bf16x8*)predDp)[i];
    bf16x8 v8 = ((const bf16x8*)vf)[i];
    bf16x8 d8;
#pragma unroll
    for (int e = 0; e < 8; e++) {
      float df = (float)p8[e] - (float)v8[e];
      lacc += df * df;
      d8[e] = (bf16)(df * (2.0f / 1024.0f));
    }
    ((bf16x8*)predDp)[i] = d8;
  }
#pragma unroll
  for (int off = 32; off > 0; off >>= 1) lacc += __shfl_down(lacc, off, 64);
  if ((tid & 63) == 0) red[tid >> 6] = lacc;
  __syncthreads();
  if (tid == 0) atomicAdd(loss, red[0] + red[1] + red[2] + red[3]);
}

// ---------------------------------------------------------------- colsum: out[c] += sum over a row chunk
__global__ __launch_bounds__(256)
void k_colsum(const bf16* __restrict__ X, float* __restrict__ out, int C, int rowsPer)
{
  int c = blockIdx.x * 256 + threadIdx.x;
  int r0 = blockIdx.y * rowsPer;
  float s = 0.f;
#pragma unroll 8
  for (int r = r0; r < r0 + rowsPer; r++) s += (float)X[(size_t)r * C + c];
  atomicAdd(&out[c], s);
}

// ---------------------------------------------------------------- dtype-aware param/momentum update -> fp32 d_out
__global__ __launch_bounds__(256)
void k_update_dt(const void* __restrict__ p0w, const void* __restrict__ p0b,
                 const void* __restrict__ p1w, const void* __restrict__ p1b,
                 const void* __restrict__ m0w, const void* __restrict__ m0b,
                 const void* __restrict__ m1w, const void* __restrict__ m1b,
                 const float* __restrict__ g0wF, const float* __restrict__ g0b,
                 const float* __restrict__ g1wF, const float* __restrict__ g1b,
                 const float* __restrict__ loss, const int* __restrict__ flag,
                 float* __restrict__ outP, float* __restrict__ outM)
{
  const int i = blockIdx.x * 256 + threadIdx.x;  // < 2099200 exactly
  const bool upd = (loss[0] >= 0.1f * 1024.f * 4096.f);  // avg_loss >= THRESH
  const bool f32 = (*flag != 0);
  constexpr int W = 1024 * 1024;
  const void *pp, *pm; int j; float g;
  if (i < W) { pp = p0w; pm = m0w; j = i; g = g0wF[i]; }
  else if (i < W + 1024) { j = i - W; pp = p0b; pm = m0b; g = g0b[j]; }
  else if (i < 2 * W + 1024) { j = i - W - 1024; pp = p1w; pm = m1w; g = g1wF[j]; }
  else { j = i - 2 * W - 1024; pp = p1b; pm = m1b; g = g1b[j]; }
  float p = f32 ? ((const float*)pp)[j] : (float)((const bf16*)pp)[j];
  float m = f32 ? ((const float*)pm)[j] : (float)((const bf16*)pm)[j];
  float nm = 0.9f * m - 0.01f * g;
  float np = 0.99f * p + nm;
  outP[i] = upd ? np : p;
  outM[i] = upd ? nm : m;
}

// ================================================================ host
extern "C" void kernel_launch(void* const* d_in, const int* in_sizes, int n_in,
                              void* d_out, int out_size, void* d_ws, size_t ws_size,
                              hipStream_t stream)
{
  (void)in_sizes; (void)n_in; (void)out_size; (void)ws_size;
  const void* x   = d_in[0];
  const void* wq  = d_in[2];
  const void* wk  = d_in[3];
  const void* wv  = d_in[4];
  const void* wo  = d_in[5];
  const void* n1  = d_in[6];
  const void* n2  = d_in[7];
  const void* n3  = d_in[8];
  const void* fw1 = d_in[9];
  const void* fw2 = d_in[10];
  const void* fw3 = d_in[11];
  const void* pkw = d_in[12];
  const void* pkb = d_in[13];
  const void* pvw = d_in[14];
  const void* pvb = d_in[15];
  const void* pqw = d_in[16];
  const void* pqb = d_in[17];
  const void* l0w = d_in[18];
  const void* l0b = d_in[19];
  const void* l1w = d_in[20];
  const void* l1b = d_in[21];
  const void* m0w = d_in[22];
  const void* m0b = d_in[23];
  const void* m1w = d_in[24];
  const void* m1b = d_in[25];

  char* ws = (char*)d_ws;
  size_t off = 0;
  auto alloc = [&](size_t bytes) -> char* {
    char* p = ws + off;
    off += (bytes + 255) & ~(size_t)255;
    return p;
  };

  const size_t DD = (size_t)Dc * Dc;   // 1M elems
  const size_t ND = (size_t)NTc * Dc;  // 4M elems
  const size_t MB8 = 2 * ND;           // 8 MiB
  const size_t M1 = DD;                // 1M elems

  // --- weight region W: 8M bf16 elems (16 MiB), phase-cycled
  bf16* W = (bf16*)alloc(2 * 8 * M1);
  bf16 *wqT = W, *wkT = W + M1, *wvT = W + 2 * M1, *woT = W + 3 * M1;   // contiguous [3072][1024] for fused qkv
  bf16 *pqT = W + 4 * M1, *pkT = W + 5 * M1, *pvT = W + 6 * M1, *l0T = W + 7 * M1;  // pqT..pvT = fused [3072][1024]
  bf16 *l1T = W + M1;          // staged after wo-GEMM (wkT dead)
  bf16 *h1buf = W + 2 * M1;    // h1 [4096][1024] after fused l0 (wvT/woT/pqT/pkT dead; l0T untouched)
  bf16 *l1c = W;               // staged after pred-GEMM (over wqT)
  bf16 *w1T = W + 4 * M1;      // staged after gemm_tn's (h1buf upper, pvT, l0T dead)
  bf16 *w2T = W;               // staged after grads (l1c/l1T/h1buf-lower dead)
  bf16 *w3T = W + 4 * M1;      // staged after ffn1 (w1T dead)

  // --- 5 activation slots, B0..B3 contiguous (seg-routing + s1 span rely on this)
  bf16* B0 = (bf16*)alloc(MB8);  // q -> hn2 -> h1r -> (s1)
  bf16* B1 = (bf16*)alloc(MB8);  // k -> qlmm -> pred/dp -> (s1)
  bf16* B2 = (bf16*)alloc(MB8);  // v -> kf -> (s1)
  bf16* B3 = (bf16*)alloc(MB8);  // o -> vf -> dz -> (s1)
  bf16* B4 = (bf16*)alloc(MB8);  // Vt (attn) -> hb -> hn3
  bf16* s1 = B0;                 // [NT][F] = 32 MiB
  bf16* VtG = B4;                // [BH][HD][S] per-head transposed V, dead before hb

  // --- smalls
  float* g0b = (float*)alloc(4 * 1024);
  float* g1b = (float*)alloc(4 * 1024);
  float* lossb = (float*)alloc(256);
  int*   flag  = (int*)alloc(256);
  bf16* n1c = (bf16*)alloc(2 * 1024);
  bf16* n2c = (bf16*)alloc(2 * 1024);
  bf16* n3c = (bf16*)alloc(2 * 1024);
  bf16* bqkv = (bf16*)alloc(2 * 3072);   // [bq;bk;bv] contiguous for fused pqkv
  bf16* b0c = (bf16*)alloc(2 * 1024);
  bf16* b1c = (bf16*)alloc(2 * 1024);

  // --- output regions (fp32)
  float* outX = (float*)d_out;                 // hn(bf16 head), then h2 fp32, then final out fp32
  float* outP = outX + ND;                     // new params (l0w,l0b,l1w,l1b)
  float* outM = outP + (2 * DD + 2048);        // new momenta; hosts g0wF/g1wF pre-update
  float* g0wF = outM;                          // [1M] grad l0_w
  float* g1wF = outM + M1 + 1024;              // [1M] grad l1_w
  bf16*  hn   = (bf16*)outX;                   // bf16 hn in first 8 MiB of outX, dead before h2

  const dim3 tb(32, 8);

  hipMemsetAsync(lossb, 0, sizeof(float), stream);
  hipMemsetAsync(g0b, 0, 4 * 1024, stream);
  hipMemsetAsync(g1b, 0, 4 * 1024, stream);
  hipMemsetAsync(outM, 0, (2 * M1 + 2048) * sizeof(float), stream);  // zero g0wF/g1wF for split-K atomics
  k_detect<<<1, 64, 0, stream>>>((const unsigned short*)x, flag);

  // small cvts
  k_cvt<<<1, 256, 0, stream>>>(n1, n1c, 256, flag);
  k_cvt<<<1, 256, 0, stream>>>(n2, n2c, 256, flag);
  k_cvt<<<1, 256, 0, stream>>>(n3, n3c, 256, flag);
  k_cvt<<<1, 256, 0, stream>>>(pqb, bqkv, 256, flag);
  k_cvt<<<1, 256, 0, stream>>>(pkb, bqkv + 1024, 256, flag);
  k_cvt<<<1, 256, 0, stream>>>(pvb, bqkv + 2048, 256, flag);
  k_cvt<<<1, 256, 0, stream>>>(l0b, b0c, 256, flag);
  k_cvt<<<1, 256, 0, stream>>>(l1b, b1c, 256, flag);

  // phase-1 weight transposes
  k_transpose_dt<<<dim3(32, 32), tb, 0, stream>>>(wq, wqT, Dc, Dc, flag);
  k_transpose_dt<<<dim3(32, 32), tb, 0, stream>>>(wk, wkT, Dc, Dc, flag);
  k_transpose_dt<<<dim3(32, 32), tb, 0, stream>>>(wv, wvT, Dc, Dc, flag);
  k_transpose_dt<<<dim3(32, 32), tb, 0, stream>>>(wo, woT, Dc, Dc, flag);
  k_transpose_dt<<<dim3(32, 32), tb, 0, stream>>>(pqw, pqT, Dc, Mc, flag);
  k_transpose_dt<<<dim3(32, 32), tb, 0, stream>>>(pkw, pkT, Dc, Mc, flag);
  k_transpose_dt<<<dim3(32, 32), tb, 0, stream>>>(pvw, pvT, Dc, Mc, flag);
  k_transpose_dt<<<dim3(32, 32), tb, 0, stream>>>(l0w, l0T, Mc, Mc, flag);

  // ---- attention
  k_rmsnorm_dt<<<NTc, 256, 0, stream>>>(x, n1c, hn, flag);
  // fused qkv: N=3072, 768 blocks = 3/CU; col>>10 routes to B0/B1/B2
  k_gemm<EPI_SEGC_BF16><<<dim3(24, 32), 256, 0, stream>>>(hn, wqT, NTc, 3072, Dc, nullptr, B0, nullptr, nullptr, nullptr, nullptr, nullptr);
  k_transpose_v<<<dim3(2, 64, 32), tb, 0, stream>>>(B2, VtG);   // per-head V^T -> B4
  k_rope<<<256, 256, 0, stream>>>(B0, B1);
  k_attn<<<4096, 256, 0, stream>>>(B0, B1, VtG, B3);
  k_gemm<EPI_RESX_BF16><<<dim3(8, 32), 256, 0, stream>>>(B3, woT, NTc, Dc, Dc, nullptr, B4, nullptr, nullptr, nullptr, x, flag);  // hb -> B4
  k_transpose_dt<<<dim3(32, 32), tb, 0, stream>>>(l1w, l1T, Mc, Mc, flag);

  // ---- LMM forward
  k_rmsnorm_b<<<NTc, 256, 0, stream>>>(B4, n2c, B0);   // hn2 -> B0
  // fused pqkv: qlmm->B1, kf->B2, vf->B3 (bias bqkv)
  k_gemm<EPI_SEGC_BIAS_BF16><<<dim3(24, 32), 256, 0, stream>>>(B0, pqT, NTc, 3072, Dc, nullptr, B1, bqkv, nullptr, nullptr, nullptr, nullptr);
  // fused l0: M=8192 over [qlmm;kf]; seg0 h1r->B0, seg1 h1->h1buf (both RELU)
  k_gemm<EPI_SEG2_RELU_BF16><<<dim3(8, 64), 256, 0, stream>>>(B1, l0T, 2 * NTc, Mc, Mc, (float*)h1buf, B0, b0c, nullptr, nullptr, nullptr, nullptr);
  // h2 = h1r@l1T + l1b + hb -> fp32 in outX (overwrites bf16 hn region; hn is dead)
  k_gemm<EPI_BIAS_RESB_F32><<<dim3(8, 32), 256, 0, stream>>>(B0, l1T, NTc, Mc, Mc, outX, nullptr, b1c, B4, nullptr, nullptr, nullptr);
  // pred = h1@l1T + l1b -> B1 (qlmm dead)
  k_gemm<EPI_BIAS_BF16><<<dim3(8, 32), 256, 0, stream>>>(h1buf, l1T, NTc, Mc, Mc, nullptr, B1, b1c, nullptr, nullptr, nullptr, nullptr);

  // ---- LMM loss bwd
  k_cvt<<<1024, 256, 0, stream>>>(l1w, l1c, (int)(DD / 4), flag);
  k_dpred<<<256, 256, 0, stream>>>(B1, B3, lossb);     // dp in-place over pred
  // dz = (h1>0) ? dp@l1c : 0  (h1>0 === z0>0)
  k_gemm<EPI_DZ_BF16><<<dim3(8, 32), 256, 0, stream>>>(B1, l1c, NTc, Mc, Mc, nullptr, B3, nullptr, h1buf, nullptr, nullptr, nullptr);
  k_gemm_tn<<<dim3(8, 8, 8), 256, 0, stream>>>(h1buf, B1, NTc, g1wF);   // g1w = h1^T dp
  k_gemm_tn<<<dim3(8, 8, 8), 256, 0, stream>>>(B2, B3, NTc, g0wF);      // g0w = kf^T dz
  k_transpose_dt<<<dim3(128, 32), tb, 0, stream>>>(fw1, w1T, Dc, Fc, flag);  // stage w1T (h1buf dead)
  k_colsum<<<dim3(4, 32), 256, 0, stream>>>(B1, g1b, Mc, NTc / 32);
  k_colsum<<<dim3(4, 32), 256, 0, stream>>>(B3, g0b, Mc, NTc / 32);
  k_update_dt<<<8200, 256, 0, stream>>>(l0w, l0b, l1w, l1b, m0w, m0b, m1w, m1b,
                                        g0wF, g0b, g1wF, g1b, lossb, flag, outP, outM);

  // ---- FFN (all B-slots free; h2 fp32 in outX)
  k_transpose_dt<<<dim3(128, 32), tb, 0, stream>>>(fw2, w2T, Dc, Fc, flag);     // stage w2T
  k_rmsnorm_f<<<NTc, 256, 0, stream>>>(outX, n3c, B4); // hn3 -> B4
  k_gemm<EPI_BF16><<<dim3(32, 32), 256, 0, stream>>>(B4, w1T, NTc, Fc, Dc, nullptr, s1, nullptr, nullptr, nullptr, nullptr, nullptr);
  k_transpose_dt<<<dim3(32, 128), tb, 0, stream>>>(fw3, w3T, Fc, Dc, flag);     // stage w3T (w1T dead)
  k_gemm<EPI_SILU_BF16><<<dim3(32, 32), 256, 0, stream>>>(B4, w2T, NTc, Fc, Dc, nullptr, s1, nullptr, s1, nullptr, nullptr, nullptr);
  // out = h2 + s1@w3T : split-K=2 fp32 atomics onto outX (pre-filled with h2)
  k_gemm<EPI_ATOMIC_F32><<<dim3(8, 32, 2), 256, 0, stream>>>(s1, w3T, NTc, Dc, Fc, outX, nullptr, nullptr, nullptr, nullptr, nullptr, nullptr);
}

// Round 4
// 954.137 us; speedup vs baseline: 1.1709x; 1.0279x over previous
//
#include <hip/hip_runtime.h>
#include <cstdint>
#include <cstddef>

typedef __bf16 bf16;
typedef __bf16 bf16x2 __attribute__((ext_vector_type(2)));
typedef __bf16 bf16x4 __attribute__((ext_vector_type(4)));
typedef __bf16 bf16x8 __attribute__((ext_vector_type(8)));
typedef float  f32x4  __attribute__((ext_vector_type(4)));
typedef float  f32x16 __attribute__((ext_vector_type(16)));
typedef __attribute__((address_space(1))) unsigned int u32_g;
typedef __attribute__((address_space(3))) unsigned int u32_l;

#define DI __device__ __forceinline__

constexpr int Bc = 2, Sc = 2048, Dc = 1024, Hc = 16, HDc = 64, Fc = 4096, Mc = 1024;
constexpr int NTc = Bc * Sc;  // 4096 tokens

DI void llds16(const bf16* g, bf16* l) {
  __builtin_amdgcn_global_load_lds((const u32_g*)g, (u32_l*)l, 16, 0, 0);
}
DI f32x4 cvt4(bf16x4 a) {
  f32x4 r; r[0] = (float)a[0]; r[1] = (float)a[1]; r[2] = (float)a[2]; r[3] = (float)a[3];
  return r;
}

// ---------------------------------------------------------------- dtype detector (inputs)
__global__ void k_detect(const unsigned short* __restrict__ x, int* __restrict__ flag)
{
  const int tid = threadIdx.x;  // 64
  int cnt = 0;
#pragma unroll
  for (int i = 0; i < 8; i++) {
    unsigned short h = x[tid * 8 + i];
    int e = (h >> 7) & 0xFF;
    if (e < 96 || e > 160) cnt++;
  }
#pragma unroll
  for (int off = 32; off > 0; off >>= 1) cnt += __shfl_down(cnt, off, 64);
  if (tid == 0) *flag = (cnt > 32) ? 1 : 0;
}

// ---------------------------------------------------------------- dtype-aware convert to bf16
__global__ __launch_bounds__(256)
void k_cvt(const void* __restrict__ src, bf16* __restrict__ dst, int n4, const int* __restrict__ flag)
{
  int i = blockIdx.x * 256 + threadIdx.x;
  if (i >= n4) return;
  bf16x4 o;
  if (*flag) {
    f32x4 v = ((const f32x4*)src)[i];
    o[0] = (bf16)v[0]; o[1] = (bf16)v[1]; o[2] = (bf16)v[2]; o[3] = (bf16)v[3];
  } else {
    o = ((const bf16x4*)src)[i];
  }
  ((bf16x4*)dst)[i] = o;
}

// ---------------------------------------------------------------- dtype-aware transpose [R][C] -> bf16 [C][R]
__global__ void k_transpose_dt(const void* __restrict__ src, bf16* __restrict__ dst,
                               int R, int C, const int* __restrict__ flag)
{
  __shared__ bf16 tile[32][33];
  const int c0 = blockIdx.x * 32, r0 = blockIdx.y * 32;
  const int tx = threadIdx.x, ty = threadIdx.y;
  const bool f32 = (*flag != 0);
  for (int i = ty; i < 32; i += 8) {
    size_t idx = (size_t)(r0 + i) * C + (c0 + tx);
    tile[i][tx] = f32 ? (bf16)((const float*)src)[idx] : ((const bf16*)src)[idx];
  }
  __syncthreads();
  for (int i = ty; i < 32; i += 8)
    dst[(size_t)(c0 + i) * R + (r0 + tx)] = tile[tx][i];
}

// ---------------------------------------------------------------- per-head V transpose: v[(b*S+s)][h*64+d] -> vt[(bh*64+d)][s]
__global__ void k_transpose_v(const bf16* __restrict__ v, bf16* __restrict__ vt)
{
  __shared__ bf16 tile[32][33];
  const int d0 = blockIdx.x * 32, s0 = blockIdx.y * 32;
  const int bh = blockIdx.z;
  const int b = bh >> 4, hh = bh & 15;
  const int tx = threadIdx.x, ty = threadIdx.y;
  for (int i = ty; i < 32; i += 8)
    tile[i][tx] = v[((size_t)(b * Sc + s0 + i)) * Dc + hh * HDc + d0 + tx];
  __syncthreads();
  for (int i = ty; i < 32; i += 8)
    vt[((size_t)(bh * HDc + d0 + i)) * Sc + s0 + tx] = tile[tx][i];
}

// ---------------------------------------------------------------- GEMM (NT): C[M][N] = A[M][K] * Bt[N][K]^T
// R2 lesson: every N=1024 GEMM at grid(8,32)=256 blocks = 1 block/CU -> the
// 4 waves are barrier-locked with zero cross-phase overlap (m114 needs ~3
// blocks/CU). Fix = batched dispatches:
//   EPI_SEGC_*: N=3072 fused (qkv / pqkv), col>>10 routes to 3 contiguous
//     8MiB output slots (B-slots are consecutive allocs).
//   EPI_SEG2_RELU: M=8192 fused l0-GEMM, rowb>>12 routes seg1 to out2
//     (passed via outF, reinterpreted bf16*).
//   EPI_ATOMIC_F32: split-K (blockIdx.z) fp32 atomicAdd epilogue; out must
//     be pre-filled with the residual (outX holds h2).
enum EpiMode { EPI_BF16 = 0, EPI_BIAS_BF16, EPI_BIAS_RELU_BF16, EPI_BIAS_RESB_F32,
               EPI_SILU_BF16, EPI_DZ_BF16, EPI_RESX_BF16, EPI_RESF_F32,
               EPI_SEGC_BF16, EPI_SEGC_BIAS_BF16, EPI_SEG2_RELU_BF16, EPI_ATOMIC_F32 };

template <int EPI>
__global__ __launch_bounds__(256)
void k_gemm(const bf16* __restrict__ A, const bf16* __restrict__ Bt,
            int Mr, int Nr, int Kr,
            float* outF, bf16* outB,
            const bf16* __restrict__ bias, const bf16* auxB,
            const float* resF,
            const void* __restrict__ resX, const int* __restrict__ flag)
{
  __shared__ bf16 As[128 * 32];
  __shared__ bf16 Bs[128 * 32];
  const int tid = threadIdx.x;
  const int w = tid >> 6, l = tid & 63;
  const int wr = w >> 1, wc = w & 1;
  const int row0 = blockIdx.y * 128, col0 = blockIdx.x * 128;

  const f32x4 vzero = {0.f, 0.f, 0.f, 0.f};
  f32x4 acc[4][4];
#pragma unroll
  for (int i = 0; i < 4; i++)
#pragma unroll
    for (int j = 0; j < 4; j++) acc[i][j] = vzero;

  const bf16* Ag = A + (size_t)(row0 + w * 16 + (l >> 2)) * Kr + ((l & 3) << 3);
  const bf16* Bg = Bt + (size_t)(col0 + w * 16 + (l >> 2)) * Kr + ((l & 3) << 3);
  bf16* AsW = &As[w * 512];
  bf16* BsW = &Bs[w * 512];
  const size_t rowHop = (size_t)64 * Kr;

  const int chunk = Kr / gridDim.z;           // split-K support (z=1 -> full K)
  const int kbeg = blockIdx.z * chunk;

  for (int k0 = kbeg; k0 < kbeg + chunk; k0 += 32) {
    __syncthreads();
    llds16(Ag + k0, AsW);
    llds16(Ag + rowHop + k0, AsW + 2048);
    llds16(Bg + k0, BsW);
    llds16(Bg + rowHop + k0, BsW + 2048);
    __syncthreads();
    bf16x8 af[4], bfr[4];
#pragma unroll
    for (int mt = 0; mt < 4; mt++)
      af[mt] = *(const bf16x8*)&As[(wr * 64 + mt * 16 + (l & 15)) * 32 + (l >> 4) * 8];
#pragma unroll
    for (int nt = 0; nt < 4; nt++)
      bfr[nt] = *(const bf16x8*)&Bs[(wc * 64 + nt * 16 + (l & 15)) * 32 + (l >> 4) * 8];
#pragma unroll
    for (int mt = 0; mt < 4; mt++)
#pragma unroll
      for (int nt = 0; nt < 4; nt++)
        acc[mt][nt] = __builtin_amdgcn_mfma_f32_16x16x32_bf16(af[mt], bfr[nt], acc[mt][nt], 0, 0, 0);
  }

  const bool f32res = (EPI == EPI_RESX_BF16) ? (*flag != 0) : false;
  // bias preload (before ANY store exists -> fully parallel)
  float biasv[4];
  if (EPI == EPI_BIAS_BF16 || EPI == EPI_BIAS_RELU_BF16 || EPI == EPI_BIAS_RESB_F32 ||
      EPI == EPI_SEGC_BIAS_BF16 || EPI == EPI_SEG2_RELU_BF16) {
#pragma unroll
    for (int nt = 0; nt < 4; nt++)
      biasv[nt] = (float)bias[col0 + wc * 64 + nt * 16 + (l & 15)];
  }
  // C/D layout (verified m89/m91): col = lane&15, row = (lane>>4)*4 + reg
#pragma unroll
  for (int mt = 0; mt < 4; mt++) {
    const int rowb = row0 + wr * 64 + mt * 16 + ((l >> 4) << 2);
    // phase 1: batch-gather aux/res for this mt (16 independent loads)
    float av[4][4];
    if (EPI == EPI_SILU_BF16 || EPI == EPI_DZ_BF16 || EPI == EPI_BIAS_RESB_F32) {
#pragma unroll
      for (int nt = 0; nt < 4; nt++) {
        const int col = col0 + wc * 64 + nt * 16 + (l & 15);
#pragma unroll
        for (int r = 0; r < 4; r++)
          av[nt][r] = (float)auxB[(size_t)(rowb + r) * Nr + col];
      }
    }
    if (EPI == EPI_RESF_F32) {
#pragma unroll
      for (int nt = 0; nt < 4; nt++) {
        const int col = col0 + wc * 64 + nt * 16 + (l & 15);
#pragma unroll
        for (int r = 0; r < 4; r++)
          av[nt][r] = resF[(size_t)(rowb + r) * Nr + col];
      }
    }
    if (EPI == EPI_RESX_BF16) {
#pragma unroll
      for (int nt = 0; nt < 4; nt++) {
        const int col = col0 + wc * 64 + nt * 16 + (l & 15);
#pragma unroll
        for (int r = 0; r < 4; r++) {
          const size_t idx = (size_t)(rowb + r) * Nr + col;
          av[nt][r] = f32res ? ((const float*)resX)[idx] : (float)((const bf16*)resX)[idx];
        }
      }
    }
    // phase 2: compute + store
#pragma unroll
    for (int nt = 0; nt < 4; nt++) {
      const int col = col0 + wc * 64 + nt * 16 + (l & 15);
#pragma unroll
      for (int r = 0; r < 4; r++) {
        const size_t idx = (size_t)(rowb + r) * Nr + col;
        float v = acc[mt][nt][r];
        if (EPI == EPI_BF16) { outB[idx] = (bf16)v; }
        else if (EPI == EPI_BIAS_BF16) { outB[idx] = (bf16)(v + biasv[nt]); }
        else if (EPI == EPI_BIAS_RELU_BF16) { outB[idx] = (bf16)fmaxf(v + biasv[nt], 0.f); }
        else if (EPI == EPI_BIAS_RESB_F32) { outF[idx] = v + biasv[nt] + av[nt][r]; }
        else if (EPI == EPI_SILU_BF16) {
          float s1v = av[nt][r];
          float sl = s1v / (1.f + __expf(-s1v));
          outB[idx] = (bf16)(sl * v);
        }
        else if (EPI == EPI_DZ_BF16) { outB[idx] = (bf16)(av[nt][r] > 0.f ? v : 0.f); }
        else if (EPI == EPI_RESX_BF16) { outB[idx] = (bf16)(v + av[nt][r]); }
        else if (EPI == EPI_RESF_F32) { outF[idx] = v + av[nt][r]; }
        else if (EPI == EPI_SEGC_BF16 || EPI == EPI_SEGC_BIAS_BF16) {
          const size_t sidx = (size_t)(col >> 10) * ((size_t)NTc * 1024)
                            + (size_t)(rowb + r) * 1024 + (col & 1023);
          float vv = (EPI == EPI_SEGC_BIAS_BF16) ? (v + biasv[nt]) : v;
          outB[sidx] = (bf16)vv;
        }
        else if (EPI == EPI_SEG2_RELU_BF16) {
          bf16* ob = (rowb >> 12) ? (bf16*)outF : outB;
          ob[(size_t)((rowb + r) & 4095) * 1024 + col] = (bf16)fmaxf(v + biasv[nt], 0.f);
        }
        else if (EPI == EPI_ATOMIC_F32) {
          atomicAdd(&outF[(size_t)(rowb + r) * Nr + col], v);
        }
      }
    }
  }
}

// ---------------------------------------------------------------- GEMM (TN) split-K: C[i][j] += sum_t X[t][i]*Y[t][j]
__global__ __launch_bounds__(256)
void k_gemm_tn(const bf16* __restrict__ X, const bf16* __restrict__ Y, int Kt,
               float* __restrict__ out)
{
  __shared__ bf16 As[128 * 36];
  __shared__ bf16 Bs[128 * 36];
  const int tid = threadIdx.x;
  const int w = tid >> 6, l = tid & 63;
  const int wr = w >> 1, wc = w & 1;
  const int row0 = blockIdx.y * 128, col0 = blockIdx.x * 128;
  const int iofs = (tid & 15) * 8;   // 0..120
  const int tp   = (tid >> 4) * 2;   // 0..30

  const f32x4 vzero = {0.f, 0.f, 0.f, 0.f};
  f32x4 acc[4][4];
#pragma unroll
  for (int i = 0; i < 4; i++)
#pragma unroll
    for (int j = 0; j < 4; j++) acc[i][j] = vzero;

  const int chunk = Kt / gridDim.z;
  const int tbeg = blockIdx.z * chunk;

  for (int t0 = tbeg; t0 < tbeg + chunk; t0 += 32) {
    __syncthreads();
    bf16x8 a0 = *(const bf16x8*)&X[(size_t)(t0 + tp) * 1024 + row0 + iofs];
    bf16x8 a1 = *(const bf16x8*)&X[(size_t)(t0 + tp + 1) * 1024 + row0 + iofs];
    bf16x8 b0 = *(const bf16x8*)&Y[(size_t)(t0 + tp) * 1024 + col0 + iofs];
    bf16x8 b1 = *(const bf16x8*)&Y[(size_t)(t0 + tp + 1) * 1024 + col0 + iofs];
#pragma unroll
    for (int e = 0; e < 8; e++) {
      bf16x2 pa; pa[0] = a0[e]; pa[1] = a1[e];
      bf16x2 pb; pb[0] = b0[e]; pb[1] = b1[e];
      *(bf16x2*)&As[(iofs + e) * 36 + tp] = pa;
      *(bf16x2*)&Bs[(iofs + e) * 36 + tp] = pb;
    }
    __syncthreads();
    bf16x8 af[4], bfr[4];
#pragma unroll
    for (int mt = 0; mt < 4; mt++) {
      const int base = (wr * 64 + mt * 16 + (l & 15)) * 36 + (l >> 4) * 8;
      bf16x4 lo = *(const bf16x4*)&As[base];
      bf16x4 hi = *(const bf16x4*)&As[base + 4];
#pragma unroll
      for (int e = 0; e < 4; e++) { af[mt][e] = lo[e]; af[mt][4 + e] = hi[e]; }
    }
#pragma unroll
    for (int nt = 0; nt < 4; nt++) {
      const int base = (wc * 64 + nt * 16 + (l & 15)) * 36 + (l >> 4) * 8;
      bf16x4 lo = *(const bf16x4*)&Bs[base];
      bf16x4 hi = *(const bf16x4*)&Bs[base + 4];
#pragma unroll
      for (int e = 0; e < 4; e++) { bfr[nt][e] = lo[e]; bfr[nt][4 + e] = hi[e]; }
    }
#pragma unroll
    for (int mt = 0; mt < 4; mt++)
#pragma unroll
      for (int nt = 0; nt < 4; nt++)
        acc[mt][nt] = __builtin_amdgcn_mfma_f32_16x16x32_bf16(af[mt], bfr[nt], acc[mt][nt], 0, 0, 0);
  }

#pragma unroll
  for (int mt = 0; mt < 4; mt++) {
    const int rowb = row0 + wr * 64 + mt * 16 + ((l >> 4) << 2);
#pragma unroll
    for (int nt = 0; nt < 4; nt++) {
      const int col = col0 + wc * 64 + nt * 16 + (l & 15);
#pragma unroll
      for (int r = 0; r < 4; r++)
        atomicAdd(&out[(size_t)(rowb + r) * 1024 + col], acc[mt][nt][r]);
    }
  }
}

// ---------------------------------------------------------------- RMSNorm variants
__global__ __launch_bounds__(256)
void k_rmsnorm_dt(const void* __restrict__ x, const bf16* __restrict__ w, bf16* __restrict__ out,
                  const int* __restrict__ flag)
{
  const int row = blockIdx.x;
  const int tid = threadIdx.x;
  f32x4 xv;
  if (*flag) xv = *(const f32x4*)((const float*)x + (size_t)row * Dc + tid * 4);
  else       xv = cvt4(*(const bf16x4*)((const bf16*)x + (size_t)row * Dc + tid * 4));
  float ss = xv[0] * xv[0] + xv[1] * xv[1] + xv[2] * xv[2] + xv[3] * xv[3];
#pragma unroll
  for (int off = 32; off > 0; off >>= 1) ss += __shfl_down(ss, off, 64);
  __shared__ float part[4];
  if ((tid & 63) == 0) part[tid >> 6] = ss;
  __syncthreads();
  float tot = part[0] + part[1] + part[2] + part[3];
  float inv = 1.f / (sqrtf(tot) * 0.03125f + 1e-8f);
  bf16x4 wb = *(const bf16x4*)(w + tid * 4);
  bf16x4 ov;
  ov[0] = (bf16)((float)wb[0] * xv[0] * inv);
  ov[1] = (bf16)((float)wb[1] * xv[1] * inv);
  ov[2] = (bf16)((float)wb[2] * xv[2] * inv);
  ov[3] = (bf16)((float)wb[3] * xv[3] * inv);
  *(bf16x4*)(out + (size_t)row * Dc + tid * 4) = ov;
}

__global__ __launch_bounds__(256)
void k_rmsnorm_b(const bf16* __restrict__ x, const bf16* __restrict__ w, bf16* __restrict__ out)
{
  const int row = blockIdx.x;
  const int tid = threadIdx.x;
  f32x4 xv = cvt4(*(const bf16x4*)(x + (size_t)row * Dc + tid * 4));
  float ss = xv[0] * xv[0] + xv[1] * xv[1] + xv[2] * xv[2] + xv[3] * xv[3];
#pragma unroll
  for (int off = 32; off > 0; off >>= 1) ss += __shfl_down(ss, off, 64);
  __shared__ float part[4];
  if ((tid & 63) == 0) part[tid >> 6] = ss;
  __syncthreads();
  float tot = part[0] + part[1] + part[2] + part[3];
  float inv = 1.f / (sqrtf(tot) * 0.03125f + 1e-8f);
  bf16x4 wb = *(const bf16x4*)(w + tid * 4);
  bf16x4 ov;
  ov[0] = (bf16)((float)wb[0] * xv[0] * inv);
  ov[1] = (bf16)((float)wb[1] * xv[1] * inv);
  ov[2] = (bf16)((float)wb[2] * xv[2] * inv);
  ov[3] = (bf16)((float)wb[3] * xv[3] * inv);
  *(bf16x4*)(out + (size_t)row * Dc + tid * 4) = ov;
}

__global__ __launch_bounds__(256)
void k_rmsnorm_f(const float* __restrict__ x, const bf16* __restrict__ w, bf16* __restrict__ out)
{
  const int row = blockIdx.x;
  const int tid = threadIdx.x;
  f32x4 xv = *(const f32x4*)(x + (size_t)row * Dc + tid * 4);
  float ss = xv[0] * xv[0] + xv[1] * xv[1] + xv[2] * xv[2] + xv[3] * xv[3];
#pragma unroll
  for (int off = 32; off > 0; off >>= 1) ss += __shfl_down(ss, off, 64);
  __shared__ float part[4];
  if ((tid & 63) == 0) part[tid >> 6] = ss;
  __syncthreads();
  float tot = part[0] + part[1] + part[2] + part[3];
  float inv = 1.f / (sqrtf(tot) * 0.03125f + 1e-8f);
  bf16x4 wb = *(const bf16x4*)(w + tid * 4);
  bf16x4 ov;
  ov[0] = (bf16)((float)wb[0] * xv[0] * inv);
  ov[1] = (bf16)((float)wb[1] * xv[1] * inv);
  ov[2] = (bf16)((float)wb[2] * xv[2] * inv);
  ov[3] = (bf16)((float)wb[3] * xv[3] * inv);
  *(bf16x4*)(out + (size_t)row * Dc + tid * 4) = ov;
}

// ---------------------------------------------------------------- RoPE in-place on bf16 q,k
__global__ __launch_bounds__(256)
void k_rope(bf16* __restrict__ q, bf16* __restrict__ kx)
{
  const int idx = blockIdx.x * 256 + threadIdx.x;  // NT*H = 65536
  const int t = idx >> 4, hh = idx & 15;
  const int s = t & (Sc - 1);
  float sn[32], cs[32];
#pragma unroll
  for (int i = 0; i < 32; i++) {
    float f = expf(-(float)i * 0.28782313662425574f);  // ln(10000)/32
    float ang = (float)s * f;
    sn[i] = sinf(ang);
    cs[i] = cosf(ang);
  }
  for (int pass = 0; pass < 2; pass++) {
    bf16* p = (pass ? kx : q) + (size_t)t * Dc + hh * HDc;
    float xb[64], ob[64];
#pragma unroll
    for (int j = 0; j < 16; j++) *(f32x4*)&xb[j * 4] = cvt4(*(const bf16x4*)(p + j * 4));
#pragma unroll
    for (int i = 0; i < 32; i++) {
      float x1 = xb[2 * i], x2 = xb[2 * i + 1];
      ob[i] = x1 * cs[i] - x2 * sn[i];
      ob[32 + i] = x1 * sn[i] + x2 * cs[i];
    }
#pragma unroll
    for (int j = 0; j < 16; j++) {
      bf16x4 o4;
      o4[0] = (bf16)ob[j * 4]; o4[1] = (bf16)ob[j * 4 + 1];
      o4[2] = (bf16)ob[j * 4 + 2]; o4[3] = (bf16)ob[j * 4 + 3];
      *(bf16x4*)(p + j * 4) = o4;
    }
  }
}

// ---------------------------------------------------------------- MFMA flash attention: swapped-QK^T, lane-local softmax
// R3 rewrite (shfl-chain structure plateaued at 127 TF, R0-R2 invariant).
// S^T = mfma_32x32x16(A=K, B=Q^T): C/D col = q = lane&31 (m74/m101 layout)
// -> each lane owns ONE q-row; 16 regs + partner lane (l^32) hold its 32 k.
// Online-softmax state (m,l) is a per-lane SCALAR; row-reduce = 15 reg-max
// + 1 shfl_xor(32). PV computed as O^T = mfma(A=V^T, B=P^T) (same col=q
// layout) so the alpha-rescale is scalar too. P^T fragment built in-register:
// bf16x2 pack + 4 shfl_xor(32) word exchanges (T12 pattern). Zero LDS, zero
// barriers; wave = 32 q-rows, block = 4 indep waves, grid 512 (LPT heavy-q
// first; bh=blk&31 keeps head->XCD affinity). K-frag k=(reg&3)+8*(reg>>2)+
// 4*hi; A/B frags are 16B-contiguous row loads (V via pre-transposed Vt).
__global__ __launch_bounds__(256)
void k_attn(const bf16* __restrict__ q, const bf16* __restrict__ kx,
            const bf16* __restrict__ vt, bf16* __restrict__ o)
{
  union UV { bf16x8 v; unsigned int u[4]; };
  union UH { bf16x2 h; unsigned int u; };

  const int blk = blockIdx.x;
  const int g  = 15 - (blk >> 5);      // heavy q first (LPT)
  const int bh = blk & 31;             // same head -> same XCD residue
  const int b = bh >> 4, hh = bh & 15;
  const int tid = threadIdx.x;
  const int w = tid >> 6, l = tid & 63;
  const int hi = l >> 5, lq = l & 31;

  const int q0 = g * 128 + w * 32;     // this wave's 32 q-rows
  const int ntiles = g * 4 + w + 1;    // 32-wide kv tiles up to the diagonal

  const bf16* kb = kx + (size_t)b * Sc * Dc + hh * HDc;
  const bf16* vb = vt + (size_t)bh * HDc * Sc;

  // Q fragments (B-operand): lane holds Q[q0+lq][ds*16 + hi*8 .. +8], pre-scaled
  bf16x8 qf[4];
  {
    const bf16* qp = q + ((size_t)(b * Sc + q0 + lq)) * Dc + hh * HDc + hi * 8;
#pragma unroll
    for (int ds = 0; ds < 4; ds++) {
      qf[ds] = *(const bf16x8*)(qp + ds * 16);
#pragma unroll
      for (int j = 0; j < 8; j++) qf[ds][j] = (bf16)((float)qf[ds][j] * 0.125f);
    }
  }

  f32x16 oacc0, oacc1;                 // O^T[d][q]: d-tiles 0-31 / 32-63
#pragma unroll
  for (int j = 0; j < 16; j++) { oacc0[j] = 0.f; oacc1[j] = 0.f; }
  float mrun = -3.0e38f, lrun = 0.f;

  for (int t0 = 0; t0 < ntiles; t0++) {
    const int kk0 = t0 * 32;

    // QK^T: A = K[32k][16d-slice] (lane: K[kk0+lq][ds*16+hi*8..+8])
    const bf16* kp = kb + (size_t)(kk0 + lq) * Dc + hi * 8;
    f32x16 sacc;
#pragma unroll
    for (int j = 0; j < 16; j++) sacc[j] = 0.f;
#pragma unroll
    for (int ds = 0; ds < 4; ds++) {
      bf16x8 kf = *(const bf16x8*)(kp + ds * 16);
      sacc = __builtin_amdgcn_mfma_f32_32x32x16_bf16(kf, qf[ds], sacc, 0, 0, 0);
    }

    if (t0 == ntiles - 1) {            // diagonal tile: causal mask (kk0 == q0)
#pragma unroll
      for (int reg = 0; reg < 16; reg++) {
        const int kidx = (reg & 3) + 8 * (reg >> 2) + 4 * hi;
        sacc[reg] = (kidx > lq) ? -3.0e38f : sacc[reg];
      }
    }

    // per-lane online softmax (q = q0 + lq)
    float mx = sacc[0];
#pragma unroll
    for (int reg = 1; reg < 16; reg++) mx = fmaxf(mx, sacc[reg]);
    mx = fmaxf(mx, __shfl_xor(mx, 32, 64));

    const float mnew = fmaxf(mrun, mx);
    const float al = __expf(mrun - mnew);
    mrun = mnew;
    float p[16], ps = 0.f;
#pragma unroll
    for (int reg = 0; reg < 16; reg++) { p[reg] = __expf(sacc[reg] - mnew); ps += p[reg]; }
    ps += __shfl_xor(ps, 32, 64);
    lrun = lrun * al + ps;
#pragma unroll
    for (int j = 0; j < 16; j++) { oacc0[j] *= al; oacc1[j] *= al; }

    // pack P -> bf16x2 words; 4 shfl_xor(32) route k-halves into B-frags:
    // pa0 = P[q][k 0..15], pa1 = P[q][k 16..31] (k = kb*16 + hi*8 + j)
    unsigned int wv[8];
#pragma unroll
    for (int m = 0; m < 8; m++) {
      UH t; t.h[0] = (bf16)p[2 * m]; t.h[1] = (bf16)p[2 * m + 1];
      wv[m] = t.u;
    }
    const unsigned int ex0 = __shfl_xor(hi ? wv[0] : wv[2], 32, 64);
    const unsigned int ex1 = __shfl_xor(hi ? wv[1] : wv[3], 32, 64);
    const unsigned int ex2 = __shfl_xor(hi ? wv[4] : wv[6], 32, 64);
    const unsigned int ex3 = __shfl_xor(hi ? wv[5] : wv[7], 32, 64);
    UV pa0, pa1;
    pa0.u[0] = hi ? ex0 : wv[0];  pa0.u[1] = hi ? ex1 : wv[1];
    pa0.u[2] = hi ? wv[2] : ex0;  pa0.u[3] = hi ? wv[3] : ex1;
    pa1.u[0] = hi ? ex2 : wv[4];  pa1.u[1] = hi ? ex3 : wv[5];
    pa1.u[2] = hi ? wv[6] : ex2;  pa1.u[3] = hi ? wv[7] : ex3;

    // PV: A = V^T[32d][16k] from Vt (lane: Vt[dt*32+lq][kk0+kb*16+hi*8..+8])
    const bf16* vp = vb + (size_t)lq * Sc + kk0 + hi * 8;
    bf16x8 v00 = *(const bf16x8*)(vp);
    bf16x8 v10 = *(const bf16x8*)(vp + 16);
    bf16x8 v01 = *(const bf16x8*)(vp + (size_t)32 * Sc);
    bf16x8 v11 = *(const bf16x8*)(vp + (size_t)32 * Sc + 16);
    oacc0 = __builtin_amdgcn_mfma_f32_32x32x16_bf16(v00, pa0.v, oacc0, 0, 0, 0);
    oacc0 = __builtin_amdgcn_mfma_f32_32x32x16_bf16(v10, pa1.v, oacc0, 0, 0, 0);
    oacc1 = __builtin_amdgcn_mfma_f32_32x32x16_bf16(v01, pa0.v, oacc1, 0, 0, 0);
    oacc1 = __builtin_amdgcn_mfma_f32_32x32x16_bf16(v11, pa1.v, oacc1, 0, 0, 0);
  }

  // epilogue: O^T reg pairs are d-adjacent -> 4B dword stores into o[q][d]
  const float inv = 1.f / lrun;
  bf16* op = o + ((size_t)(b * Sc + q0 + lq)) * Dc + hh * HDc;
#pragma unroll
  for (int m = 0; m < 8; m++) {
    const int d0 = (2 * m & 3) + 8 * (m >> 1) + 4 * hi;
    UH t0v; t0v.h[0] = (bf16)(oacc0[2 * m] * inv); t0v.h[1] = (bf16)(oacc0[2 * m + 1] * inv);
    *(unsigned int*)(op + d0) = t0v.u;
    UH t1v; t1v.h[0] = (bf16)(oacc1[2 * m] * inv); t1v.h[1] = (bf16)(oacc1[2 * m + 1] * inv);
    *(unsigned int*)(op + 32 + d0) = t1v.u;
  }
}

// ---------------------------------------------------------------- dp = 2(pred-vf)/M in-place + loss
__global__ __launch_bounds__(256)
void k_dpred(bf16* __restrict__ predDp, const bf16* __restrict__ vf, float* __restrict__ loss)
{
  __shared__ float red[4];
  const int tid = threadIdx.x;
  const size_t n8 = (size_t)NTc * Mc / 8;
  float lacc = 0.f;
  for (size_t i = (size_t)blockIdx.x * 256 + tid; i < n8; i += (size_t)gridDim.x * 256) {
    bf16x8 p8 = ((const bf16x8*)predDp)[i];
    bf16x8 v8 = ((const bf16x8*)vf)[i];
    bf16x8 d8;
#pragma unroll
    for (int e = 0; e < 8; e++) {
      float df = (float)p8[e] - (float)v8[e];
      lacc += df * df;
      d8[e] = (bf16)(df * (2.0f / 1024.0f));
    }
    ((bf16x8*)predDp)[i] = d8;
  }
#pragma unroll
  for (int off = 32; off > 0; off >>= 1) lacc += __shfl_down(lacc, off, 64);
  if ((tid & 63) == 0) red[tid >> 6] = lacc;
  __syncthreads();
  if (tid == 0) atomicAdd(loss, red[0] + red[1] + red[2] + red[3]);
}

// ---------------------------------------------------------------- colsum: out[c] += sum over a row chunk
__global__ __launch_bounds__(256)
void k_colsum(const bf16* __restrict__ X, float* __restrict__ out, int C, int rowsPer)
{
  int c = blockIdx.x * 256 + threadIdx.x;
  int r0 = blockIdx.y * rowsPer;
  float s = 0.f;
#pragma unroll 8
  for (int r = r0; r < r0 + rowsPer; r++) s += (float)X[(size_t)r * C + c];
  atomicAdd(&out[c], s);
}

// ---------------------------------------------------------------- dtype-aware param/momentum update -> fp32 d_out
__global__ __launch_bounds__(256)
void k_update_dt(const void* __restrict__ p0w, const void* __restrict__ p0b,
                 const void* __restrict__ p1w, const void* __restrict__ p1b,
                 const void* __restrict__ m0w, const void* __restrict__ m0b,
                 const void* __restrict__ m1w, const void* __restrict__ m1b,
                 const float* __restrict__ g0wF, const float* __restrict__ g0b,
                 const float* __restrict__ g1wF, const float* __restrict__ g1b,
                 const float* __restrict__ loss, const int* __restrict__ flag,
                 float* __restrict__ outP, float* __restrict__ outM)
{
  const int i = blockIdx.x * 256 + threadIdx.x;  // < 2099200 exactly
  const bool upd = (loss[0] >= 0.1f * 1024.f * 4096.f);  // avg_loss >= THRESH
  const bool f32 = (*flag != 0);
  constexpr int W = 1024 * 1024;
  const void *pp, *pm; int j; float g;
  if (i < W) { pp = p0w; pm = m0w; j = i; g = g0wF[i]; }
  else if (i < W + 1024) { j = i - W; pp = p0b; pm = m0b; g = g0b[j]; }
  else if (i < 2 * W + 1024) { j = i - W - 1024; pp = p1w; pm = m1w; g = g1wF[j]; }
  else { j = i - 2 * W - 1024; pp = p1b; pm = m1b; g = g1b[j]; }
  float p = f32 ? ((const float*)pp)[j] : (float)((const bf16*)pp)[j];
  float m = f32 ? ((const float*)pm)[j] : (float)((const bf16*)pm)[j];
  float nm = 0.9f * m - 0.01f * g;
  float np = 0.99f * p + nm;
  outP[i] = upd ? np : p;
  outM[i] = upd ? nm : m;
}

// ================================================================ host
extern "C" void kernel_launch(void* const* d_in, const int* in_sizes, int n_in,
                              void* d_out, int out_size, void* d_ws, size_t ws_size,
                              hipStream_t stream)
{
  (void)in_sizes; (void)n_in; (void)out_size; (void)ws_size;
  const void* x   = d_in[0];
  const void* wq  = d_in[2];
  const void* wk  = d_in[3];
  const void* wv  = d_in[4];
  const void* wo  = d_in[5];
  const void* n1  = d_in[6];
  const void* n2  = d_in[7];
  const void* n3  = d_in[8];
  const void* fw1 = d_in[9];
  const void* fw2 = d_in[10];
  const void* fw3 = d_in[11];
  const void* pkw = d_in[12];
  const void* pkb = d_in[13];
  const void* pvw = d_in[14];
  const void* pvb = d_in[15];
  const void* pqw = d_in[16];
  const void* pqb = d_in[17];
  const void* l0w = d_in[18];
  const void* l0b = d_in[19];
  const void* l1w = d_in[20];
  const void* l1b = d_in[21];
  const void* m0w = d_in[22];
  const void* m0b = d_in[23];
  const void* m1w = d_in[24];
  const void* m1b = d_in[25];

  char* ws = (char*)d_ws;
  size_t off = 0;
  auto alloc = [&](size_t bytes) -> char* {
    char* p = ws + off;
    off += (bytes + 255) & ~(size_t)255;
    return p;
  };

  const size_t DD = (size_t)Dc * Dc;   // 1M elems
  const size_t ND = (size_t)NTc * Dc;  // 4M elems
  const size_t MB8 = 2 * ND;           // 8 MiB
  const size_t M1 = DD;                // 1M elems

  // --- weight region W: 8M bf16 elems (16 MiB), phase-cycled
  bf16* W = (bf16*)alloc(2 * 8 * M1);
  bf16 *wqT = W, *wkT = W + M1, *wvT = W + 2 * M1, *woT = W + 3 * M1;   // contiguous [3072][1024] for fused qkv
  bf16 *pqT = W + 4 * M1, *pkT = W + 5 * M1, *pvT = W + 6 * M1, *l0T = W + 7 * M1;  // pqT..pvT = fused [3072][1024]
  bf16 *l1T = W + M1;          // staged after wo-GEMM (wkT dead)
  bf16 *h1buf = W + 2 * M1;    // h1 [4096][1024] after fused l0 (wvT/woT/pqT/pkT dead; l0T untouched)
  bf16 *l1c = W;               // staged after pred-GEMM (over wqT)
  bf16 *w1T = W + 4 * M1;      // staged after gemm_tn's (h1buf upper, pvT, l0T dead)
  bf16 *w2T = W;               // staged after grads (l1c/l1T/h1buf-lower dead)
  bf16 *w3T = W + 4 * M1;      // staged after ffn1 (w1T dead)

  // --- 5 activation slots, B0..B3 contiguous (seg-routing + s1 span rely on this)
  bf16* B0 = (bf16*)alloc(MB8);  // q -> hn2 -> h1r -> (s1)
  bf16* B1 = (bf16*)alloc(MB8);  // k -> qlmm -> pred/dp -> (s1)
  bf16* B2 = (bf16*)alloc(MB8);  // v -> kf -> (s1)
  bf16* B3 = (bf16*)alloc(MB8);  // o -> vf -> dz -> (s1)
  bf16* B4 = (bf16*)alloc(MB8);  // Vt (attn) -> hb -> hn3
  bf16* s1 = B0;                 // [NT][F] = 32 MiB
  bf16* VtG = B4;                // [BH][HD][S] per-head transposed V, dead before hb

  // --- smalls
  float* g0b = (float*)alloc(4 * 1024);
  float* g1b = (float*)alloc(4 * 1024);
  float* lossb = (float*)alloc(256);
  int*   flag  = (int*)alloc(256);
  bf16* n1c = (bf16*)alloc(2 * 1024);
  bf16* n2c = (bf16*)alloc(2 * 1024);
  bf16* n3c = (bf16*)alloc(2 * 1024);
  bf16* bqkv = (bf16*)alloc(2 * 3072);   // [bq;bk;bv] contiguous for fused pqkv
  bf16* b0c = (bf16*)alloc(2 * 1024);
  bf16* b1c = (bf16*)alloc(2 * 1024);

  // --- output regions (fp32)
  float* outX = (float*)d_out;                 // hn(bf16 head), then h2 fp32, then final out fp32
  float* outP = outX + ND;                     // new params (l0w,l0b,l1w,l1b)
  float* outM = outP + (2 * DD + 2048);        // new momenta; hosts g0wF/g1wF pre-update
  float* g0wF = outM;                          // [1M] grad l0_w
  float* g1wF = outM + M1 + 1024;              // [1M] grad l1_w
  bf16*  hn   = (bf16*)outX;                   // bf16 hn in first 8 MiB of outX, dead before h2

  const dim3 tb(32, 8);

  hipMemsetAsync(lossb, 0, sizeof(float), stream);
  hipMemsetAsync(g0b, 0, 4 * 1024, stream);
  hipMemsetAsync(g1b, 0, 4 * 1024, stream);
  hipMemsetAsync(outM, 0, (2 * M1 + 2048) * sizeof(float), stream);  // zero g0wF/g1wF for split-K atomics
  k_detect<<<1, 64, 0, stream>>>((const unsigned short*)x, flag);

  // small cvts
  k_cvt<<<1, 256, 0, stream>>>(n1, n1c, 256, flag);
  k_cvt<<<1, 256, 0, stream>>>(n2, n2c, 256, flag);
  k_cvt<<<1, 256, 0, stream>>>(n3, n3c, 256, flag);
  k_cvt<<<1, 256, 0, stream>>>(pqb, bqkv, 256, flag);
  k_cvt<<<1, 256, 0, stream>>>(pkb, bqkv + 1024, 256, flag);
  k_cvt<<<1, 256, 0, stream>>>(pvb, bqkv + 2048, 256, flag);
  k_cvt<<<1, 256, 0, stream>>>(l0b, b0c, 256, flag);
  k_cvt<<<1, 256, 0, stream>>>(l1b, b1c, 256, flag);

  // phase-1 weight transposes
  k_transpose_dt<<<dim3(32, 32), tb, 0, stream>>>(wq, wqT, Dc, Dc, flag);
  k_transpose_dt<<<dim3(32, 32), tb, 0, stream>>>(wk, wkT, Dc, Dc, flag);
  k_transpose_dt<<<dim3(32, 32), tb, 0, stream>>>(wv, wvT, Dc, Dc, flag);
  k_transpose_dt<<<dim3(32, 32), tb, 0, stream>>>(wo, woT, Dc, Dc, flag);
  k_transpose_dt<<<dim3(32, 32), tb, 0, stream>>>(pqw, pqT, Dc, Mc, flag);
  k_transpose_dt<<<dim3(32, 32), tb, 0, stream>>>(pkw, pkT, Dc, Mc, flag);
  k_transpose_dt<<<dim3(32, 32), tb, 0, stream>>>(pvw, pvT, Dc, Mc, flag);
  k_transpose_dt<<<dim3(32, 32), tb, 0, stream>>>(l0w, l0T, Mc, Mc, flag);

  // ---- attention
  k_rmsnorm_dt<<<NTc, 256, 0, stream>>>(x, n1c, hn, flag);
  // fused qkv: N=3072, 768 blocks = 3/CU; col>>10 routes to B0/B1/B2
  k_gemm<EPI_SEGC_BF16><<<dim3(24, 32), 256, 0, stream>>>(hn, wqT, NTc, 3072, Dc, nullptr, B0, nullptr, nullptr, nullptr, nullptr, nullptr);
  k_transpose_v<<<dim3(2, 64, 32), tb, 0, stream>>>(B2, VtG);   // per-head V^T -> B4
  k_rope<<<256, 256, 0, stream>>>(B0, B1);
  k_attn<<<512, 256, 0, stream>>>(B0, B1, VtG, B3);
  k_gemm<EPI_RESX_BF16><<<dim3(8, 32), 256, 0, stream>>>(B3, woT, NTc, Dc, Dc, nullptr, B4, nullptr, nullptr, nullptr, x, flag);  // hb -> B4
  k_transpose_dt<<<dim3(32, 32), tb, 0, stream>>>(l1w, l1T, Mc, Mc, flag);

  // ---- LMM forward
  k_rmsnorm_b<<<NTc, 256, 0, stream>>>(B4, n2c, B0);   // hn2 -> B0
  // fused pqkv: qlmm->B1, kf->B2, vf->B3 (bias bqkv)
  k_gemm<EPI_SEGC_BIAS_BF16><<<dim3(24, 32), 256, 0, stream>>>(B0, pqT, NTc, 3072, Dc, nullptr, B1, bqkv, nullptr, nullptr, nullptr, nullptr);
  // fused l0: M=8192 over [qlmm;kf]; seg0 h1r->B0, seg1 h1->h1buf (both RELU)
  k_gemm<EPI_SEG2_RELU_BF16><<<dim3(8, 64), 256, 0, stream>>>(B1, l0T, 2 * NTc, Mc, Mc, (float*)h1buf, B0, b0c, nullptr, nullptr, nullptr, nullptr);
  // h2 = h1r@l1T + l1b + hb -> fp32 in outX (overwrites bf16 hn region; hn is dead)
  k_gemm<EPI_BIAS_RESB_F32><<<dim3(8, 32), 256, 0, stream>>>(B0, l1T, NTc, Mc, Mc, outX, nullptr, b1c, B4, nullptr, nullptr, nullptr);
  // pred = h1@l1T + l1b -> B1 (qlmm dead)
  k_gemm<EPI_BIAS_BF16><<<dim3(8, 32), 256, 0, stream>>>(h1buf, l1T, NTc, Mc, Mc, nullptr, B1, b1c, nullptr, nullptr, nullptr, nullptr);

  // ---- LMM loss bwd
  k_cvt<<<1024, 256, 0, stream>>>(l1w, l1c, (int)(DD / 4), flag);
  k_dpred<<<256, 256, 0, stream>>>(B1, B3, lossb);     // dp in-place over pred
  // dz = (h1>0) ? dp@l1c : 0  (h1>0 === z0>0)
  k_gemm<EPI_DZ_BF16><<<dim3(8, 32), 256, 0, stream>>>(B1, l1c, NTc, Mc, Mc, nullptr, B3, nullptr, h1buf, nullptr, nullptr, nullptr);
  k_gemm_tn<<<dim3(8, 8, 8), 256, 0, stream>>>(h1buf, B1, NTc, g1wF);   // g1w = h1^T dp
  k_gemm_tn<<<dim3(8, 8, 8), 256, 0, stream>>>(B2, B3, NTc, g0wF);      // g0w = kf^T dz
  k_transpose_dt<<<dim3(128, 32), tb, 0, stream>>>(fw1, w1T, Dc, Fc, flag);  // stage w1T (h1buf dead)
  k_colsum<<<dim3(4, 32), 256, 0, stream>>>(B1, g1b, Mc, NTc / 32);
  k_colsum<<<dim3(4, 32), 256, 0, stream>>>(B3, g0b, Mc, NTc / 32);
  k_update_dt<<<8200, 256, 0, stream>>>(l0w, l0b, l1w, l1b, m0w, m0b, m1w, m1b,
                                        g0wF, g0b, g1wF, g1b, lossb, flag, outP, outM);

  // ---- FFN (all B-slots free; h2 fp32 in outX)
  k_transpose_dt<<<dim3(128, 32), tb, 0, stream>>>(fw2, w2T, Dc, Fc, flag);     // stage w2T
  k_rmsnorm_f<<<NTc, 256, 0, stream>>>(outX, n3c, B4); // hn3 -> B4
  k_gemm<EPI_BF16><<<dim3(32, 32), 256, 0, stream>>>(B4, w1T, NTc, Fc, Dc, nullptr, s1, nullptr, nullptr, nullptr, nullptr, nullptr);
  k_transpose_dt<<<dim3(32, 128), tb, 0, stream>>>(fw3, w3T, Fc, Dc, flag);     // stage w3T (w1T dead)
  k_gemm<EPI_SILU_BF16><<<dim3(32, 32), 256, 0, stream>>>(B4, w2T, NTc, Fc, Dc, nullptr, s1, nullptr, s1, nullptr, nullptr, nullptr);
  // out = h2 + s1@w3T : split-K=2 fp32 atomics onto outX (pre-filled with h2)
  k_gemm<EPI_ATOMIC_F32><<<dim3(8, 32, 2), 256, 0, stream>>>(s1, w3T, NTc, Dc, Fc, outX, nullptr, nullptr, nullptr, nullptr, nullptr, nullptr);
}

// Round 6
// 921.292 us; speedup vs baseline: 1.2127x; 1.0357x over previous
//
#include <hip/hip_runtime.h>
#include <cstdint>
#include <cstddef>

typedef __bf16 bf16;
typedef __bf16 bf16x2 __attribute__((ext_vector_type(2)));
typedef __bf16 bf16x4 __attribute__((ext_vector_type(4)));
typedef __bf16 bf16x8 __attribute__((ext_vector_type(8)));
typedef float  f32x4  __attribute__((ext_vector_type(4)));
typedef float  f32x16 __attribute__((ext_vector_type(16)));
typedef __attribute__((address_space(1))) unsigned int u32_g;
typedef __attribute__((address_space(3))) unsigned int u32_l;

#define DI __device__ __forceinline__

constexpr int Bc = 2, Sc = 2048, Dc = 1024, Hc = 16, HDc = 64, Fc = 4096, Mc = 1024;
constexpr int NTc = Bc * Sc;  // 4096 tokens

DI void llds16(const bf16* g, bf16* l) {
  __builtin_amdgcn_global_load_lds((const u32_g*)g, (u32_l*)l, 16, 0, 0);
}
DI f32x4 cvt4(bf16x4 a) {
  f32x4 r; r[0] = (float)a[0]; r[1] = (float)a[1]; r[2] = (float)a[2]; r[3] = (float)a[3];
  return r;
}

// ---------------------------------------------------------------- dtype detector (inputs)
__global__ void k_detect(const unsigned short* __restrict__ x, int* __restrict__ flag)
{
  const int tid = threadIdx.x;  // 64
  int cnt = 0;
#pragma unroll
  for (int i = 0; i < 8; i++) {
    unsigned short h = x[tid * 8 + i];
    int e = (h >> 7) & 0xFF;
    if (e < 96 || e > 160) cnt++;
  }
#pragma unroll
  for (int off = 32; off > 0; off >>= 1) cnt += __shfl_down(cnt, off, 64);
  if (tid == 0) *flag = (cnt > 32) ? 1 : 0;
}

// ---------------------------------------------------------------- dtype-aware convert to bf16
__global__ __launch_bounds__(256)
void k_cvt(const void* __restrict__ src, bf16* __restrict__ dst, int n4, const int* __restrict__ flag)
{
  int i = blockIdx.x * 256 + threadIdx.x;
  if (i >= n4) return;
  bf16x4 o;
  if (*flag) {
    f32x4 v = ((const f32x4*)src)[i];
    o[0] = (bf16)v[0]; o[1] = (bf16)v[1]; o[2] = (bf16)v[2]; o[3] = (bf16)v[3];
  } else {
    o = ((const bf16x4*)src)[i];
  }
  ((bf16x4*)dst)[i] = o;
}

// ---------------------------------------------------------------- dtype-aware transpose [R][C] -> bf16 [C][R]
__global__ void k_transpose_dt(const void* __restrict__ src, bf16* __restrict__ dst,
                               int R, int C, const int* __restrict__ flag)
{
  __shared__ bf16 tile[32][33];
  const int c0 = blockIdx.x * 32, r0 = blockIdx.y * 32;
  const int tx = threadIdx.x, ty = threadIdx.y;
  const bool f32 = (*flag != 0);
  for (int i = ty; i < 32; i += 8) {
    size_t idx = (size_t)(r0 + i) * C + (c0 + tx);
    tile[i][tx] = f32 ? (bf16)((const float*)src)[idx] : ((const bf16*)src)[idx];
  }
  __syncthreads();
  for (int i = ty; i < 32; i += 8)
    dst[(size_t)(c0 + i) * R + (r0 + tx)] = tile[tx][i];
}

// ---------------------------------------------------------------- per-head V transpose: v[(b*S+s)][h*64+d] -> vt[(bh*64+d)][s]
__global__ void k_transpose_v(const bf16* __restrict__ v, bf16* __restrict__ vt)
{
  __shared__ bf16 tile[32][33];
  const int d0 = blockIdx.x * 32, s0 = blockIdx.y * 32;
  const int bh = blockIdx.z;
  const int b = bh >> 4, hh = bh & 15;
  const int tx = threadIdx.x, ty = threadIdx.y;
  for (int i = ty; i < 32; i += 8)
    tile[i][tx] = v[((size_t)(b * Sc + s0 + i)) * Dc + hh * HDc + d0 + tx];
  __syncthreads();
  for (int i = ty; i < 32; i += 8)
    vt[((size_t)(bh * HDc + d0 + i)) * Sc + s0 + tx] = tile[tx][i];
}

// ---------------------------------------------------------------- GEMM (NT): C[M][N] = A[M][K] * Bt[N][K]^T
// R2 lesson: every N=1024 GEMM at grid(8,32)=256 blocks = 1 block/CU -> the
// 4 waves are barrier-locked with zero cross-phase overlap (m114 needs ~3
// blocks/CU). Fix = batched dispatches:
//   EPI_SEGC_*: N=3072 fused (qkv / pqkv), col>>10 routes to 3 contiguous
//     8MiB output slots (B-slots are consecutive allocs).
//   EPI_SEG2_RELU: M=8192 fused l0-GEMM, rowb>>12 routes seg1 to out2
//     (passed via outF, reinterpreted bf16*).
//   EPI_ATOMIC_F32: split-K (blockIdx.z) fp32 atomicAdd epilogue; out must
//     be pre-filled with the residual (outX holds h2).
enum EpiMode { EPI_BF16 = 0, EPI_BIAS_BF16, EPI_BIAS_RELU_BF16, EPI_BIAS_RESB_F32,
               EPI_SILU_BF16, EPI_DZ_BF16, EPI_RESX_BF16, EPI_RESF_F32,
               EPI_SEGC_BF16, EPI_SEGC_BIAS_BF16, EPI_SEG2_RELU_BF16, EPI_ATOMIC_F32 };

template <int EPI>
__global__ __launch_bounds__(256)
void k_gemm(const bf16* __restrict__ A, const bf16* __restrict__ Bt,
            int Mr, int Nr, int Kr,
            float* outF, bf16* outB,
            const bf16* __restrict__ bias, const bf16* auxB,
            const float* resF,
            const void* __restrict__ resX, const int* __restrict__ flag)
{
  __shared__ bf16 As[128 * 32];
  __shared__ bf16 Bs[128 * 32];
  const int tid = threadIdx.x;
  const int w = tid >> 6, l = tid & 63;
  const int wr = w >> 1, wc = w & 1;
  const int row0 = blockIdx.y * 128, col0 = blockIdx.x * 128;

  const f32x4 vzero = {0.f, 0.f, 0.f, 0.f};
  f32x4 acc[4][4];
#pragma unroll
  for (int i = 0; i < 4; i++)
#pragma unroll
    for (int j = 0; j < 4; j++) acc[i][j] = vzero;

  const bf16* Ag = A + (size_t)(row0 + w * 16 + (l >> 2)) * Kr + ((l & 3) << 3);
  const bf16* Bg = Bt + (size_t)(col0 + w * 16 + (l >> 2)) * Kr + ((l & 3) << 3);
  bf16* AsW = &As[w * 512];
  bf16* BsW = &Bs[w * 512];
  const size_t rowHop = (size_t)64 * Kr;

  const int chunk = Kr / gridDim.z;           // split-K support (z=1 -> full K)
  const int kbeg = blockIdx.z * chunk;

  for (int k0 = kbeg; k0 < kbeg + chunk; k0 += 32) {
    __syncthreads();
    llds16(Ag + k0, AsW);
    llds16(Ag + rowHop + k0, AsW + 2048);
    llds16(Bg + k0, BsW);
    llds16(Bg + rowHop + k0, BsW + 2048);
    __syncthreads();
    bf16x8 af[4], bfr[4];
#pragma unroll
    for (int mt = 0; mt < 4; mt++)
      af[mt] = *(const bf16x8*)&As[(wr * 64 + mt * 16 + (l & 15)) * 32 + (l >> 4) * 8];
#pragma unroll
    for (int nt = 0; nt < 4; nt++)
      bfr[nt] = *(const bf16x8*)&Bs[(wc * 64 + nt * 16 + (l & 15)) * 32 + (l >> 4) * 8];
#pragma unroll
    for (int mt = 0; mt < 4; mt++)
#pragma unroll
      for (int nt = 0; nt < 4; nt++)
        acc[mt][nt] = __builtin_amdgcn_mfma_f32_16x16x32_bf16(af[mt], bfr[nt], acc[mt][nt], 0, 0, 0);
  }

  const bool f32res = (EPI == EPI_RESX_BF16) ? (*flag != 0) : false;
  // bias preload (before ANY store exists -> fully parallel)
  float biasv[4];
  if (EPI == EPI_BIAS_BF16 || EPI == EPI_BIAS_RELU_BF16 || EPI == EPI_BIAS_RESB_F32 ||
      EPI == EPI_SEGC_BIAS_BF16 || EPI == EPI_SEG2_RELU_BF16) {
#pragma unroll
    for (int nt = 0; nt < 4; nt++)
      biasv[nt] = (float)bias[col0 + wc * 64 + nt * 16 + (l & 15)];
  }
  // C/D layout (verified m89/m91): col = lane&15, row = (lane>>4)*4 + reg
#pragma unroll
  for (int mt = 0; mt < 4; mt++) {
    const int rowb = row0 + wr * 64 + mt * 16 + ((l >> 4) << 2);
    // phase 1: batch-gather aux/res for this mt (16 independent loads)
    float av[4][4];
    if (EPI == EPI_SILU_BF16 || EPI == EPI_DZ_BF16 || EPI == EPI_BIAS_RESB_F32) {
#pragma unroll
      for (int nt = 0; nt < 4; nt++) {
        const int col = col0 + wc * 64 + nt * 16 + (l & 15);
#pragma unroll
        for (int r = 0; r < 4; r++)
          av[nt][r] = (float)auxB[(size_t)(rowb + r) * Nr + col];
      }
    }
    if (EPI == EPI_RESF_F32) {
#pragma unroll
      for (int nt = 0; nt < 4; nt++) {
        const int col = col0 + wc * 64 + nt * 16 + (l & 15);
#pragma unroll
        for (int r = 0; r < 4; r++)
          av[nt][r] = resF[(size_t)(rowb + r) * Nr + col];
      }
    }
    if (EPI == EPI_RESX_BF16) {
#pragma unroll
      for (int nt = 0; nt < 4; nt++) {
        const int col = col0 + wc * 64 + nt * 16 + (l & 15);
#pragma unroll
        for (int r = 0; r < 4; r++) {
          const size_t idx = (size_t)(rowb + r) * Nr + col;
          av[nt][r] = f32res ? ((const float*)resX)[idx] : (float)((const bf16*)resX)[idx];
        }
      }
    }
    // phase 2: compute + store
#pragma unroll
    for (int nt = 0; nt < 4; nt++) {
      const int col = col0 + wc * 64 + nt * 16 + (l & 15);
#pragma unroll
      for (int r = 0; r < 4; r++) {
        const size_t idx = (size_t)(rowb + r) * Nr + col;
        float v = acc[mt][nt][r];
        if (EPI == EPI_BF16) { outB[idx] = (bf16)v; }
        else if (EPI == EPI_BIAS_BF16) { outB[idx] = (bf16)(v + biasv[nt]); }
        else if (EPI == EPI_BIAS_RELU_BF16) { outB[idx] = (bf16)fmaxf(v + biasv[nt], 0.f); }
        else if (EPI == EPI_BIAS_RESB_F32) { outF[idx] = v + biasv[nt] + av[nt][r]; }
        else if (EPI == EPI_SILU_BF16) {
          float s1v = av[nt][r];
          float sl = s1v / (1.f + __expf(-s1v));
          outB[idx] = (bf16)(sl * v);
        }
        else if (EPI == EPI_DZ_BF16) { outB[idx] = (bf16)(av[nt][r] > 0.f ? v : 0.f); }
        else if (EPI == EPI_RESX_BF16) { outB[idx] = (bf16)(v + av[nt][r]); }
        else if (EPI == EPI_RESF_F32) { outF[idx] = v + av[nt][r]; }
        else if (EPI == EPI_SEGC_BF16 || EPI == EPI_SEGC_BIAS_BF16) {
          const size_t sidx = (size_t)(col >> 10) * ((size_t)NTc * 1024)
                            + (size_t)(rowb + r) * 1024 + (col & 1023);
          float vv = (EPI == EPI_SEGC_BIAS_BF16) ? (v + biasv[nt]) : v;
          outB[sidx] = (bf16)vv;
        }
        else if (EPI == EPI_SEG2_RELU_BF16) {
          bf16* ob = (rowb >> 12) ? (bf16*)outF : outB;
          ob[(size_t)((rowb + r) & 4095) * 1024 + col] = (bf16)fmaxf(v + biasv[nt], 0.f);
        }
        else if (EPI == EPI_ATOMIC_F32) {
          atomicAdd(&outF[(size_t)(rowb + r) * Nr + col], v);
        }
      }
    }
  }
}

// ---------------------------------------------------------------- GEMM (TN) split-K: C[i][j] += sum_t X[t][i]*Y[t][j]
__global__ __launch_bounds__(256)
void k_gemm_tn(const bf16* __restrict__ X, const bf16* __restrict__ Y, int Kt,
               float* __restrict__ out)
{
  __shared__ bf16 As[128 * 36];
  __shared__ bf16 Bs[128 * 36];
  const int tid = threadIdx.x;
  const int w = tid >> 6, l = tid & 63;
  const int wr = w >> 1, wc = w & 1;
  const int row0 = blockIdx.y * 128, col0 = blockIdx.x * 128;
  const int iofs = (tid & 15) * 8;   // 0..120
  const int tp   = (tid >> 4) * 2;   // 0..30

  const f32x4 vzero = {0.f, 0.f, 0.f, 0.f};
  f32x4 acc[4][4];
#pragma unroll
  for (int i = 0; i < 4; i++)
#pragma unroll
    for (int j = 0; j < 4; j++) acc[i][j] = vzero;

  const int chunk = Kt / gridDim.z;
  const int tbeg = blockIdx.z * chunk;

  for (int t0 = tbeg; t0 < tbeg + chunk; t0 += 32) {
    __syncthreads();
    bf16x8 a0 = *(const bf16x8*)&X[(size_t)(t0 + tp) * 1024 + row0 + iofs];
    bf16x8 a1 = *(const bf16x8*)&X[(size_t)(t0 + tp + 1) * 1024 + row0 + iofs];
    bf16x8 b0 = *(const bf16x8*)&Y[(size_t)(t0 + tp) * 1024 + col0 + iofs];
    bf16x8 b1 = *(const bf16x8*)&Y[(size_t)(t0 + tp + 1) * 1024 + col0 + iofs];
#pragma unroll
    for (int e = 0; e < 8; e++) {
      bf16x2 pa; pa[0] = a0[e]; pa[1] = a1[e];
      bf16x2 pb; pb[0] = b0[e]; pb[1] = b1[e];
      *(bf16x2*)&As[(iofs + e) * 36 + tp] = pa;
      *(bf16x2*)&Bs[(iofs + e) * 36 + tp] = pb;
    }
    __syncthreads();
    bf16x8 af[4], bfr[4];
#pragma unroll
    for (int mt = 0; mt < 4; mt++) {
      const int base = (wr * 64 + mt * 16 + (l & 15)) * 36 + (l >> 4) * 8;
      bf16x4 lo = *(const bf16x4*)&As[base];
      bf16x4 hi = *(const bf16x4*)&As[base + 4];
#pragma unroll
      for (int e = 0; e < 4; e++) { af[mt][e] = lo[e]; af[mt][4 + e] = hi[e]; }
    }
#pragma unroll
    for (int nt = 0; nt < 4; nt++) {
      const int base = (wc * 64 + nt * 16 + (l & 15)) * 36 + (l >> 4) * 8;
      bf16x4 lo = *(const bf16x4*)&Bs[base];
      bf16x4 hi = *(const bf16x4*)&Bs[base + 4];
#pragma unroll
      for (int e = 0; e < 4; e++) { bfr[nt][e] = lo[e]; bfr[nt][4 + e] = hi[e]; }
    }
#pragma unroll
    for (int mt = 0; mt < 4; mt++)
#pragma unroll
      for (int nt = 0; nt < 4; nt++)
        acc[mt][nt] = __builtin_amdgcn_mfma_f32_16x16x32_bf16(af[mt], bfr[nt], acc[mt][nt], 0, 0, 0);
  }

#pragma unroll
  for (int mt = 0; mt < 4; mt++) {
    const int rowb = row0 + wr * 64 + mt * 16 + ((l >> 4) << 2);
#pragma unroll
    for (int nt = 0; nt < 4; nt++) {
      const int col = col0 + wc * 64 + nt * 16 + (l & 15);
#pragma unroll
      for (int r = 0; r < 4; r++)
        atomicAdd(&out[(size_t)(rowb + r) * 1024 + col], acc[mt][nt][r]);
    }
  }
}

// ---------------------------------------------------------------- RMSNorm variants
__global__ __launch_bounds__(256)
void k_rmsnorm_dt(const void* __restrict__ x, const bf16* __restrict__ w, bf16* __restrict__ out,
                  const int* __restrict__ flag)
{
  const int row = blockIdx.x;
  const int tid = threadIdx.x;
  f32x4 xv;
  if (*flag) xv = *(const f32x4*)((const float*)x + (size_t)row * Dc + tid * 4);
  else       xv = cvt4(*(const bf16x4*)((const bf16*)x + (size_t)row * Dc + tid * 4));
  float ss = xv[0] * xv[0] + xv[1] * xv[1] + xv[2] * xv[2] + xv[3] * xv[3];
#pragma unroll
  for (int off = 32; off > 0; off >>= 1) ss += __shfl_down(ss, off, 64);
  __shared__ float part[4];
  if ((tid & 63) == 0) part[tid >> 6] = ss;
  __syncthreads();
  float tot = part[0] + part[1] + part[2] + part[3];
  float inv = 1.f / (sqrtf(tot) * 0.03125f + 1e-8f);
  bf16x4 wb = *(const bf16x4*)(w + tid * 4);
  bf16x4 ov;
  ov[0] = (bf16)((float)wb[0] * xv[0] * inv);
  ov[1] = (bf16)((float)wb[1] * xv[1] * inv);
  ov[2] = (bf16)((float)wb[2] * xv[2] * inv);
  ov[3] = (bf16)((float)wb[3] * xv[3] * inv);
  *(bf16x4*)(out + (size_t)row * Dc + tid * 4) = ov;
}

__global__ __launch_bounds__(256)
void k_rmsnorm_b(const bf16* __restrict__ x, const bf16* __restrict__ w, bf16* __restrict__ out)
{
  const int row = blockIdx.x;
  const int tid = threadIdx.x;
  f32x4 xv = cvt4(*(const bf16x4*)(x + (size_t)row * Dc + tid * 4));
  float ss = xv[0] * xv[0] + xv[1] * xv[1] + xv[2] * xv[2] + xv[3] * xv[3];
#pragma unroll
  for (int off = 32; off > 0; off >>= 1) ss += __shfl_down(ss, off, 64);
  __shared__ float part[4];
  if ((tid & 63) == 0) part[tid >> 6] = ss;
  __syncthreads();
  float tot = part[0] + part[1] + part[2] + part[3];
  float inv = 1.f / (sqrtf(tot) * 0.03125f + 1e-8f);
  bf16x4 wb = *(const bf16x4*)(w + tid * 4);
  bf16x4 ov;
  ov[0] = (bf16)((float)wb[0] * xv[0] * inv);
  ov[1] = (bf16)((float)wb[1] * xv[1] * inv);
  ov[2] = (bf16)((float)wb[2] * xv[2] * inv);
  ov[3] = (bf16)((float)wb[3] * xv[3] * inv);
  *(bf16x4*)(out + (size_t)row * Dc + tid * 4) = ov;
}

__global__ __launch_bounds__(256)
void k_rmsnorm_f(const float* __restrict__ x, const bf16* __restrict__ w, bf16* __restrict__ out)
{
  const int row = blockIdx.x;
  const int tid = threadIdx.x;
  f32x4 xv = *(const f32x4*)(x + (size_t)row * Dc + tid * 4);
  float ss = xv[0] * xv[0] + xv[1] * xv[1] + xv[2] * xv[2] + xv[3] * xv[3];
#pragma unroll
  for (int off = 32; off > 0; off >>= 1) ss += __shfl_down(ss, off, 64);
  __shared__ float part[4];
  if ((tid & 63) == 0) part[tid >> 6] = ss;
  __syncthreads();
  float tot = part[0] + part[1] + part[2] + part[3];
  float inv = 1.f / (sqrtf(tot) * 0.03125f + 1e-8f);
  bf16x4 wb = *(const bf16x4*)(w + tid * 4);
  bf16x4 ov;
  ov[0] = (bf16)((float)wb[0] * xv[0] * inv);
  ov[1] = (bf16)((float)wb[1] * xv[1] * inv);
  ov[2] = (bf16)((float)wb[2] * xv[2] * inv);
  ov[3] = (bf16)((float)wb[3] * xv[3] * inv);
  *(bf16x4*)(out + (size_t)row * Dc + tid * 4) = ov;
}

// ---------------------------------------------------------------- RoPE in-place on bf16 q,k
__global__ __launch_bounds__(256)
void k_rope(bf16* __restrict__ q, bf16* __restrict__ kx)
{
  const int idx = blockIdx.x * 256 + threadIdx.x;  // NT*H = 65536
  const int t = idx >> 4, hh = idx & 15;
  const int s = t & (Sc - 1);
  float sn[32], cs[32];
#pragma unroll
  for (int i = 0; i < 32; i++) {
    float f = expf(-(float)i * 0.28782313662425574f);  // ln(10000)/32
    float ang = (float)s * f;
    sn[i] = sinf(ang);
    cs[i] = cosf(ang);
  }
  for (int pass = 0; pass < 2; pass++) {
    bf16* p = (pass ? kx : q) + (size_t)t * Dc + hh * HDc;
    float xb[64], ob[64];
#pragma unroll
    for (int j = 0; j < 16; j++) *(f32x4*)&xb[j * 4] = cvt4(*(const bf16x4*)(p + j * 4));
#pragma unroll
    for (int i = 0; i < 32; i++) {
      float x1 = xb[2 * i], x2 = xb[2 * i + 1];
      ob[i] = x1 * cs[i] - x2 * sn[i];
      ob[32 + i] = x1 * sn[i] + x2 * cs[i];
    }
#pragma unroll
    for (int j = 0; j < 16; j++) {
      bf16x4 o4;
      o4[0] = (bf16)ob[j * 4]; o4[1] = (bf16)ob[j * 4 + 1];
      o4[2] = (bf16)ob[j * 4 + 2]; o4[3] = (bf16)ob[j * 4 + 3];
      *(bf16x4*)(p + j * 4) = o4;
    }
  }
}

// ---------------------------------------------------------------- MFMA flash attention: swapped-QK^T, lane-local softmax,
// kv-split across 4 waves.
// R4 lesson: single-wave-per-32q was correct (109us) but grid 512 = 2
// waves/SIMD with up to 64 serial kv-tiles -> occupancy 11.7%, exposed
// latency. Re-shard: block = one 32-q chunk, 4 waves split the kv-tile
// range mod 4 (private scalar m,l + 32-reg O^T), one-barrier LDS merge.
// R5 BUG: grid was 4096 (128 q-chunks) but S/32 = 64 chunks per (b,h);
// qc>=64 wrote O into the next batch's rows. Fix: qc = 63-(blk>>5),
// grid 2048. Serial depth 64 -> 16; ~5 blocks/CU resident (26.9KB LDS).
__global__ __launch_bounds__(256)
void k_attn(const bf16* __restrict__ q, const bf16* __restrict__ kx,
            const bf16* __restrict__ vt, bf16* __restrict__ o)
{
  union UV { bf16x8 v; unsigned int u[4]; };
  union UH { bf16x2 h; unsigned int u; };

  __shared__ float Buf[3 * 64 * 35];   // 26880B: 3 waves x 64 lanes x (32 O + m + l), stride 35

  const int blk = blockIdx.x;
  const int qc = 63 - (blk >> 5);      // q-chunk (64 per bh), heavy first (LPT)
  const int bh = blk & 31;             // same head -> same XCD residue
  const int b = bh >> 4, hh = bh & 15;
  const int tid = threadIdx.x;
  const int w = tid >> 6, l = tid & 63;
  const int hi = l >> 5, lq = l & 31;

  const int q0 = qc * 32;              // block's 32 q-rows (shared by all 4 waves)
  const int ntiles = qc + 1;           // 32-wide kv tiles up to the diagonal

  const bf16* kb = kx + (size_t)b * Sc * Dc + hh * HDc;
  const bf16* vb = vt + (size_t)bh * HDc * Sc;

  // Q fragments (B-operand): lane holds Q[q0+lq][ds*16 + hi*8 .. +8], pre-scaled
  bf16x8 qf[4];
  {
    const bf16* qp = q + ((size_t)(b * Sc + q0 + lq)) * Dc + hh * HDc + hi * 8;
#pragma unroll
    for (int ds = 0; ds < 4; ds++) {
      qf[ds] = *(const bf16x8*)(qp + ds * 16);
#pragma unroll
      for (int j = 0; j < 8; j++) qf[ds][j] = (bf16)((float)qf[ds][j] * 0.125f);
    }
  }

  f32x16 oacc0, oacc1;                 // O^T[d][q]: d-tiles 0-31 / 32-63
#pragma unroll
  for (int j = 0; j < 16; j++) { oacc0[j] = 0.f; oacc1[j] = 0.f; }
  float mrun = -3.0e38f, lrun = 0.f;

  for (int t0 = w; t0 < ntiles; t0 += 4) {
    const int kk0 = t0 * 32;

    // QK^T: A = K[32k][16d-slice] (lane: K[kk0+lq][ds*16+hi*8..+8])
    const bf16* kp = kb + (size_t)(kk0 + lq) * Dc + hi * 8;
    f32x16 sacc;
#pragma unroll
    for (int j = 0; j < 16; j++) sacc[j] = 0.f;
#pragma unroll
    for (int ds = 0; ds < 4; ds++) {
      bf16x8 kf = *(const bf16x8*)(kp + ds * 16);
      sacc = __builtin_amdgcn_mfma_f32_32x32x16_bf16(kf, qf[ds], sacc, 0, 0, 0);
    }

    if (t0 == ntiles - 1) {            // diagonal tile: causal mask (kk0 == q0)
#pragma unroll
      for (int reg = 0; reg < 16; reg++) {
        const int kidx = (reg & 3) + 8 * (reg >> 2) + 4 * hi;
        sacc[reg] = (kidx > lq) ? -3.0e38f : sacc[reg];
      }
    }

    // per-lane online softmax (q = q0 + lq)
    float mx = sacc[0];
#pragma unroll
    for (int reg = 1; reg < 16; reg++) mx = fmaxf(mx, sacc[reg]);
    mx = fmaxf(mx, __shfl_xor(mx, 32, 64));

    const float mnew = fmaxf(mrun, mx);
    const float al = __expf(mrun - mnew);
    mrun = mnew;
    float p[16], ps = 0.f;
#pragma unroll
    for (int reg = 0; reg < 16; reg++) { p[reg] = __expf(sacc[reg] - mnew); ps += p[reg]; }
    ps += __shfl_xor(ps, 32, 64);
    lrun = lrun * al + ps;
#pragma unroll
    for (int j = 0; j < 16; j++) { oacc0[j] *= al; oacc1[j] *= al; }

    // pack P -> bf16x2 words; 4 shfl_xor(32) route k-halves into B-frags:
    // pa0 = P[q][k 0..15], pa1 = P[q][k 16..31] (k = kb*16 + hi*8 + j)
    unsigned int wv[8];
#pragma unroll
    for (int m = 0; m < 8; m++) {
      UH t; t.h[0] = (bf16)p[2 * m]; t.h[1] = (bf16)p[2 * m + 1];
      wv[m] = t.u;
    }
    const unsigned int ex0 = __shfl_xor(hi ? wv[0] : wv[2], 32, 64);
    const unsigned int ex1 = __shfl_xor(hi ? wv[1] : wv[3], 32, 64);
    const unsigned int ex2 = __shfl_xor(hi ? wv[4] : wv[6], 32, 64);
    const unsigned int ex3 = __shfl_xor(hi ? wv[5] : wv[7], 32, 64);
    UV pa0, pa1;
    pa0.u[0] = hi ? ex0 : wv[0];  pa0.u[1] = hi ? ex1 : wv[1];
    pa0.u[2] = hi ? wv[2] : ex0;  pa0.u[3] = hi ? wv[3] : ex1;
    pa1.u[0] = hi ? ex2 : wv[4];  pa1.u[1] = hi ? ex3 : wv[5];
    pa1.u[2] = hi ? wv[6] : ex2;  pa1.u[3] = hi ? wv[7] : ex3;

    // PV: A = V^T[32d][16k] from Vt (lane: Vt[dt*32+lq][kk0+kb*16+hi*8..+8])
    const bf16* vp = vb + (size_t)lq * Sc + kk0 + hi * 8;
    bf16x8 v00 = *(const bf16x8*)(vp);
    bf16x8 v10 = *(const bf16x8*)(vp + 16);
    bf16x8 v01 = *(const bf16x8*)(vp + (size_t)32 * Sc);
    bf16x8 v11 = *(const bf16x8*)(vp + (size_t)32 * Sc + 16);
    oacc0 = __builtin_amdgcn_mfma_f32_32x32x16_bf16(v00, pa0.v, oacc0, 0, 0, 0);
    oacc0 = __builtin_amdgcn_mfma_f32_32x32x16_bf16(v10, pa1.v, oacc0, 0, 0, 0);
    oacc1 = __builtin_amdgcn_mfma_f32_32x32x16_bf16(v01, pa0.v, oacc1, 0, 0, 0);
    oacc1 = __builtin_amdgcn_mfma_f32_32x32x16_bf16(v11, pa1.v, oacc1, 0, 0, 0);
  }

  // ---- cross-wave online-softmax merge (waves 1..3 -> wave 0).
  // Per-lane state is scalar (m,l) + 32 O regs; lane l of every wave maps to
  // the same (q,d) slice, so the merge is lane-to-lane. Stride 35 dwords ->
  // consecutive lanes hit banks 3 apart (coprime w/ 32): 2-way alias = free.
  if (w > 0) {
    float* dst = &Buf[((w - 1) * 64 + l) * 35];
#pragma unroll
    for (int j = 0; j < 16; j++) { dst[j] = oacc0[j]; dst[16 + j] = oacc1[j]; }
    dst[32] = mrun; dst[33] = lrun;
  }
  __syncthreads();
  if (w == 0) {
#pragma unroll
    for (int w2 = 0; w2 < 3; w2++) {
      const float* src = &Buf[(w2 * 64 + l) * 35];
      const float m2 = src[32], l2 = src[33];
      const float mn = fmaxf(mrun, m2);
      const float a = __expf(mrun - mn);
      const float bb = __expf(m2 - mn);
      lrun = lrun * a + l2 * bb;
      mrun = mn;
#pragma unroll
      for (int j = 0; j < 16; j++) {
        oacc0[j] = oacc0[j] * a + src[j] * bb;
        oacc1[j] = oacc1[j] * a + src[16 + j] * bb;
      }
    }

    // epilogue: O^T reg pairs are d-adjacent -> 4B dword stores into o[q][d]
    const float inv = 1.f / lrun;
    bf16* op = o + ((size_t)(b * Sc + q0 + lq)) * Dc + hh * HDc;
#pragma unroll
    for (int m = 0; m < 8; m++) {
      const int d0 = (2 * m & 3) + 8 * (m >> 1) + 4 * hi;
      UH t0v; t0v.h[0] = (bf16)(oacc0[2 * m] * inv); t0v.h[1] = (bf16)(oacc0[2 * m + 1] * inv);
      *(unsigned int*)(op + d0) = t0v.u;
      UH t1v; t1v.h[0] = (bf16)(oacc1[2 * m] * inv); t1v.h[1] = (bf16)(oacc1[2 * m + 1] * inv);
      *(unsigned int*)(op + 32 + d0) = t1v.u;
    }
  }
}

// ---------------------------------------------------------------- dp = 2(pred-vf)/M in-place + loss
__global__ __launch_bounds__(256)
void k_dpred(bf16* __restrict__ predDp, const bf16* __restrict__ vf, float* __restrict__ loss)
{
  __shared__ float red[4];
  const int tid = threadIdx.x;
  const size_t n8 = (size_t)NTc * Mc / 8;
  float lacc = 0.f;
  for (size_t i = (size_t)blockIdx.x * 256 + tid; i < n8; i += (size_t)gridDim.x * 256) {
    bf16x8 p8 = ((const bf16x8*)predDp)[i];
    bf16x8 v8 = ((const bf16x8*)vf)[i];
    bf16x8 d8;
#pragma unroll
    for (int e = 0; e < 8; e++) {
      float df = (float)p8[e] - (float)v8[e];
      lacc += df * df;
      d8[e] = (bf16)(df * (2.0f / 1024.0f));
    }
    ((bf16x8*)predDp)[i] = d8;
  }
#pragma unroll
  for (int off = 32; off > 0; off >>= 1) lacc += __shfl_down(lacc, off, 64);
  if ((tid & 63) == 0) red[tid >> 6] = lacc;
  __syncthreads();
  if (tid == 0) atomicAdd(loss, red[0] + red[1] + red[2] + red[3]);
}

// ---------------------------------------------------------------- colsum: out[c] += sum over a row chunk
__global__ __launch_bounds__(256)
void k_colsum(const bf16* __restrict__ X, float* __restrict__ out, int C, int rowsPer)
{
  int c = blockIdx.x * 256 + threadIdx.x;
  int r0 = blockIdx.y * rowsPer;
  float s = 0.f;
#pragma unroll 8
  for (int r = r0; r < r0 + rowsPer; r++) s += (float)X[(size_t)r * C + c];
  atomicAdd(&out[c], s);
}

// ---------------------------------------------------------------- dtype-aware param/momentum update -> fp32 d_out
__global__ __launch_bounds__(256)
void k_update_dt(const void* __restrict__ p0w, const void* __restrict__ p0b,
                 const void* __restrict__ p1w, const void* __restrict__ p1b,
                 const void* __restrict__ m0w, const void* __restrict__ m0b,
                 const void* __restrict__ m1w, const void* __restrict__ m1b,
                 const float* __restrict__ g0wF, const float* __restrict__ g0b,
                 const float* __restrict__ g1wF, const float* __restrict__ g1b,
                 const float* __restrict__ loss, const int* __restrict__ flag,
                 float* __restrict__ outP, float* __restrict__ outM)
{
  const int i = blockIdx.x * 256 + threadIdx.x;  // < 2099200 exactly
  const bool upd = (loss[0] >= 0.1f * 1024.f * 4096.f);  // avg_loss >= THRESH
  const bool f32 = (*flag != 0);
  constexpr int W = 1024 * 1024;
  const void *pp, *pm; int j; float g;
  if (i < W) { pp = p0w; pm = m0w; j = i; g = g0wF[i]; }
  else if (i < W + 1024) { j = i - W; pp = p0b; pm = m0b; g = g0b[j]; }
  else if (i < 2 * W + 1024) { j = i - W - 1024; pp = p1w; pm = m1w; g = g1wF[j]; }
  else { j = i - 2 * W - 1024; pp = p1b; pm = m1b; g = g1b[j]; }
  float p = f32 ? ((const float*)pp)[j] : (float)((const bf16*)pp)[j];
  float m = f32 ? ((const float*)pm)[j] : (float)((const bf16*)pm)[j];
  float nm = 0.9f * m - 0.01f * g;
  float np = 0.99f * p + nm;
  outP[i] = upd ? np : p;
  outM[i] = upd ? nm : m;
}

// ================================================================ host
extern "C" void kernel_launch(void* const* d_in, const int* in_sizes, int n_in,
                              void* d_out, int out_size, void* d_ws, size_t ws_size,
                              hipStream_t stream)
{
  (void)in_sizes; (void)n_in; (void)out_size; (void)ws_size;
  const void* x   = d_in[0];
  const void* wq  = d_in[2];
  const void* wk  = d_in[3];
  const void* wv  = d_in[4];
  const void* wo  = d_in[5];
  const void* n1  = d_in[6];
  const void* n2  = d_in[7];
  const void* n3  = d_in[8];
  const void* fw1 = d_in[9];
  const void* fw2 = d_in[10];
  const void* fw3 = d_in[11];
  const void* pkw = d_in[12];
  const void* pkb = d_in[13];
  const void* pvw = d_in[14];
  const void* pvb = d_in[15];
  const void* pqw = d_in[16];
  const void* pqb = d_in[17];
  const void* l0w = d_in[18];
  const void* l0b = d_in[19];
  const void* l1w = d_in[20];
  const void* l1b = d_in[21];
  const void* m0w = d_in[22];
  const void* m0b = d_in[23];
  const void* m1w = d_in[24];
  const void* m1b = d_in[25];

  char* ws = (char*)d_ws;
  size_t off = 0;
  auto alloc = [&](size_t bytes) -> char* {
    char* p = ws + off;
    off += (bytes + 255) & ~(size_t)255;
    return p;
  };

  const size_t DD = (size_t)Dc * Dc;   // 1M elems
  const size_t ND = (size_t)NTc * Dc;  // 4M elems
  const size_t MB8 = 2 * ND;           // 8 MiB
  const size_t M1 = DD;                // 1M elems

  // --- weight region W: 8M bf16 elems (16 MiB), phase-cycled
  bf16* W = (bf16*)alloc(2 * 8 * M1);
  bf16 *wqT = W, *wkT = W + M1, *wvT = W + 2 * M1, *woT = W + 3 * M1;   // contiguous [3072][1024] for fused qkv
  bf16 *pqT = W + 4 * M1, *pkT = W + 5 * M1, *pvT = W + 6 * M1, *l0T = W + 7 * M1;  // pqT..pvT = fused [3072][1024]
  bf16 *l1T = W + M1;          // staged after wo-GEMM (wkT dead)
  bf16 *h1buf = W + 2 * M1;    // h1 [4096][1024] after fused l0 (wvT/woT/pqT/pkT dead; l0T untouched)
  bf16 *l1c = W;               // staged after pred-GEMM (over wqT)
  bf16 *w1T = W + 4 * M1;      // staged after gemm_tn's (h1buf upper, pvT, l0T dead)
  bf16 *w2T = W;               // staged after grads (l1c/l1T/h1buf-lower dead)
  bf16 *w3T = W + 4 * M1;      // staged after ffn1 (w1T dead)

  // --- 5 activation slots, B0..B3 contiguous (seg-routing + s1 span rely on this)
  bf16* B0 = (bf16*)alloc(MB8);  // q -> hn2 -> h1r -> (s1)
  bf16* B1 = (bf16*)alloc(MB8);  // k -> qlmm -> pred/dp -> (s1)
  bf16* B2 = (bf16*)alloc(MB8);  // v -> kf -> (s1)
  bf16* B3 = (bf16*)alloc(MB8);  // o -> vf -> dz -> (s1)
  bf16* B4 = (bf16*)alloc(MB8);  // Vt (attn) -> hb -> hn3
  bf16* s1 = B0;                 // [NT][F] = 32 MiB
  bf16* VtG = B4;                // [BH][HD][S] per-head transposed V, dead before hb

  // --- smalls
  float* g0b = (float*)alloc(4 * 1024);
  float* g1b = (float*)alloc(4 * 1024);
  float* lossb = (float*)alloc(256);
  int*   flag  = (int*)alloc(256);
  bf16* n1c = (bf16*)alloc(2 * 1024);
  bf16* n2c = (bf16*)alloc(2 * 1024);
  bf16* n3c = (bf16*)alloc(2 * 1024);
  bf16* bqkv = (bf16*)alloc(2 * 3072);   // [bq;bk;bv] contiguous for fused pqkv
  bf16* b0c = (bf16*)alloc(2 * 1024);
  bf16* b1c = (bf16*)alloc(2 * 1024);

  // --- output regions (fp32)
  float* outX = (float*)d_out;                 // hn(bf16 head), then h2 fp32, then final out fp32
  float* outP = outX + ND;                     // new params (l0w,l0b,l1w,l1b)
  float* outM = outP + (2 * DD + 2048);        // new momenta; hosts g0wF/g1wF pre-update
  float* g0wF = outM;                          // [1M] grad l0_w
  float* g1wF = outM + M1 + 1024;              // [1M] grad l1_w
  bf16*  hn   = (bf16*)outX;                   // bf16 hn in first 8 MiB of outX, dead before h2

  const dim3 tb(32, 8);

  hipMemsetAsync(lossb, 0, sizeof(float), stream);
  hipMemsetAsync(g0b, 0, 4 * 1024, stream);
  hipMemsetAsync(g1b, 0, 4 * 1024, stream);
  hipMemsetAsync(outM, 0, (2 * M1 + 2048) * sizeof(float), stream);  // zero g0wF/g1wF for split-K atomics
  k_detect<<<1, 64, 0, stream>>>((const unsigned short*)x, flag);

  // small cvts
  k_cvt<<<1, 256, 0, stream>>>(n1, n1c, 256, flag);
  k_cvt<<<1, 256, 0, stream>>>(n2, n2c, 256, flag);
  k_cvt<<<1, 256, 0, stream>>>(n3, n3c, 256, flag);
  k_cvt<<<1, 256, 0, stream>>>(pqb, bqkv, 256, flag);
  k_cvt<<<1, 256, 0, stream>>>(pkb, bqkv + 1024, 256, flag);
  k_cvt<<<1, 256, 0, stream>>>(pvb, bqkv + 2048, 256, flag);
  k_cvt<<<1, 256, 0, stream>>>(l0b, b0c, 256, flag);
  k_cvt<<<1, 256, 0, stream>>>(l1b, b1c, 256, flag);

  // phase-1 weight transposes
  k_transpose_dt<<<dim3(32, 32), tb, 0, stream>>>(wq, wqT, Dc, Dc, flag);
  k_transpose_dt<<<dim3(32, 32), tb, 0, stream>>>(wk, wkT, Dc, Dc, flag);
  k_transpose_dt<<<dim3(32, 32), tb, 0, stream>>>(wv, wvT, Dc, Dc, flag);
  k_transpose_dt<<<dim3(32, 32), tb, 0, stream>>>(wo, woT, Dc, Dc, flag);
  k_transpose_dt<<<dim3(32, 32), tb, 0, stream>>>(pqw, pqT, Dc, Mc, flag);
  k_transpose_dt<<<dim3(32, 32), tb, 0, stream>>>(pkw, pkT, Dc, Mc, flag);
  k_transpose_dt<<<dim3(32, 32), tb, 0, stream>>>(pvw, pvT, Dc, Mc, flag);
  k_transpose_dt<<<dim3(32, 32), tb, 0, stream>>>(l0w, l0T, Mc, Mc, flag);

  // ---- attention
  k_rmsnorm_dt<<<NTc, 256, 0, stream>>>(x, n1c, hn, flag);
  // fused qkv: N=3072, 768 blocks = 3/CU; col>>10 routes to B0/B1/B2
  k_gemm<EPI_SEGC_BF16><<<dim3(24, 32), 256, 0, stream>>>(hn, wqT, NTc, 3072, Dc, nullptr, B0, nullptr, nullptr, nullptr, nullptr, nullptr);
  k_transpose_v<<<dim3(2, 64, 32), tb, 0, stream>>>(B2, VtG);   // per-head V^T -> B4
  k_rope<<<256, 256, 0, stream>>>(B0, B1);
  k_attn<<<2048, 256, 0, stream>>>(B0, B1, VtG, B3);
  k_gemm<EPI_RESX_BF16><<<dim3(8, 32), 256, 0, stream>>>(B3, woT, NTc, Dc, Dc, nullptr, B4, nullptr, nullptr, nullptr, x, flag);  // hb -> B4
  k_transpose_dt<<<dim3(32, 32), tb, 0, stream>>>(l1w, l1T, Mc, Mc, flag);

  // ---- LMM forward
  k_rmsnorm_b<<<NTc, 256, 0, stream>>>(B4, n2c, B0);   // hn2 -> B0
  // fused pqkv: qlmm->B1, kf->B2, vf->B3 (bias bqkv)
  k_gemm<EPI_SEGC_BIAS_BF16><<<dim3(24, 32), 256, 0, stream>>>(B0, pqT, NTc, 3072, Dc, nullptr, B1, bqkv, nullptr, nullptr, nullptr, nullptr);
  // fused l0: M=8192 over [qlmm;kf]; seg0 h1r->B0, seg1 h1->h1buf (both RELU)
  k_gemm<EPI_SEG2_RELU_BF16><<<dim3(8, 64), 256, 0, stream>>>(B1, l0T, 2 * NTc, Mc, Mc, (float*)h1buf, B0, b0c, nullptr, nullptr, nullptr, nullptr);
  // h2 = h1r@l1T + l1b + hb -> fp32 in outX (overwrites bf16 hn region; hn is dead)
  k_gemm<EPI_BIAS_RESB_F32><<<dim3(8, 32), 256, 0, stream>>>(B0, l1T, NTc, Mc, Mc, outX, nullptr, b1c, B4, nullptr, nullptr, nullptr);
  // pred = h1@l1T + l1b -> B1 (qlmm dead)
  k_gemm<EPI_BIAS_BF16><<<dim3(8, 32), 256, 0, stream>>>(h1buf, l1T, NTc, Mc, Mc, nullptr, B1, b1c, nullptr, nullptr, nullptr, nullptr);

  // ---- LMM loss bwd
  k_cvt<<<1024, 256, 0, stream>>>(l1w, l1c, (int)(DD / 4), flag);
  k_dpred<<<256, 256, 0, stream>>>(B1, B3, lossb);     // dp in-place over pred
  // dz = (h1>0) ? dp@l1c : 0  (h1>0 === z0>0)
  k_gemm<EPI_DZ_BF16><<<dim3(8, 32), 256, 0, stream>>>(B1, l1c, NTc, Mc, Mc, nullptr, B3, nullptr, h1buf, nullptr, nullptr, nullptr);
  k_gemm_tn<<<dim3(8, 8, 8), 256, 0, stream>>>(h1buf, B1, NTc, g1wF);   // g1w = h1^T dp
  k_gemm_tn<<<dim3(8, 8, 8), 256, 0, stream>>>(B2, B3, NTc, g0wF);      // g0w = kf^T dz
  k_transpose_dt<<<dim3(128, 32), tb, 0, stream>>>(fw1, w1T, Dc, Fc, flag);  // stage w1T (h1buf dead)
  k_colsum<<<dim3(4, 32), 256, 0, stream>>>(B1, g1b, Mc, NTc / 32);
  k_colsum<<<dim3(4, 32), 256, 0, stream>>>(B3, g0b, Mc, NTc / 32);
  k_update_dt<<<8200, 256, 0, stream>>>(l0w, l0b, l1w, l1b, m0w, m0b, m1w, m1b,
                                        g0wF, g0b, g1wF, g1b, lossb, flag, outP, outM);

  // ---- FFN (all B-slots free; h2 fp32 in outX)
  k_transpose_dt<<<dim3(128, 32), tb, 0, stream>>>(fw2, w2T, Dc, Fc, flag);     // stage w2T
  k_rmsnorm_f<<<NTc, 256, 0, stream>>>(outX, n3c, B4); // hn3 -> B4
  k_gemm<EPI_BF16><<<dim3(32, 32), 256, 0, stream>>>(B4, w1T, NTc, Fc, Dc, nullptr, s1, nullptr, nullptr, nullptr, nullptr, nullptr);
  k_transpose_dt<<<dim3(32, 128), tb, 0, stream>>>(fw3, w3T, Fc, Dc, flag);     // stage w3T (w1T dead)
  k_gemm<EPI_SILU_BF16><<<dim3(32, 32), 256, 0, stream>>>(B4, w2T, NTc, Fc, Dc, nullptr, s1, nullptr, s1, nullptr, nullptr, nullptr);
  // out = h2 + s1@w3T : split-K=2 fp32 atomics onto outX (pre-filled with h2)
  k_gemm<EPI_ATOMIC_F32><<<dim3(8, 32, 2), 256, 0, stream>>>(s1, w3T, NTc, Dc, Fc, outX, nullptr, nullptr, nullptr, nullptr, nullptr, nullptr);
}